// Round 2
// baseline (874.768 us; speedup 1.0000x reference)
//
#include <hip/hip_runtime.h>

// ---- problem constants ----
#define NB 2          // batch
#define LT 512        // per-tensor seq len
#define LL 2048       // concatenated seq len
#define MM 4096       // NB*LL rows
#define DMODEL 512
#define DINNER 1024
#define DTRANK 32
#define DSTATE 16
#define NSEG 8
#define SEGLEN 256    // NSEG*SEGLEN == LL

__device__ __forceinline__ float silu_f(float x) { return x / (1.f + __expf(-x)); }

// ---------------------------------------------------------------------------
// K1: fused interleaved gather + in_proj GEMM.
// C[m][n] = sum_k x[m][k] * W[n][k],  M=4096, N=2048, K=512
// writes n<1024 -> xc_raw, n>=1024 -> zbuf  (fp32)
// ---------------------------------------------------------------------------
__global__ __launch_bounds__(256) void k_inproj(
    const float* __restrict__ t0, const float* __restrict__ t1,
    const float* __restrict__ t2, const float* __restrict__ t3,
    const float* __restrict__ W,
    float* __restrict__ xc_raw, float* __restrict__ zbuf)
{
    __shared__ float As[16][64];
    __shared__ float Bs[16][64];
    const int t  = threadIdx.x;
    const int tx = t & 15, ty = t >> 4;
    const int bm = blockIdx.x, bn = blockIdx.y;

    const int lrow = t & 63;
    const int lkk  = (t >> 6) << 2;

    // gather: chunk c = l>>7 (0..15): tensor ti = c&3, offset i = c>>2; elem r = l&127
    // x[b, l, :] = t_ti[b, i + 4*r, :]
    const int arow = bm * 64 + lrow;
    const int b = arow >> 11;
    const int l = arow & 2047;
    const int c = l >> 7, r = l & 127;
    const int ti = c & 3, ci = c >> 2;
    const float* tp = (ti == 0) ? t0 : (ti == 1) ? t1 : (ti == 2) ? t2 : t3;
    const float* asrc = tp + ((size_t)b * 512 + (size_t)(ci + 4 * r)) * 512;
    const float* bsrc = W + (size_t)(bn * 64 + lrow) * 512;

    float acc[4][4] = {};

    for (int k0 = 0; k0 < 512; k0 += 16) {
        float4 av = *(const float4*)(asrc + k0 + lkk);
        float4 bv = *(const float4*)(bsrc + k0 + lkk);
        __syncthreads();
        As[lkk + 0][lrow] = av.x;
        As[lkk + 1][lrow] = av.y;
        As[lkk + 2][lrow] = av.z;
        As[lkk + 3][lrow] = av.w;
        Bs[lkk + 0][lrow] = bv.x;
        Bs[lkk + 1][lrow] = bv.y;
        Bs[lkk + 2][lrow] = bv.z;
        Bs[lkk + 3][lrow] = bv.w;
        __syncthreads();
#pragma unroll
        for (int kk = 0; kk < 16; ++kk) {
            float4 a  = *(const float4*)&As[kk][ty << 2];
            float4 bq = *(const float4*)&Bs[kk][tx << 2];
            acc[0][0] += a.x * bq.x; acc[0][1] += a.x * bq.y; acc[0][2] += a.x * bq.z; acc[0][3] += a.x * bq.w;
            acc[1][0] += a.y * bq.x; acc[1][1] += a.y * bq.y; acc[1][2] += a.y * bq.z; acc[1][3] += a.y * bq.w;
            acc[2][0] += a.z * bq.x; acc[2][1] += a.z * bq.y; acc[2][2] += a.z * bq.z; acc[2][3] += a.z * bq.w;
            acc[3][0] += a.w * bq.x; acc[3][1] += a.w * bq.y; acc[3][2] += a.w * bq.z; acc[3][3] += a.w * bq.w;
        }
    }

#pragma unroll
    for (int i = 0; i < 4; ++i) {
        const int gm = bm * 64 + (ty << 2) + i;
#pragma unroll
        for (int j = 0; j < 4; ++j) {
            const int gn = bn * 64 + (tx << 2) + j;
            const float v = acc[i][j];
            if (gn < DINNER) xc_raw[(size_t)gm * DINNER + gn] = v;
            else             zbuf  [(size_t)gm * DINNER + gn - DINNER] = v;
        }
    }
}

// ---------------------------------------------------------------------------
// K2: causal depthwise conv1d (K=4, left pad 3) + bias + SiLU
// ---------------------------------------------------------------------------
__global__ __launch_bounds__(256) void k_conv(
    const float* __restrict__ xc_raw, const float* __restrict__ cw,
    const float* __restrict__ cb, float* __restrict__ xc_act)
{
    const int idx = blockIdx.x * 256 + threadIdx.x;   // < 4096*1024
    const int m = idx >> 10, d = idx & 1023;
    const int l = m & 2047;   // within-batch position
    float s = cb[d];
#pragma unroll
    for (int k = 0; k < 4; ++k) {
        const int ll = l - 3 + k;
        if (ll >= 0) s += cw[d * 4 + k] * xc_raw[(size_t)(m - 3 + k) * DINNER + d];
    }
    xc_act[idx] = silu_f(s);
}

// ---------------------------------------------------------------------------
// K3: dbc[m][n] = sum_k xc_act[m][k] * x_proj_w[n][k],  N=64, K=1024
// block: 4 rows x 64 cols
// ---------------------------------------------------------------------------
__global__ __launch_bounds__(256) void k_xproj(
    const float* __restrict__ xc_act, const float* __restrict__ Wx,
    float* __restrict__ dbc)
{
    __shared__ float xr[4][DINNER];
    const int t = threadIdx.x;
    const int m0 = blockIdx.x * 4;
    for (int q = t; q < 4 * DINNER; q += 256)
        xr[q >> 10][q & 1023] = xc_act[(size_t)m0 * DINNER + q];
    __syncthreads();
    const int rr = t >> 6, n = t & 63;
    const float* wr = Wx + (size_t)n * DINNER;
    float s = 0.f;
    for (int k = 0; k < DINNER; k += 4) {
        float4 wv = *(const float4*)(wr + k);
        s += xr[rr][k]     * wv.x;
        s += xr[rr][k + 1] * wv.y;
        s += xr[rr][k + 2] * wv.z;
        s += xr[rr][k + 3] * wv.w;
    }
    dbc[(size_t)(m0 + rr) * 64 + n] = s;
}

// ---------------------------------------------------------------------------
// K4: delta[m][d] = softplus( sum_r dbc[m][r]*dt_w[d][r] + dt_b[d] ), K=32
// ---------------------------------------------------------------------------
__global__ __launch_bounds__(256) void k_dtproj(
    const float* __restrict__ dbc, const float* __restrict__ dtw,
    const float* __restrict__ dtb, float* __restrict__ delta)
{
    __shared__ float dr[DTRANK];
    const int blk = blockIdx.x;      // 4096*4
    const int m = blk >> 2;
    const int d = ((blk & 3) << 8) + threadIdx.x;
    if (threadIdx.x < DTRANK) dr[threadIdx.x] = dbc[(size_t)m * 64 + threadIdx.x];
    __syncthreads();
    const float* wr = dtw + (size_t)d * DTRANK;
    float s = dtb[d];
#pragma unroll
    for (int r0 = 0; r0 < DTRANK; r0 += 4) {
        float4 wv = *(const float4*)(wr + r0);
        s += dr[r0]     * wv.x;
        s += dr[r0 + 1] * wv.y;
        s += dr[r0 + 2] * wv.z;
        s += dr[r0 + 3] * wv.w;
    }
    const float sp = (s > 20.f) ? s : log1pf(__expf(s));
    delta[(size_t)m * DINNER + d] = sp;
}

// ---------------------------------------------------------------------------
// K5: segmented scan, phase A: per (seg g, b, d) run recurrence with h_in=0,
// store final h and prod(dA) per state.  q = g*2048 + b*1024 + d
// ---------------------------------------------------------------------------
__global__ __launch_bounds__(256) void k_scan_partial(
    const float* __restrict__ delta, const float* __restrict__ xc_act,
    const float* __restrict__ dbc, const float* __restrict__ A_log,
    float* __restrict__ hfin, float* __restrict__ aprod)
{
    const int q = blockIdx.x * 256 + threadIdx.x;   // 16384
    const int g = q >> 11;
    const int bd = q & 2047;
    const int b = bd >> 10, d = bd & 1023;

    float Af[DSTATE];
#pragma unroll
    for (int s = 0; s < DSTATE; ++s) Af[s] = -__expf(A_log[d * DSTATE + s]);

    float h[DSTATE], ap[DSTATE];
#pragma unroll
    for (int s = 0; s < DSTATE; ++s) { h[s] = 0.f; ap[s] = 1.f; }

    const int mbase = b * LL + g * SEGLEN;
    for (int ll = 0; ll < SEGLEN; ++ll) {
        const int m = mbase + ll;
        const float de = delta[(size_t)m * DINNER + d];
        const float x  = xc_act[(size_t)m * DINNER + d];
        const float dx = de * x;
        const float* bc = dbc + (size_t)m * 64;
        float4 B0 = *(const float4*)(bc + 32);
        float4 B1 = *(const float4*)(bc + 36);
        float4 B2 = *(const float4*)(bc + 40);
        float4 B3 = *(const float4*)(bc + 44);
        float Bv[16] = {B0.x,B0.y,B0.z,B0.w, B1.x,B1.y,B1.z,B1.w,
                        B2.x,B2.y,B2.z,B2.w, B3.x,B3.y,B3.z,B3.w};
#pragma unroll
        for (int s = 0; s < DSTATE; ++s) {
            const float dA = __expf(de * Af[s]);
            ap[s] *= dA;
            h[s] = dA * h[s] + dx * Bv[s];
        }
    }
    float* hp = hfin  + (size_t)q * DSTATE;
    float* pp = aprod + (size_t)q * DSTATE;
#pragma unroll
    for (int s = 0; s < DSTATE; ++s) { hp[s] = h[s]; pp[s] = ap[s]; }
}

// ---------------------------------------------------------------------------
// K6: phase B: sequential combine over segments; store incoming state per seg
// ---------------------------------------------------------------------------
__global__ __launch_bounds__(256) void k_scan_combine(
    const float* __restrict__ hfin, const float* __restrict__ aprod,
    float* __restrict__ hin)
{
    const int bd = blockIdx.x * 256 + threadIdx.x;  // 2048
    float h[DSTATE];
#pragma unroll
    for (int s = 0; s < DSTATE; ++s) h[s] = 0.f;
    for (int g = 0; g < NSEG; ++g) {
        const size_t o = ((size_t)g * 2048 + bd) * DSTATE;
#pragma unroll
        for (int s = 0; s < DSTATE; ++s) {
            hin[o + s] = h[s];
            h[s] = aprod[o + s] * h[s] + hfin[o + s];
        }
    }
}

// ---------------------------------------------------------------------------
// K7: phase C: re-run recurrence with correct h_in, produce yz = (y + D*x)*silu(z)
// ---------------------------------------------------------------------------
__global__ __launch_bounds__(256) void k_scan_final(
    const float* __restrict__ delta, const float* __restrict__ xc_act,
    const float* __restrict__ dbc, const float* __restrict__ A_log,
    const float* __restrict__ Dp, const float* __restrict__ zbuf,
    const float* __restrict__ hin, float* __restrict__ yz)
{
    const int q = blockIdx.x * 256 + threadIdx.x;
    const int g = q >> 11;
    const int bd = q & 2047;
    const int b = bd >> 10, d = bd & 1023;

    float Af[DSTATE];
#pragma unroll
    for (int s = 0; s < DSTATE; ++s) Af[s] = -__expf(A_log[d * DSTATE + s]);

    float h[DSTATE];
    const float* hp = hin + (size_t)q * DSTATE;
#pragma unroll
    for (int s = 0; s < DSTATE; ++s) h[s] = hp[s];

    const float Dd = Dp[d];
    const int mbase = b * LL + g * SEGLEN;
    for (int ll = 0; ll < SEGLEN; ++ll) {
        const int m = mbase + ll;
        const float de = delta[(size_t)m * DINNER + d];
        const float x  = xc_act[(size_t)m * DINNER + d];
        const float dx = de * x;
        const float* bc = dbc + (size_t)m * 64;
        float4 B0 = *(const float4*)(bc + 32);
        float4 B1 = *(const float4*)(bc + 36);
        float4 B2 = *(const float4*)(bc + 40);
        float4 B3 = *(const float4*)(bc + 44);
        float4 C0 = *(const float4*)(bc + 48);
        float4 C1 = *(const float4*)(bc + 52);
        float4 C2 = *(const float4*)(bc + 56);
        float4 C3 = *(const float4*)(bc + 60);
        float Bv[16] = {B0.x,B0.y,B0.z,B0.w, B1.x,B1.y,B1.z,B1.w,
                        B2.x,B2.y,B2.z,B2.w, B3.x,B3.y,B3.z,B3.w};
        float Cv[16] = {C0.x,C0.y,C0.z,C0.w, C1.x,C1.y,C1.z,C1.w,
                        C2.x,C2.y,C2.z,C2.w, C3.x,C3.y,C3.z,C3.w};
        float y = 0.f;
#pragma unroll
        for (int s = 0; s < DSTATE; ++s) {
            const float dA = __expf(de * Af[s]);
            h[s] = dA * h[s] + dx * Bv[s];
            y += h[s] * Cv[s];
        }
        y += Dd * x;
        const float zz = zbuf[(size_t)m * DINNER + d];
        yz[(size_t)m * DINNER + d] = y * silu_f(zz);
    }
}

// ---------------------------------------------------------------------------
// K8: out_proj GEMM + de-interleave scatter + residual add.
// out[m][n] = sum_k yz[m][k] * Wo[n][k];  M=4096, N=512, K=1024
// res_i[b,j,n] = out[b, i+4j, n] + t_i[b,j,n]
// ---------------------------------------------------------------------------
__global__ __launch_bounds__(256) void k_outproj(
    const float* __restrict__ yz, const float* __restrict__ Wo,
    const float* __restrict__ t0, const float* __restrict__ t1,
    const float* __restrict__ t2, const float* __restrict__ t3,
    float* __restrict__ outp)
{
    __shared__ float As[16][64];
    __shared__ float Bs[16][64];
    const int t  = threadIdx.x;
    const int tx = t & 15, ty = t >> 4;
    const int bm = blockIdx.x, bn = blockIdx.y;
    const int lrow = t & 63;
    const int lkk  = (t >> 6) << 2;

    const float* asrc = yz + (size_t)(bm * 64 + lrow) * DINNER;
    const float* bsrc = Wo + (size_t)(bn * 64 + lrow) * DINNER;

    float acc[4][4] = {};

    for (int k0 = 0; k0 < DINNER; k0 += 16) {
        float4 av = *(const float4*)(asrc + k0 + lkk);
        float4 bv = *(const float4*)(bsrc + k0 + lkk);
        __syncthreads();
        As[lkk + 0][lrow] = av.x;
        As[lkk + 1][lrow] = av.y;
        As[lkk + 2][lrow] = av.z;
        As[lkk + 3][lrow] = av.w;
        Bs[lkk + 0][lrow] = bv.x;
        Bs[lkk + 1][lrow] = bv.y;
        Bs[lkk + 2][lrow] = bv.z;
        Bs[lkk + 3][lrow] = bv.w;
        __syncthreads();
#pragma unroll
        for (int kk = 0; kk < 16; ++kk) {
            float4 a  = *(const float4*)&As[kk][ty << 2];
            float4 bq = *(const float4*)&Bs[kk][tx << 2];
            acc[0][0] += a.x * bq.x; acc[0][1] += a.x * bq.y; acc[0][2] += a.x * bq.z; acc[0][3] += a.x * bq.w;
            acc[1][0] += a.y * bq.x; acc[1][1] += a.y * bq.y; acc[1][2] += a.y * bq.z; acc[1][3] += a.y * bq.w;
            acc[2][0] += a.z * bq.x; acc[2][1] += a.z * bq.y; acc[2][2] += a.z * bq.z; acc[2][3] += a.z * bq.w;
            acc[3][0] += a.w * bq.x; acc[3][1] += a.w * bq.y; acc[3][2] += a.w * bq.z; acc[3][3] += a.w * bq.w;
        }
    }

#pragma unroll
    for (int i = 0; i < 4; ++i) {
        const int gm = bm * 64 + (ty << 2) + i;
        const int b = gm >> 11;
        const int l = gm & 2047;
        const int ii = l & 3;
        const int jj = l >> 2;
        const float* tsel = (ii == 0) ? t0 : (ii == 1) ? t1 : (ii == 2) ? t2 : t3;
#pragma unroll
        for (int j = 0; j < 4; ++j) {
            const int gn = bn * 64 + (tx << 2) + j;
            const float tv = tsel[((size_t)b * 512 + jj) * 512 + gn];
            outp[(((size_t)ii * NB + b) * 512 + jj) * 512 + gn] = acc[i][j] + tv;
        }
    }
}

// ---------------------------------------------------------------------------
extern "C" void kernel_launch(void* const* d_in, const int* in_sizes, int n_in,
                              void* d_out, int out_size, void* d_ws, size_t ws_size,
                              hipStream_t stream)
{
    const float* t0 = (const float*)d_in[0];
    const float* t1 = (const float*)d_in[1];
    const float* t2 = (const float*)d_in[2];
    const float* t3 = (const float*)d_in[3];
    const float* in_proj_w  = (const float*)d_in[4];
    const float* conv_w     = (const float*)d_in[5];
    const float* conv_b     = (const float*)d_in[6];
    const float* x_proj_w   = (const float*)d_in[7];
    const float* dt_w       = (const float*)d_in[8];
    const float* dt_b       = (const float*)d_in[9];
    const float* A_log      = (const float*)d_in[10];
    const float* D_param    = (const float*)d_in[11];
    const float* out_proj_w = (const float*)d_in[12];
    float* outp = (float*)d_out;

    // workspace carve (fp32), yz aliases xc_raw (xc_raw dead after conv)
    float* xc_raw = (float*)d_ws;                          // 4096*1024
    float* zbuf   = xc_raw + (size_t)MM * DINNER;          // 4096*1024
    float* xc_act = zbuf   + (size_t)MM * DINNER;          // 4096*1024
    float* delta  = xc_act + (size_t)MM * DINNER;          // 4096*1024
    float* dbc    = delta  + (size_t)MM * DINNER;          // 4096*64
    float* hfin   = dbc    + (size_t)MM * 64;              // 16384*16
    float* aprod  = hfin   + (size_t)16384 * DSTATE;       // 16384*16
    float* hin    = aprod  + (size_t)16384 * DSTATE;       // 16384*16
    float* yz     = xc_raw;                                // alias

    k_inproj<<<dim3(64, 32), 256, 0, stream>>>(t0, t1, t2, t3, in_proj_w, xc_raw, zbuf);
    k_conv<<<(MM * DINNER) / 256, 256, 0, stream>>>(xc_raw, conv_w, conv_b, xc_act);
    k_xproj<<<MM / 4, 256, 0, stream>>>(xc_act, x_proj_w, dbc);
    k_dtproj<<<MM * 4, 256, 0, stream>>>(dbc, dt_w, dt_b, delta);
    k_scan_partial<<<64, 256, 0, stream>>>(delta, xc_act, dbc, A_log, hfin, aprod);
    k_scan_combine<<<8, 256, 0, stream>>>(hfin, aprod, hin);
    k_scan_final<<<64, 256, 0, stream>>>(delta, xc_act, dbc, A_log, D_param, zbuf, hin, yz);
    k_outproj<<<dim3(64, 8), 256, 0, stream>>>(yz, out_proj_w, t0, t1, t2, t3, outp);
}

// Round 3
// 524.557 us; speedup vs baseline: 1.6676x; 1.6676x over previous
//
#include <hip/hip_runtime.h>

// ---- problem constants ----
#define NB 2          // batch
#define LT 512        // per-tensor seq len
#define LL 2048       // concatenated seq len
#define MM 4096       // NB*LL rows
#define DMODEL 512
#define DINNER 1024
#define DTRANK 32
#define DSTATE 16
#define NSEG 16
#define SEGLEN 128    // NSEG*SEGLEN == LL
#define NQ (NSEG * NB * DINNER * DSTATE)   // 524288 scan threads

__device__ __forceinline__ float silu_f(float x) { return x / (1.f + __expf(-x)); }

// ---------------------------------------------------------------------------
// K1: fused interleaved gather + in_proj GEMM.
// C[m][n] = sum_k x[m][k] * W[n][k],  M=4096, N=2048, K=512
// writes n<1024 -> xc_raw, n>=1024 -> zbuf  (fp32)
// ---------------------------------------------------------------------------
__global__ __launch_bounds__(256) void k_inproj(
    const float* __restrict__ t0, const float* __restrict__ t1,
    const float* __restrict__ t2, const float* __restrict__ t3,
    const float* __restrict__ W,
    float* __restrict__ xc_raw, float* __restrict__ zbuf)
{
    __shared__ float As[16][64];
    __shared__ float Bs[16][64];
    const int t  = threadIdx.x;
    const int tx = t & 15, ty = t >> 4;
    const int bm = blockIdx.x, bn = blockIdx.y;

    const int lrow = t & 63;
    const int lkk  = (t >> 6) << 2;

    // gather: chunk c = l>>7 (0..15): tensor ti = c&3, offset i = c>>2; elem r = l&127
    const int arow = bm * 64 + lrow;
    const int b = arow >> 11;
    const int l = arow & 2047;
    const int c = l >> 7, r = l & 127;
    const int ti = c & 3, ci = c >> 2;
    const float* tp = (ti == 0) ? t0 : (ti == 1) ? t1 : (ti == 2) ? t2 : t3;
    const float* asrc = tp + ((size_t)b * 512 + (size_t)(ci + 4 * r)) * 512;
    const float* bsrc = W + (size_t)(bn * 64 + lrow) * 512;

    float acc[4][4] = {};

    for (int k0 = 0; k0 < 512; k0 += 16) {
        float4 av = *(const float4*)(asrc + k0 + lkk);
        float4 bv = *(const float4*)(bsrc + k0 + lkk);
        __syncthreads();
        As[lkk + 0][lrow] = av.x;
        As[lkk + 1][lrow] = av.y;
        As[lkk + 2][lrow] = av.z;
        As[lkk + 3][lrow] = av.w;
        Bs[lkk + 0][lrow] = bv.x;
        Bs[lkk + 1][lrow] = bv.y;
        Bs[lkk + 2][lrow] = bv.z;
        Bs[lkk + 3][lrow] = bv.w;
        __syncthreads();
#pragma unroll
        for (int kk = 0; kk < 16; ++kk) {
            float4 a  = *(const float4*)&As[kk][ty << 2];
            float4 bq = *(const float4*)&Bs[kk][tx << 2];
            acc[0][0] += a.x * bq.x; acc[0][1] += a.x * bq.y; acc[0][2] += a.x * bq.z; acc[0][3] += a.x * bq.w;
            acc[1][0] += a.y * bq.x; acc[1][1] += a.y * bq.y; acc[1][2] += a.y * bq.z; acc[1][3] += a.y * bq.w;
            acc[2][0] += a.z * bq.x; acc[2][1] += a.z * bq.y; acc[2][2] += a.z * bq.z; acc[2][3] += a.z * bq.w;
            acc[3][0] += a.w * bq.x; acc[3][1] += a.w * bq.y; acc[3][2] += a.w * bq.z; acc[3][3] += a.w * bq.w;
        }
    }

#pragma unroll
    for (int i = 0; i < 4; ++i) {
        const int gm = bm * 64 + (ty << 2) + i;
#pragma unroll
        for (int j = 0; j < 4; ++j) {
            const int gn = bn * 64 + (tx << 2) + j;
            const float v = acc[i][j];
            if (gn < DINNER) xc_raw[(size_t)gm * DINNER + gn] = v;
            else             zbuf  [(size_t)gm * DINNER + gn - DINNER] = v;
        }
    }
}

// ---------------------------------------------------------------------------
// K2: causal depthwise conv1d (K=4, left pad 3) + bias + SiLU
// ---------------------------------------------------------------------------
__global__ __launch_bounds__(256) void k_conv(
    const float* __restrict__ xc_raw, const float* __restrict__ cw,
    const float* __restrict__ cb, float* __restrict__ xc_act)
{
    const int idx = blockIdx.x * 256 + threadIdx.x;   // < 4096*1024
    const int m = idx >> 10, d = idx & 1023;
    const int l = m & 2047;   // within-batch position
    float s = cb[d];
#pragma unroll
    for (int k = 0; k < 4; ++k) {
        const int ll = l - 3 + k;
        if (ll >= 0) s += cw[d * 4 + k] * xc_raw[(size_t)(m - 3 + k) * DINNER + d];
    }
    xc_act[idx] = silu_f(s);
}

// ---------------------------------------------------------------------------
// K3: dbc[m][n] = sum_k xc_act[m][k] * x_proj_w[n][k],  N=64, K=1024
// ---------------------------------------------------------------------------
__global__ __launch_bounds__(256) void k_xproj(
    const float* __restrict__ xc_act, const float* __restrict__ Wx,
    float* __restrict__ dbc)
{
    __shared__ float xr[4][DINNER];
    const int t = threadIdx.x;
    const int m0 = blockIdx.x * 4;
    for (int q = t; q < 4 * DINNER; q += 256)
        xr[q >> 10][q & 1023] = xc_act[(size_t)m0 * DINNER + q];
    __syncthreads();
    const int rr = t >> 6, n = t & 63;
    const float* wr = Wx + (size_t)n * DINNER;
    float s = 0.f;
    for (int k = 0; k < DINNER; k += 4) {
        float4 wv = *(const float4*)(wr + k);
        s += xr[rr][k]     * wv.x;
        s += xr[rr][k + 1] * wv.y;
        s += xr[rr][k + 2] * wv.z;
        s += xr[rr][k + 3] * wv.w;
    }
    dbc[(size_t)(m0 + rr) * 64 + n] = s;
}

// ---------------------------------------------------------------------------
// K4: delta[m][d] = softplus( sum_r dbc[m][r]*dt_w[d][r] + dt_b[d] ), K=32
// ---------------------------------------------------------------------------
__global__ __launch_bounds__(256) void k_dtproj(
    const float* __restrict__ dbc, const float* __restrict__ dtw,
    const float* __restrict__ dtb, float* __restrict__ delta)
{
    __shared__ float dr[DTRANK];
    const int blk = blockIdx.x;      // 4096*4
    const int m = blk >> 2;
    const int d = ((blk & 3) << 8) + threadIdx.x;
    if (threadIdx.x < DTRANK) dr[threadIdx.x] = dbc[(size_t)m * 64 + threadIdx.x];
    __syncthreads();
    const float* wr = dtw + (size_t)d * DTRANK;
    float s = dtb[d];
#pragma unroll
    for (int r0 = 0; r0 < DTRANK; r0 += 4) {
        float4 wv = *(const float4*)(wr + r0);
        s += dr[r0]     * wv.x;
        s += dr[r0 + 1] * wv.y;
        s += dr[r0 + 2] * wv.z;
        s += dr[r0 + 3] * wv.w;
    }
    const float sp = (s > 20.f) ? s : log1pf(__expf(s));
    delta[(size_t)m * DINNER + d] = sp;
}

// ---------------------------------------------------------------------------
// K5: scan phase A: one thread per (g, b, d, s). gid = ((g*NB+b)*DINNER+d)*16+s
// Runs segment recurrence with h_in=0; stores final h and prod(dA), both
// laid out [g][b][d][s] == gid order (coalesced).
// ---------------------------------------------------------------------------
__global__ __launch_bounds__(256) void k_scan_partial(
    const float* __restrict__ delta, const float* __restrict__ xc_act,
    const float* __restrict__ dbc, const float* __restrict__ A_log,
    float* __restrict__ hfin, float* __restrict__ aprod)
{
    const int gid = blockIdx.x * 256 + threadIdx.x;   // < NQ
    const int s = gid & 15;
    const int d = (gid >> 4) & 1023;
    const int b = (gid >> 14) & (NB - 1);
    const int g = gid >> 15;

    const float Af = -__expf(A_log[d * DSTATE + s]);

    float h = 0.f, ap = 1.f;
    const int mbase = b * LL + g * SEGLEN;
    for (int ll = 0; ll < SEGLEN; ++ll) {
        const int m = mbase + ll;
        const float de = delta[(size_t)m * DINNER + d];
        const float x  = xc_act[(size_t)m * DINNER + d];
        const float Bv = dbc[(size_t)m * 64 + 32 + s];
        const float dA = __expf(de * Af);
        ap *= dA;
        h = dA * h + de * x * Bv;
    }
    hfin[gid]  = h;
    aprod[gid] = ap;
}

// ---------------------------------------------------------------------------
// K6: combine across segments, one thread per (b,d,s).  In-place: hfin[g]
// is overwritten with the INCOMING state for segment g.
// ---------------------------------------------------------------------------
__global__ __launch_bounds__(256) void k_scan_combine(
    float* __restrict__ hfin, const float* __restrict__ aprod)
{
    const int tid = blockIdx.x * 256 + threadIdx.x;   // < NB*DINNER*DSTATE = 32768
    float h = 0.f;
#pragma unroll
    for (int g = 0; g < NSEG; ++g) {
        const size_t o = (size_t)g * (NB * DINNER * DSTATE) + tid;
        const float hseg = hfin[o];
        const float ap   = aprod[o];
        hfin[o] = h;              // h_in for segment g
        h = ap * h + hseg;
    }
}

// ---------------------------------------------------------------------------
// K7: scan phase C: re-run recurrence with correct h_in; y = sum_s h*C via
// 16-lane shfl_xor reduce; lane s==0 writes yz = (y + D*x)*silu(z).
// ---------------------------------------------------------------------------
__global__ __launch_bounds__(256) void k_scan_final(
    const float* __restrict__ delta, const float* __restrict__ xc_act,
    const float* __restrict__ dbc, const float* __restrict__ A_log,
    const float* __restrict__ Dp, const float* __restrict__ zbuf,
    const float* __restrict__ hin, float* __restrict__ yz)
{
    const int gid = blockIdx.x * 256 + threadIdx.x;   // < NQ
    const int s = gid & 15;
    const int d = (gid >> 4) & 1023;
    const int b = (gid >> 14) & (NB - 1);
    const int g = gid >> 15;

    const float Af = -__expf(A_log[d * DSTATE + s]);
    const float Dd = Dp[d];

    float h = hin[gid];
    const int mbase = b * LL + g * SEGLEN;
    for (int ll = 0; ll < SEGLEN; ++ll) {
        const int m = mbase + ll;
        const float de = delta[(size_t)m * DINNER + d];
        const float x  = xc_act[(size_t)m * DINNER + d];
        const float Bv = dbc[(size_t)m * 64 + 32 + s];
        const float Cv = dbc[(size_t)m * 64 + 48 + s];
        const float dA = __expf(de * Af);
        h = dA * h + de * x * Bv;
        float y = h * Cv;
        // reduce over the 16 state lanes
        y += __shfl_xor(y, 1, 16);
        y += __shfl_xor(y, 2, 16);
        y += __shfl_xor(y, 4, 16);
        y += __shfl_xor(y, 8, 16);
        if (s == 0) {
            const float zz = zbuf[(size_t)m * DINNER + d];
            yz[(size_t)m * DINNER + d] = (y + Dd * x) * silu_f(zz);
        }
    }
}

// ---------------------------------------------------------------------------
// K8: out_proj GEMM + de-interleave scatter + residual add.
// ---------------------------------------------------------------------------
__global__ __launch_bounds__(256) void k_outproj(
    const float* __restrict__ yz, const float* __restrict__ Wo,
    const float* __restrict__ t0, const float* __restrict__ t1,
    const float* __restrict__ t2, const float* __restrict__ t3,
    float* __restrict__ outp)
{
    __shared__ float As[16][64];
    __shared__ float Bs[16][64];
    const int t  = threadIdx.x;
    const int tx = t & 15, ty = t >> 4;
    const int bm = blockIdx.x, bn = blockIdx.y;
    const int lrow = t & 63;
    const int lkk  = (t >> 6) << 2;

    const float* asrc = yz + (size_t)(bm * 64 + lrow) * DINNER;
    const float* bsrc = Wo + (size_t)(bn * 64 + lrow) * DINNER;

    float acc[4][4] = {};

    for (int k0 = 0; k0 < DINNER; k0 += 16) {
        float4 av = *(const float4*)(asrc + k0 + lkk);
        float4 bv = *(const float4*)(bsrc + k0 + lkk);
        __syncthreads();
        As[lkk + 0][lrow] = av.x;
        As[lkk + 1][lrow] = av.y;
        As[lkk + 2][lrow] = av.z;
        As[lkk + 3][lrow] = av.w;
        Bs[lkk + 0][lrow] = bv.x;
        Bs[lkk + 1][lrow] = bv.y;
        Bs[lkk + 2][lrow] = bv.z;
        Bs[lkk + 3][lrow] = bv.w;
        __syncthreads();
#pragma unroll
        for (int kk = 0; kk < 16; ++kk) {
            float4 a  = *(const float4*)&As[kk][ty << 2];
            float4 bq = *(const float4*)&Bs[kk][tx << 2];
            acc[0][0] += a.x * bq.x; acc[0][1] += a.x * bq.y; acc[0][2] += a.x * bq.z; acc[0][3] += a.x * bq.w;
            acc[1][0] += a.y * bq.x; acc[1][1] += a.y * bq.y; acc[1][2] += a.y * bq.z; acc[1][3] += a.y * bq.w;
            acc[2][0] += a.z * bq.x; acc[2][1] += a.z * bq.y; acc[2][2] += a.z * bq.z; acc[2][3] += a.z * bq.w;
            acc[3][0] += a.w * bq.x; acc[3][1] += a.w * bq.y; acc[3][2] += a.w * bq.z; acc[3][3] += a.w * bq.w;
        }
    }

#pragma unroll
    for (int i = 0; i < 4; ++i) {
        const int gm = bm * 64 + (ty << 2) + i;
        const int b = gm >> 11;
        const int l = gm & 2047;
        const int ii = l & 3;
        const int jj = l >> 2;
        const float* tsel = (ii == 0) ? t0 : (ii == 1) ? t1 : (ii == 2) ? t2 : t3;
#pragma unroll
        for (int j = 0; j < 4; ++j) {
            const int gn = bn * 64 + (tx << 2) + j;
            const float tv = tsel[((size_t)b * 512 + jj) * 512 + gn];
            outp[(((size_t)ii * NB + b) * 512 + jj) * 512 + gn] = acc[i][j] + tv;
        }
    }
}

// ---------------------------------------------------------------------------
extern "C" void kernel_launch(void* const* d_in, const int* in_sizes, int n_in,
                              void* d_out, int out_size, void* d_ws, size_t ws_size,
                              hipStream_t stream)
{
    const float* t0 = (const float*)d_in[0];
    const float* t1 = (const float*)d_in[1];
    const float* t2 = (const float*)d_in[2];
    const float* t3 = (const float*)d_in[3];
    const float* in_proj_w  = (const float*)d_in[4];
    const float* conv_w     = (const float*)d_in[5];
    const float* conv_b     = (const float*)d_in[6];
    const float* x_proj_w   = (const float*)d_in[7];
    const float* dt_w       = (const float*)d_in[8];
    const float* dt_b       = (const float*)d_in[9];
    const float* A_log      = (const float*)d_in[10];
    const float* D_param    = (const float*)d_in[11];
    const float* out_proj_w = (const float*)d_in[12];
    float* outp = (float*)d_out;

    // workspace carve (fp32), yz aliases xc_raw (xc_raw dead after conv)
    float* xc_raw = (float*)d_ws;                          // 4096*1024
    float* zbuf   = xc_raw + (size_t)MM * DINNER;          // 4096*1024
    float* xc_act = zbuf   + (size_t)MM * DINNER;          // 4096*1024
    float* delta  = xc_act + (size_t)MM * DINNER;          // 4096*1024
    float* dbc    = delta  + (size_t)MM * DINNER;          // 4096*64
    float* hfin   = dbc    + (size_t)MM * 64;              // NQ
    float* aprod  = hfin   + (size_t)NQ;                   // NQ
    float* yz     = xc_raw;                                // alias

    k_inproj<<<dim3(64, 32), 256, 0, stream>>>(t0, t1, t2, t3, in_proj_w, xc_raw, zbuf);
    k_conv<<<(MM * DINNER) / 256, 256, 0, stream>>>(xc_raw, conv_w, conv_b, xc_act);
    k_xproj<<<MM / 4, 256, 0, stream>>>(xc_act, x_proj_w, dbc);
    k_dtproj<<<MM * 4, 256, 0, stream>>>(dbc, dt_w, dt_b, delta);
    k_scan_partial<<<NQ / 256, 256, 0, stream>>>(delta, xc_act, dbc, A_log, hfin, aprod);
    k_scan_combine<<<(NB * DINNER * DSTATE) / 256, 256, 0, stream>>>(hfin, aprod);
    k_scan_final<<<NQ / 256, 256, 0, stream>>>(delta, xc_act, dbc, A_log, D_param, zbuf, hfin, yz);
    k_outproj<<<dim3(64, 8), 256, 0, stream>>>(yz, out_proj_w, t0, t1, t2, t3, outp);
}

// Round 4
// 400.253 us; speedup vs baseline: 2.1855x; 1.3106x over previous
//
#include <hip/hip_runtime.h>

// ---- problem constants ----
#define NB 2          // batch
#define LT 512        // per-tensor seq len
#define LL 2048       // concatenated seq len
#define MM 4096       // NB*LL rows
#define DMODEL 512
#define DINNER 1024
#define DTRANK 32
#define DSTATE 16
#define NSEG 16
#define SEGLEN 128    // NSEG*SEGLEN == LL
#define NQ (NSEG * NB * DINNER * DSTATE)   // 524288 scan threads

typedef short bf16x8 __attribute__((ext_vector_type(8)));
typedef float f32x4  __attribute__((ext_vector_type(4)));

__device__ __forceinline__ float silu_f(float x) { return x / (1.f + __expf(-x)); }
__device__ __forceinline__ short f2b(float f) {
    unsigned u = __float_as_uint(f);
    u += 0x7fffu + ((u >> 16) & 1u);   // RNE
    return (short)(u >> 16);
}

// ---------------------------------------------------------------------------
// K1: fused interleaved gather + in_proj GEMM (bf16 MFMA).
// C[m][n] = sum_k x[m][k] * W[n][k],  M=4096, N=2048, K=512
// 128x128 tile, BK=32, 4 waves (2x2), 64x64 per wave, reg-staged fp32->bf16.
// n<1024 -> xc_raw, n>=1024 -> zbuf (block-uniform: bn<8 vs bn>=8)
// ---------------------------------------------------------------------------
__global__ __launch_bounds__(256) void k_inproj(
    const float* __restrict__ t0, const float* __restrict__ t1,
    const float* __restrict__ t2, const float* __restrict__ t3,
    const float* __restrict__ W,
    float* __restrict__ xc_raw, float* __restrict__ zbuf)
{
    __shared__ short As[128 * 40];   // 32 cols + 8 pad (80B row stride)
    __shared__ short Bs[128 * 40];
    const int t = threadIdx.x;
    const int lane = t & 63;
    const int wid = t >> 6;
    const int wm = wid >> 1, wn = wid & 1;
    const int bm = blockIdx.x, bn = blockIdx.y;

    const int srow  = t >> 1;          // 0..127 staging row
    const int shalf = (t & 1) * 16;    // 0 or 16 (col offset)

    // gather: arow -> tensors[c&3][b, (c>>2) + 4*r, :], c=l>>7, r=l&127
    const int arow = bm * 128 + srow;
    const int gb = arow >> 11;
    const int gl = arow & 2047;
    const int gc = gl >> 7, gr = gl & 127;
    const int ti = gc & 3, ci = gc >> 2;
    const float* tp = (ti == 0) ? t0 : (ti == 1) ? t1 : (ti == 2) ? t2 : t3;
    const float* asrc = tp + ((size_t)gb * 512 + (size_t)(ci + 4 * gr)) * 512 + shalf;
    const float* bsrc = W + (size_t)(bn * 128 + srow) * 512 + shalf;

    f32x4 acc[4][4];
#pragma unroll
    for (int i = 0; i < 4; ++i)
#pragma unroll
        for (int j = 0; j < 4; ++j) acc[i][j] = (f32x4){0.f, 0.f, 0.f, 0.f};

    float4 ra[4], rb[4];
#pragma unroll
    for (int q = 0; q < 4; ++q) {
        ra[q] = *(const float4*)(asrc + q * 4);
        rb[q] = *(const float4*)(bsrc + q * 4);
    }

    const int ko = (lane >> 4) * 8;    // k-offset (shorts) within 32-col window
    const int fr = lane & 15;

    for (int ks = 0; ks < 512 / 32; ++ks) {
        __syncthreads();
        {
            bf16x8 v0, v1, w0, w1;
            v0[0]=f2b(ra[0].x); v0[1]=f2b(ra[0].y); v0[2]=f2b(ra[0].z); v0[3]=f2b(ra[0].w);
            v0[4]=f2b(ra[1].x); v0[5]=f2b(ra[1].y); v0[6]=f2b(ra[1].z); v0[7]=f2b(ra[1].w);
            v1[0]=f2b(ra[2].x); v1[1]=f2b(ra[2].y); v1[2]=f2b(ra[2].z); v1[3]=f2b(ra[2].w);
            v1[4]=f2b(ra[3].x); v1[5]=f2b(ra[3].y); v1[6]=f2b(ra[3].z); v1[7]=f2b(ra[3].w);
            w0[0]=f2b(rb[0].x); w0[1]=f2b(rb[0].y); w0[2]=f2b(rb[0].z); w0[3]=f2b(rb[0].w);
            w0[4]=f2b(rb[1].x); w0[5]=f2b(rb[1].y); w0[6]=f2b(rb[1].z); w0[7]=f2b(rb[1].w);
            w1[0]=f2b(rb[2].x); w1[1]=f2b(rb[2].y); w1[2]=f2b(rb[2].z); w1[3]=f2b(rb[2].w);
            w1[4]=f2b(rb[3].x); w1[5]=f2b(rb[3].y); w1[6]=f2b(rb[3].z); w1[7]=f2b(rb[3].w);
            *(bf16x8*)&As[srow * 40 + shalf]     = v0;
            *(bf16x8*)&As[srow * 40 + shalf + 8] = v1;
            *(bf16x8*)&Bs[srow * 40 + shalf]     = w0;
            *(bf16x8*)&Bs[srow * 40 + shalf + 8] = w1;
        }
        __syncthreads();
        if (ks + 1 < 512 / 32) {
            const int k0 = (ks + 1) * 32;
#pragma unroll
            for (int q = 0; q < 4; ++q) {
                ra[q] = *(const float4*)(asrc + k0 + q * 4);
                rb[q] = *(const float4*)(bsrc + k0 + q * 4);
            }
        }
        bf16x8 af[4], bfr[4];
#pragma unroll
        for (int mf = 0; mf < 4; ++mf)
            af[mf] = *(const bf16x8*)&As[(wm * 64 + mf * 16 + fr) * 40 + ko];
#pragma unroll
        for (int nf = 0; nf < 4; ++nf)
            bfr[nf] = *(const bf16x8*)&Bs[(wn * 64 + nf * 16 + fr) * 40 + ko];
#pragma unroll
        for (int mf = 0; mf < 4; ++mf)
#pragma unroll
            for (int nf = 0; nf < 4; ++nf)
                acc[mf][nf] = __builtin_amdgcn_mfma_f32_16x16x32_bf16(
                    af[mf], bfr[nf], acc[mf][nf], 0, 0, 0);
    }

    float* dst = (bn < 8) ? xc_raw : zbuf;
    const int coladj = (bn < 8) ? 0 : 1024;
#pragma unroll
    for (int mf = 0; mf < 4; ++mf) {
        const int gmb = bm * 128 + wm * 64 + mf * 16 + (lane >> 4) * 4;
#pragma unroll
        for (int nf = 0; nf < 4; ++nf) {
            const int gn = bn * 128 + wn * 64 + nf * 16 + (lane & 15) - coladj;
#pragma unroll
            for (int j = 0; j < 4; ++j)
                dst[(size_t)(gmb + j) * DINNER + gn] = acc[mf][nf][j];
        }
    }
}

// ---------------------------------------------------------------------------
// K2: causal depthwise conv1d (K=4, left pad 3) + bias + SiLU
// ---------------------------------------------------------------------------
__global__ __launch_bounds__(256) void k_conv(
    const float* __restrict__ xc_raw, const float* __restrict__ cw,
    const float* __restrict__ cb, float* __restrict__ xc_act)
{
    const int idx = blockIdx.x * 256 + threadIdx.x;   // < 4096*1024
    const int m = idx >> 10, d = idx & 1023;
    const int l = m & 2047;   // within-batch position
    float s = cb[d];
#pragma unroll
    for (int k = 0; k < 4; ++k) {
        const int ll = l - 3 + k;
        if (ll >= 0) s += cw[d * 4 + k] * xc_raw[(size_t)(m - 3 + k) * DINNER + d];
    }
    xc_act[idx] = silu_f(s);
}

// ---------------------------------------------------------------------------
// K3: dbc[m][n] = sum_k xc_act[m][k] * x_proj_w[n][k],  N=64, K=1024
// ---------------------------------------------------------------------------
__global__ __launch_bounds__(256) void k_xproj(
    const float* __restrict__ xc_act, const float* __restrict__ Wx,
    float* __restrict__ dbc)
{
    __shared__ float xr[4][DINNER];
    const int t = threadIdx.x;
    const int m0 = blockIdx.x * 4;
    for (int q = t; q < 4 * DINNER; q += 256)
        xr[q >> 10][q & 1023] = xc_act[(size_t)m0 * DINNER + q];
    __syncthreads();
    const int rr = t >> 6, n = t & 63;
    const float* wr = Wx + (size_t)n * DINNER;
    float s = 0.f;
    for (int k = 0; k < DINNER; k += 4) {
        float4 wv = *(const float4*)(wr + k);
        s += xr[rr][k]     * wv.x;
        s += xr[rr][k + 1] * wv.y;
        s += xr[rr][k + 2] * wv.z;
        s += xr[rr][k + 3] * wv.w;
    }
    dbc[(size_t)(m0 + rr) * 64 + n] = s;
}

// ---------------------------------------------------------------------------
// K4: delta[m][d] = softplus( sum_r dbc[m][r]*dt_w[d][r] + dt_b[d] ), K=32
// ---------------------------------------------------------------------------
__global__ __launch_bounds__(256) void k_dtproj(
    const float* __restrict__ dbc, const float* __restrict__ dtw,
    const float* __restrict__ dtb, float* __restrict__ delta)
{
    __shared__ float dr[DTRANK];
    const int blk = blockIdx.x;      // 4096*4
    const int m = blk >> 2;
    const int d = ((blk & 3) << 8) + threadIdx.x;
    if (threadIdx.x < DTRANK) dr[threadIdx.x] = dbc[(size_t)m * 64 + threadIdx.x];
    __syncthreads();
    const float* wr = dtw + (size_t)d * DTRANK;
    float s = dtb[d];
#pragma unroll
    for (int r0 = 0; r0 < DTRANK; r0 += 4) {
        float4 wv = *(const float4*)(wr + r0);
        s += dr[r0]     * wv.x;
        s += dr[r0 + 1] * wv.y;
        s += dr[r0 + 2] * wv.z;
        s += dr[r0 + 3] * wv.w;
    }
    const float sp = (s > 20.f) ? s : log1pf(__expf(s));
    delta[(size_t)m * DINNER + d] = sp;
}

// ---------------------------------------------------------------------------
// K5: scan phase A: one thread per (g, b, d, s). gid = ((g*NB+b)*DINNER+d)*16+s
// ---------------------------------------------------------------------------
__global__ __launch_bounds__(256) void k_scan_partial(
    const float* __restrict__ delta, const float* __restrict__ xc_act,
    const float* __restrict__ dbc, const float* __restrict__ A_log,
    float* __restrict__ hfin, float* __restrict__ aprod)
{
    const int gid = blockIdx.x * 256 + threadIdx.x;   // < NQ
    const int s = gid & 15;
    const int d = (gid >> 4) & 1023;
    const int b = (gid >> 14) & (NB - 1);
    const int g = gid >> 15;

    const float Af = -__expf(A_log[d * DSTATE + s]);

    float h = 0.f, ap = 1.f;
    const int mbase = b * LL + g * SEGLEN;
    for (int ll = 0; ll < SEGLEN; ++ll) {
        const int m = mbase + ll;
        const float de = delta[(size_t)m * DINNER + d];
        const float x  = xc_act[(size_t)m * DINNER + d];
        const float Bv = dbc[(size_t)m * 64 + 32 + s];
        const float dA = __expf(de * Af);
        ap *= dA;
        h = dA * h + de * x * Bv;
    }
    hfin[gid]  = h;
    aprod[gid] = ap;
}

// ---------------------------------------------------------------------------
// K6: combine across segments, one thread per (b,d,s). In-place h_in rewrite.
// ---------------------------------------------------------------------------
__global__ __launch_bounds__(256) void k_scan_combine(
    float* __restrict__ hfin, const float* __restrict__ aprod)
{
    const int tid = blockIdx.x * 256 + threadIdx.x;   // < 32768
    float h = 0.f;
#pragma unroll
    for (int g = 0; g < NSEG; ++g) {
        const size_t o = (size_t)g * (NB * DINNER * DSTATE) + tid;
        const float hseg = hfin[o];
        const float ap   = aprod[o];
        hfin[o] = h;              // h_in for segment g
        h = ap * h + hseg;
    }
}

// ---------------------------------------------------------------------------
// K7: scan phase C: recurrence with h_in; y via 16-lane shfl_xor reduce.
// ---------------------------------------------------------------------------
__global__ __launch_bounds__(256) void k_scan_final(
    const float* __restrict__ delta, const float* __restrict__ xc_act,
    const float* __restrict__ dbc, const float* __restrict__ A_log,
    const float* __restrict__ Dp, const float* __restrict__ zbuf,
    const float* __restrict__ hin, float* __restrict__ yz)
{
    const int gid = blockIdx.x * 256 + threadIdx.x;   // < NQ
    const int s = gid & 15;
    const int d = (gid >> 4) & 1023;
    const int b = (gid >> 14) & (NB - 1);
    const int g = gid >> 15;

    const float Af = -__expf(A_log[d * DSTATE + s]);
    const float Dd = Dp[d];

    float h = hin[gid];
    const int mbase = b * LL + g * SEGLEN;
    for (int ll = 0; ll < SEGLEN; ++ll) {
        const int m = mbase + ll;
        const float de = delta[(size_t)m * DINNER + d];
        const float x  = xc_act[(size_t)m * DINNER + d];
        const float Bv = dbc[(size_t)m * 64 + 32 + s];
        const float Cv = dbc[(size_t)m * 64 + 48 + s];
        const float dA = __expf(de * Af);
        h = dA * h + de * x * Bv;
        float y = h * Cv;
        y += __shfl_xor(y, 1, 16);
        y += __shfl_xor(y, 2, 16);
        y += __shfl_xor(y, 4, 16);
        y += __shfl_xor(y, 8, 16);
        if (s == 0) {
            const float zz = zbuf[(size_t)m * DINNER + d];
            yz[(size_t)m * DINNER + d] = (y + Dd * x) * silu_f(zz);
        }
    }
}

// ---------------------------------------------------------------------------
// K8: out_proj GEMM (bf16 MFMA) + de-interleave scatter + residual add.
// out[m][n] = sum_k yz[m][k] * Wo[n][k];  M=4096, N=512, K=1024
// ---------------------------------------------------------------------------
__global__ __launch_bounds__(256) void k_outproj(
    const float* __restrict__ yz, const float* __restrict__ Wo,
    const float* __restrict__ t0, const float* __restrict__ t1,
    const float* __restrict__ t2, const float* __restrict__ t3,
    float* __restrict__ outp)
{
    __shared__ short As[128 * 40];
    __shared__ short Bs[128 * 40];
    const int t = threadIdx.x;
    const int lane = t & 63;
    const int wid = t >> 6;
    const int wm = wid >> 1, wn = wid & 1;
    const int bm = blockIdx.x, bn = blockIdx.y;

    const int srow  = t >> 1;
    const int shalf = (t & 1) * 16;

    const float* asrc = yz + (size_t)(bm * 128 + srow) * DINNER + shalf;
    const float* bsrc = Wo + (size_t)(bn * 128 + srow) * DINNER + shalf;

    f32x4 acc[4][4];
#pragma unroll
    for (int i = 0; i < 4; ++i)
#pragma unroll
        for (int j = 0; j < 4; ++j) acc[i][j] = (f32x4){0.f, 0.f, 0.f, 0.f};

    float4 ra[4], rb[4];
#pragma unroll
    for (int q = 0; q < 4; ++q) {
        ra[q] = *(const float4*)(asrc + q * 4);
        rb[q] = *(const float4*)(bsrc + q * 4);
    }

    const int ko = (lane >> 4) * 8;
    const int fr = lane & 15;

    for (int ks = 0; ks < DINNER / 32; ++ks) {
        __syncthreads();
        {
            bf16x8 v0, v1, w0, w1;
            v0[0]=f2b(ra[0].x); v0[1]=f2b(ra[0].y); v0[2]=f2b(ra[0].z); v0[3]=f2b(ra[0].w);
            v0[4]=f2b(ra[1].x); v0[5]=f2b(ra[1].y); v0[6]=f2b(ra[1].z); v0[7]=f2b(ra[1].w);
            v1[0]=f2b(ra[2].x); v1[1]=f2b(ra[2].y); v1[2]=f2b(ra[2].z); v1[3]=f2b(ra[2].w);
            v1[4]=f2b(ra[3].x); v1[5]=f2b(ra[3].y); v1[6]=f2b(ra[3].z); v1[7]=f2b(ra[3].w);
            w0[0]=f2b(rb[0].x); w0[1]=f2b(rb[0].y); w0[2]=f2b(rb[0].z); w0[3]=f2b(rb[0].w);
            w0[4]=f2b(rb[1].x); w0[5]=f2b(rb[1].y); w0[6]=f2b(rb[1].z); w0[7]=f2b(rb[1].w);
            w1[0]=f2b(rb[2].x); w1[1]=f2b(rb[2].y); w1[2]=f2b(rb[2].z); w1[3]=f2b(rb[2].w);
            w1[4]=f2b(rb[3].x); w1[5]=f2b(rb[3].y); w1[6]=f2b(rb[3].z); w1[7]=f2b(rb[3].w);
            *(bf16x8*)&As[srow * 40 + shalf]     = v0;
            *(bf16x8*)&As[srow * 40 + shalf + 8] = v1;
            *(bf16x8*)&Bs[srow * 40 + shalf]     = w0;
            *(bf16x8*)&Bs[srow * 40 + shalf + 8] = w1;
        }
        __syncthreads();
        if (ks + 1 < DINNER / 32) {
            const int k0 = (ks + 1) * 32;
#pragma unroll
            for (int q = 0; q < 4; ++q) {
                ra[q] = *(const float4*)(asrc + k0 + q * 4);
                rb[q] = *(const float4*)(bsrc + k0 + q * 4);
            }
        }
        bf16x8 af[4], bfr[4];
#pragma unroll
        for (int mf = 0; mf < 4; ++mf)
            af[mf] = *(const bf16x8*)&As[(wm * 64 + mf * 16 + fr) * 40 + ko];
#pragma unroll
        for (int nf = 0; nf < 4; ++nf)
            bfr[nf] = *(const bf16x8*)&Bs[(wn * 64 + nf * 16 + fr) * 40 + ko];
#pragma unroll
        for (int mf = 0; mf < 4; ++mf)
#pragma unroll
            for (int nf = 0; nf < 4; ++nf)
                acc[mf][nf] = __builtin_amdgcn_mfma_f32_16x16x32_bf16(
                    af[mf], bfr[nf], acc[mf][nf], 0, 0, 0);
    }

#pragma unroll
    for (int mf = 0; mf < 4; ++mf) {
#pragma unroll
        for (int j = 0; j < 4; ++j) {
            const int gm = bm * 128 + wm * 64 + mf * 16 + (lane >> 4) * 4 + j;
            const int b = gm >> 11;
            const int l = gm & 2047;
            const int ii = l & 3;
            const int jj = l >> 2;
            const float* tsel = (ii == 0) ? t0 : (ii == 1) ? t1 : (ii == 2) ? t2 : t3;
#pragma unroll
            for (int nf = 0; nf < 4; ++nf) {
                const int gn = bn * 128 + wn * 64 + nf * 16 + (lane & 15);
                const float tv = tsel[((size_t)b * 512 + jj) * 512 + gn];
                outp[(((size_t)ii * NB + b) * 512 + jj) * 512 + gn] = acc[mf][nf][j] + tv;
            }
        }
    }
}

// ---------------------------------------------------------------------------
extern "C" void kernel_launch(void* const* d_in, const int* in_sizes, int n_in,
                              void* d_out, int out_size, void* d_ws, size_t ws_size,
                              hipStream_t stream)
{
    const float* t0 = (const float*)d_in[0];
    const float* t1 = (const float*)d_in[1];
    const float* t2 = (const float*)d_in[2];
    const float* t3 = (const float*)d_in[3];
    const float* in_proj_w  = (const float*)d_in[4];
    const float* conv_w     = (const float*)d_in[5];
    const float* conv_b     = (const float*)d_in[6];
    const float* x_proj_w   = (const float*)d_in[7];
    const float* dt_w       = (const float*)d_in[8];
    const float* dt_b       = (const float*)d_in[9];
    const float* A_log      = (const float*)d_in[10];
    const float* D_param    = (const float*)d_in[11];
    const float* out_proj_w = (const float*)d_in[12];
    float* outp = (float*)d_out;

    // workspace carve (fp32), yz aliases xc_raw (xc_raw dead after conv)
    float* xc_raw = (float*)d_ws;                          // 4096*1024
    float* zbuf   = xc_raw + (size_t)MM * DINNER;          // 4096*1024
    float* xc_act = zbuf   + (size_t)MM * DINNER;          // 4096*1024
    float* delta  = xc_act + (size_t)MM * DINNER;          // 4096*1024
    float* dbc    = delta  + (size_t)MM * DINNER;          // 4096*64
    float* hfin   = dbc    + (size_t)MM * 64;              // NQ
    float* aprod  = hfin   + (size_t)NQ;                   // NQ
    float* yz     = xc_raw;                                // alias

    k_inproj<<<dim3(32, 16), 256, 0, stream>>>(t0, t1, t2, t3, in_proj_w, xc_raw, zbuf);
    k_conv<<<(MM * DINNER) / 256, 256, 0, stream>>>(xc_raw, conv_w, conv_b, xc_act);
    k_xproj<<<MM / 4, 256, 0, stream>>>(xc_act, x_proj_w, dbc);
    k_dtproj<<<MM * 4, 256, 0, stream>>>(dbc, dt_w, dt_b, delta);
    k_scan_partial<<<NQ / 256, 256, 0, stream>>>(delta, xc_act, dbc, A_log, hfin, aprod);
    k_scan_combine<<<(NB * DINNER * DSTATE) / 256, 256, 0, stream>>>(hfin, aprod);
    k_scan_final<<<NQ / 256, 256, 0, stream>>>(delta, xc_act, dbc, A_log, D_param, zbuf, hfin, yz);
    k_outproj<<<dim3(32, 4), 256, 0, stream>>>(yz, out_proj_w, t0, t1, t2, t3, outp);
}

// Round 5
// 299.305 us; speedup vs baseline: 2.9227x; 1.3373x over previous
//
#include <hip/hip_runtime.h>

// ---- problem constants ----
#define NB 2          // batch
#define LT 512        // per-tensor seq len
#define LL 2048       // concatenated seq len
#define MM 4096       // NB*LL rows
#define DMODEL 512
#define DINNER 1024
#define DTRANK 32
#define DSTATE 16
#define NSEG 16
#define SEGLEN 128    // NSEG*SEGLEN == LL
#define NQ (NSEG * NB * DINNER * DSTATE)   // 524288 scan threads
#define KCH 8         // xproj K-chunks (split-K)

typedef short bf16x8 __attribute__((ext_vector_type(8)));
typedef float f32x4  __attribute__((ext_vector_type(4)));

__device__ __forceinline__ float silu_f(float x) { return x / (1.f + __expf(-x)); }
__device__ __forceinline__ short f2b(float f) {
    unsigned u = __float_as_uint(f);
    u += 0x7fffu + ((u >> 16) & 1u);   // RNE
    return (short)(u >> 16);
}

// ---------------------------------------------------------------------------
// K1: fused interleaved gather + in_proj GEMM (bf16 MFMA).
// ---------------------------------------------------------------------------
__global__ __launch_bounds__(256) void k_inproj(
    const float* __restrict__ t0, const float* __restrict__ t1,
    const float* __restrict__ t2, const float* __restrict__ t3,
    const float* __restrict__ W,
    float* __restrict__ xc_raw, float* __restrict__ zbuf)
{
    __shared__ short As[128 * 40];   // 32 cols + 8 pad (80B row stride)
    __shared__ short Bs[128 * 40];
    const int t = threadIdx.x;
    const int lane = t & 63;
    const int wid = t >> 6;
    const int wm = wid >> 1, wn = wid & 1;
    const int bm = blockIdx.x, bn = blockIdx.y;

    const int srow  = t >> 1;          // 0..127 staging row
    const int shalf = (t & 1) * 16;    // 0 or 16 (col offset)

    const int arow = bm * 128 + srow;
    const int gb = arow >> 11;
    const int gl = arow & 2047;
    const int gc = gl >> 7, gr = gl & 127;
    const int ti = gc & 3, ci = gc >> 2;
    const float* tp = (ti == 0) ? t0 : (ti == 1) ? t1 : (ti == 2) ? t2 : t3;
    const float* asrc = tp + ((size_t)gb * 512 + (size_t)(ci + 4 * gr)) * 512 + shalf;
    const float* bsrc = W + (size_t)(bn * 128 + srow) * 512 + shalf;

    f32x4 acc[4][4];
#pragma unroll
    for (int i = 0; i < 4; ++i)
#pragma unroll
        for (int j = 0; j < 4; ++j) acc[i][j] = (f32x4){0.f, 0.f, 0.f, 0.f};

    float4 ra[4], rb[4];
#pragma unroll
    for (int q = 0; q < 4; ++q) {
        ra[q] = *(const float4*)(asrc + q * 4);
        rb[q] = *(const float4*)(bsrc + q * 4);
    }

    const int ko = (lane >> 4) * 8;
    const int fr = lane & 15;

    for (int ks = 0; ks < 512 / 32; ++ks) {
        __syncthreads();
        {
            bf16x8 v0, v1, w0, w1;
            v0[0]=f2b(ra[0].x); v0[1]=f2b(ra[0].y); v0[2]=f2b(ra[0].z); v0[3]=f2b(ra[0].w);
            v0[4]=f2b(ra[1].x); v0[5]=f2b(ra[1].y); v0[6]=f2b(ra[1].z); v0[7]=f2b(ra[1].w);
            v1[0]=f2b(ra[2].x); v1[1]=f2b(ra[2].y); v1[2]=f2b(ra[2].z); v1[3]=f2b(ra[2].w);
            v1[4]=f2b(ra[3].x); v1[5]=f2b(ra[3].y); v1[6]=f2b(ra[3].z); v1[7]=f2b(ra[3].w);
            w0[0]=f2b(rb[0].x); w0[1]=f2b(rb[0].y); w0[2]=f2b(rb[0].z); w0[3]=f2b(rb[0].w);
            w0[4]=f2b(rb[1].x); w0[5]=f2b(rb[1].y); w0[6]=f2b(rb[1].z); w0[7]=f2b(rb[1].w);
            w1[0]=f2b(rb[2].x); w1[1]=f2b(rb[2].y); w1[2]=f2b(rb[2].z); w1[3]=f2b(rb[2].w);
            w1[4]=f2b(rb[3].x); w1[5]=f2b(rb[3].y); w1[6]=f2b(rb[3].z); w1[7]=f2b(rb[3].w);
            *(bf16x8*)&As[srow * 40 + shalf]     = v0;
            *(bf16x8*)&As[srow * 40 + shalf + 8] = v1;
            *(bf16x8*)&Bs[srow * 40 + shalf]     = w0;
            *(bf16x8*)&Bs[srow * 40 + shalf + 8] = w1;
        }
        __syncthreads();
        if (ks + 1 < 512 / 32) {
            const int k0 = (ks + 1) * 32;
#pragma unroll
            for (int q = 0; q < 4; ++q) {
                ra[q] = *(const float4*)(asrc + k0 + q * 4);
                rb[q] = *(const float4*)(bsrc + k0 + q * 4);
            }
        }
        bf16x8 af[4], bfr[4];
#pragma unroll
        for (int mf = 0; mf < 4; ++mf)
            af[mf] = *(const bf16x8*)&As[(wm * 64 + mf * 16 + fr) * 40 + ko];
#pragma unroll
        for (int nf = 0; nf < 4; ++nf)
            bfr[nf] = *(const bf16x8*)&Bs[(wn * 64 + nf * 16 + fr) * 40 + ko];
#pragma unroll
        for (int mf = 0; mf < 4; ++mf)
#pragma unroll
            for (int nf = 0; nf < 4; ++nf)
                acc[mf][nf] = __builtin_amdgcn_mfma_f32_16x16x32_bf16(
                    af[mf], bfr[nf], acc[mf][nf], 0, 0, 0);
    }

    float* dst = (bn < 8) ? xc_raw : zbuf;
    const int coladj = (bn < 8) ? 0 : 1024;
#pragma unroll
    for (int mf = 0; mf < 4; ++mf) {
        const int gmb = bm * 128 + wm * 64 + mf * 16 + (lane >> 4) * 4;
#pragma unroll
        for (int nf = 0; nf < 4; ++nf) {
            const int gn = bn * 128 + wn * 64 + nf * 16 + (lane & 15) - coladj;
#pragma unroll
            for (int j = 0; j < 4; ++j)
                dst[(size_t)(gmb + j) * DINNER + gn] = acc[mf][nf][j];
        }
    }
}

// ---------------------------------------------------------------------------
// K2: causal depthwise conv1d (K=4, left pad 3) + bias + SiLU.
// Dual write: xc_act (f32, scan) and xc_b (bf16, xproj A operand).
// ---------------------------------------------------------------------------
__global__ __launch_bounds__(256) void k_conv(
    const float* __restrict__ xc_raw, const float* __restrict__ cw,
    const float* __restrict__ cb, float* __restrict__ xc_act,
    unsigned short* __restrict__ xc_b)
{
    const int idx = blockIdx.x * 256 + threadIdx.x;   // < 4096*1024
    const int m = idx >> 10, d = idx & 1023;
    const int l = m & 2047;   // within-batch position
    float s = cb[d];
#pragma unroll
    for (int k = 0; k < 4; ++k) {
        const int ll = l - 3 + k;
        if (ll >= 0) s += cw[d * 4 + k] * xc_raw[(size_t)(m - 3 + k) * DINNER + d];
    }
    const float a = silu_f(s);
    xc_act[idx] = a;
    xc_b[idx] = (unsigned short)f2b(a);
}

// ---------------------------------------------------------------------------
// K2b: convert x_proj_w (64x1024 f32) -> bf16
// ---------------------------------------------------------------------------
__global__ __launch_bounds__(256) void k_cvt_wx(
    const float* __restrict__ Wx, unsigned short* __restrict__ wxb)
{
    const int i4 = blockIdx.x * 256 + threadIdx.x;    // < 16384
    float4 v = *(const float4*)(Wx + (size_t)i4 * 4);
    ushort4 o;
    o.x = (unsigned short)f2b(v.x);
    o.y = (unsigned short)f2b(v.y);
    o.z = (unsigned short)f2b(v.z);
    o.w = (unsigned short)f2b(v.w);
    *(ushort4*)(wxb + (size_t)i4 * 4) = o;
}

// ---------------------------------------------------------------------------
// K3: xproj split-K MFMA GEMM.  dbc_part[kc][m][n] = sum_{k in chunk} xc[m][k]*Wx[n][k]
// M=4096, N=64, K=1024, 8 chunks of 128.  Block: 128 rows x 64 cols x Kchunk 128.
// ---------------------------------------------------------------------------
__global__ __launch_bounds__(256) void k_xproj_mfma(
    const unsigned short* __restrict__ xc_b, const unsigned short* __restrict__ wxb,
    float* __restrict__ part)
{
    __shared__ short As[128 * 136];   // 128 K-cols + 8 pad
    __shared__ short Bs[64 * 136];
    const int t = threadIdx.x;
    const int lane = t & 63;
    const int w = t >> 6;             // wave 0..3 -> rows w*32
    const int bm = blockIdx.x;        // 0..31
    const int kc = blockIdx.y;        // 0..7

    // stage A: 2 threads/row, 64 shorts each
    {
        const int row = t >> 1;
        const int cb0 = (t & 1) * 64;
        const unsigned short* src = xc_b + (size_t)(bm * 128 + row) * 1024 + kc * 128 + cb0;
#pragma unroll
        for (int q = 0; q < 8; ++q)
            *(bf16x8*)&As[row * 136 + cb0 + q * 8] = *(const bf16x8*)(src + q * 8);
    }
    // stage B: 4 threads/row, 32 shorts each
    {
        const int row = t >> 2;
        const int cb0 = (t & 3) * 32;
        const unsigned short* src = wxb + (size_t)row * 1024 + kc * 128 + cb0;
#pragma unroll
        for (int q = 0; q < 4; ++q)
            *(bf16x8*)&Bs[row * 136 + cb0 + q * 8] = *(const bf16x8*)(src + q * 8);
    }
    __syncthreads();

    const int fr = lane & 15;
    const int ko = (lane >> 4) * 8;

    f32x4 acc[2][4];
#pragma unroll
    for (int i = 0; i < 2; ++i)
#pragma unroll
        for (int j = 0; j < 4; ++j) acc[i][j] = (f32x4){0.f, 0.f, 0.f, 0.f};

#pragma unroll
    for (int ks = 0; ks < 4; ++ks) {
        const int kb = ks * 32 + ko;
        bf16x8 af[2], bfr[4];
#pragma unroll
        for (int mf = 0; mf < 2; ++mf)
            af[mf] = *(const bf16x8*)&As[(w * 32 + mf * 16 + fr) * 136 + kb];
#pragma unroll
        for (int nf = 0; nf < 4; ++nf)
            bfr[nf] = *(const bf16x8*)&Bs[(nf * 16 + fr) * 136 + kb];
#pragma unroll
        for (int mf = 0; mf < 2; ++mf)
#pragma unroll
            for (int nf = 0; nf < 4; ++nf)
                acc[mf][nf] = __builtin_amdgcn_mfma_f32_16x16x32_bf16(
                    af[mf], bfr[nf], acc[mf][nf], 0, 0, 0);
    }

    float* pb = part + (size_t)kc * (MM * 64);
#pragma unroll
    for (int mf = 0; mf < 2; ++mf) {
        const int rb = bm * 128 + w * 32 + mf * 16 + (lane >> 4) * 4;
#pragma unroll
        for (int nf = 0; nf < 4; ++nf) {
            const int col = nf * 16 + (lane & 15);
#pragma unroll
            for (int j = 0; j < 4; ++j)
                pb[(size_t)(rb + j) * 64 + col] = acc[mf][nf][j];
        }
    }
}

// ---------------------------------------------------------------------------
// K3b: reduce split-K partials -> dbc
// ---------------------------------------------------------------------------
__global__ __launch_bounds__(256) void k_xreduce(
    const float* __restrict__ part, float* __restrict__ dbc)
{
    const int i = blockIdx.x * 256 + threadIdx.x;    // < MM*64
    float s = 0.f;
#pragma unroll
    for (int kc = 0; kc < KCH; ++kc)
        s += part[(size_t)kc * (MM * 64) + i];
    dbc[i] = s;
}

// ---------------------------------------------------------------------------
// K4: delta[m][d] = softplus( sum_r dbc[m][r]*dt_w[d][r] + dt_b[d] ), K=32
// ---------------------------------------------------------------------------
__global__ __launch_bounds__(256) void k_dtproj(
    const float* __restrict__ dbc, const float* __restrict__ dtw,
    const float* __restrict__ dtb, float* __restrict__ delta)
{
    __shared__ float dr[DTRANK];
    const int blk = blockIdx.x;      // 4096*4
    const int m = blk >> 2;
    const int d = ((blk & 3) << 8) + threadIdx.x;
    if (threadIdx.x < DTRANK) dr[threadIdx.x] = dbc[(size_t)m * 64 + threadIdx.x];
    __syncthreads();
    const float* wr = dtw + (size_t)d * DTRANK;
    float s = dtb[d];
#pragma unroll
    for (int r0 = 0; r0 < DTRANK; r0 += 4) {
        float4 wv = *(const float4*)(wr + r0);
        s += dr[r0]     * wv.x;
        s += dr[r0 + 1] * wv.y;
        s += dr[r0 + 2] * wv.z;
        s += dr[r0 + 3] * wv.w;
    }
    const float sp = (s > 20.f) ? s : log1pf(__expf(s));
    delta[(size_t)m * DINNER + d] = sp;
}

// ---------------------------------------------------------------------------
// K5: scan phase A: one thread per (g, b, d, s). gid = ((g*NB+b)*DINNER+d)*16+s
// ---------------------------------------------------------------------------
__global__ __launch_bounds__(256) void k_scan_partial(
    const float* __restrict__ delta, const float* __restrict__ xc_act,
    const float* __restrict__ dbc, const float* __restrict__ A_log,
    float* __restrict__ hfin, float* __restrict__ aprod)
{
    const int gid = blockIdx.x * 256 + threadIdx.x;   // < NQ
    const int s = gid & 15;
    const int d = (gid >> 4) & 1023;
    const int b = (gid >> 14) & (NB - 1);
    const int g = gid >> 15;

    const float Af = -__expf(A_log[d * DSTATE + s]);

    float h = 0.f, ap = 1.f;
    const int mbase = b * LL + g * SEGLEN;
    for (int ll = 0; ll < SEGLEN; ++ll) {
        const int m = mbase + ll;
        const float de = delta[(size_t)m * DINNER + d];
        const float x  = xc_act[(size_t)m * DINNER + d];
        const float Bv = dbc[(size_t)m * 64 + 32 + s];
        const float dA = __expf(de * Af);
        ap *= dA;
        h = dA * h + de * x * Bv;
    }
    hfin[gid]  = h;
    aprod[gid] = ap;
}

// ---------------------------------------------------------------------------
// K6: combine across segments, one thread per (b,d,s). In-place h_in rewrite.
// ---------------------------------------------------------------------------
__global__ __launch_bounds__(256) void k_scan_combine(
    float* __restrict__ hfin, const float* __restrict__ aprod)
{
    const int tid = blockIdx.x * 256 + threadIdx.x;   // < 32768
    float h = 0.f;
#pragma unroll
    for (int g = 0; g < NSEG; ++g) {
        const size_t o = (size_t)g * (NB * DINNER * DSTATE) + tid;
        const float hseg = hfin[o];
        const float ap   = aprod[o];
        hfin[o] = h;              // h_in for segment g
        h = ap * h + hseg;
    }
}

// ---------------------------------------------------------------------------
// K7: scan phase C: recurrence with h_in; y via 16-lane shfl_xor reduce.
// ---------------------------------------------------------------------------
__global__ __launch_bounds__(256) void k_scan_final(
    const float* __restrict__ delta, const float* __restrict__ xc_act,
    const float* __restrict__ dbc, const float* __restrict__ A_log,
    const float* __restrict__ Dp, const float* __restrict__ zbuf,
    const float* __restrict__ hin, float* __restrict__ yz)
{
    const int gid = blockIdx.x * 256 + threadIdx.x;   // < NQ
    const int s = gid & 15;
    const int d = (gid >> 4) & 1023;
    const int b = (gid >> 14) & (NB - 1);
    const int g = gid >> 15;

    const float Af = -__expf(A_log[d * DSTATE + s]);
    const float Dd = Dp[d];

    float h = hin[gid];
    const int mbase = b * LL + g * SEGLEN;
    for (int ll = 0; ll < SEGLEN; ++ll) {
        const int m = mbase + ll;
        const float de = delta[(size_t)m * DINNER + d];
        const float x  = xc_act[(size_t)m * DINNER + d];
        const float Bv = dbc[(size_t)m * 64 + 32 + s];
        const float Cv = dbc[(size_t)m * 64 + 48 + s];
        const float dA = __expf(de * Af);
        h = dA * h + de * x * Bv;
        float y = h * Cv;
        y += __shfl_xor(y, 1, 16);
        y += __shfl_xor(y, 2, 16);
        y += __shfl_xor(y, 4, 16);
        y += __shfl_xor(y, 8, 16);
        if (s == 0) {
            const float zz = zbuf[(size_t)m * DINNER + d];
            yz[(size_t)m * DINNER + d] = (y + Dd * x) * silu_f(zz);
        }
    }
}

// ---------------------------------------------------------------------------
// K8: out_proj GEMM (bf16 MFMA) + de-interleave scatter + residual add.
// ---------------------------------------------------------------------------
__global__ __launch_bounds__(256) void k_outproj(
    const float* __restrict__ yz, const float* __restrict__ Wo,
    const float* __restrict__ t0, const float* __restrict__ t1,
    const float* __restrict__ t2, const float* __restrict__ t3,
    float* __restrict__ outp)
{
    __shared__ short As[128 * 40];
    __shared__ short Bs[128 * 40];
    const int t = threadIdx.x;
    const int lane = t & 63;
    const int wid = t >> 6;
    const int wm = wid >> 1, wn = wid & 1;
    const int bm = blockIdx.x, bn = blockIdx.y;

    const int srow  = t >> 1;
    const int shalf = (t & 1) * 16;

    const float* asrc = yz + (size_t)(bm * 128 + srow) * DINNER + shalf;
    const float* bsrc = Wo + (size_t)(bn * 128 + srow) * DINNER + shalf;

    f32x4 acc[4][4];
#pragma unroll
    for (int i = 0; i < 4; ++i)
#pragma unroll
        for (int j = 0; j < 4; ++j) acc[i][j] = (f32x4){0.f, 0.f, 0.f, 0.f};

    float4 ra[4], rb[4];
#pragma unroll
    for (int q = 0; q < 4; ++q) {
        ra[q] = *(const float4*)(asrc + q * 4);
        rb[q] = *(const float4*)(bsrc + q * 4);
    }

    const int ko = (lane >> 4) * 8;
    const int fr = lane & 15;

    for (int ks = 0; ks < DINNER / 32; ++ks) {
        __syncthreads();
        {
            bf16x8 v0, v1, w0, w1;
            v0[0]=f2b(ra[0].x); v0[1]=f2b(ra[0].y); v0[2]=f2b(ra[0].z); v0[3]=f2b(ra[0].w);
            v0[4]=f2b(ra[1].x); v0[5]=f2b(ra[1].y); v0[6]=f2b(ra[1].z); v0[7]=f2b(ra[1].w);
            v1[0]=f2b(ra[2].x); v1[1]=f2b(ra[2].y); v1[2]=f2b(ra[2].z); v1[3]=f2b(ra[2].w);
            v1[4]=f2b(ra[3].x); v1[5]=f2b(ra[3].y); v1[6]=f2b(ra[3].z); v1[7]=f2b(ra[3].w);
            w0[0]=f2b(rb[0].x); w0[1]=f2b(rb[0].y); w0[2]=f2b(rb[0].z); w0[3]=f2b(rb[0].w);
            w0[4]=f2b(rb[1].x); w0[5]=f2b(rb[1].y); w0[6]=f2b(rb[1].z); w0[7]=f2b(rb[1].w);
            w1[0]=f2b(rb[2].x); w1[1]=f2b(rb[2].y); w1[2]=f2b(rb[2].z); w1[3]=f2b(rb[2].w);
            w1[4]=f2b(rb[3].x); w1[5]=f2b(rb[3].y); w1[6]=f2b(rb[3].z); w1[7]=f2b(rb[3].w);
            *(bf16x8*)&As[srow * 40 + shalf]     = v0;
            *(bf16x8*)&As[srow * 40 + shalf + 8] = v1;
            *(bf16x8*)&Bs[srow * 40 + shalf]     = w0;
            *(bf16x8*)&Bs[srow * 40 + shalf + 8] = w1;
        }
        __syncthreads();
        if (ks + 1 < DINNER / 32) {
            const int k0 = (ks + 1) * 32;
#pragma unroll
            for (int q = 0; q < 4; ++q) {
                ra[q] = *(const float4*)(asrc + k0 + q * 4);
                rb[q] = *(const float4*)(bsrc + k0 + q * 4);
            }
        }
        bf16x8 af[4], bfr[4];
#pragma unroll
        for (int mf = 0; mf < 4; ++mf)
            af[mf] = *(const bf16x8*)&As[(wm * 64 + mf * 16 + fr) * 40 + ko];
#pragma unroll
        for (int nf = 0; nf < 4; ++nf)
            bfr[nf] = *(const bf16x8*)&Bs[(wn * 64 + nf * 16 + fr) * 40 + ko];
#pragma unroll
        for (int mf = 0; mf < 4; ++mf)
#pragma unroll
            for (int nf = 0; nf < 4; ++nf)
                acc[mf][nf] = __builtin_amdgcn_mfma_f32_16x16x32_bf16(
                    af[mf], bfr[nf], acc[mf][nf], 0, 0, 0);
    }

#pragma unroll
    for (int mf = 0; mf < 4; ++mf) {
#pragma unroll
        for (int j = 0; j < 4; ++j) {
            const int gm = bm * 128 + wm * 64 + mf * 16 + (lane >> 4) * 4 + j;
            const int b = gm >> 11;
            const int l = gm & 2047;
            const int ii = l & 3;
            const int jj = l >> 2;
            const float* tsel = (ii == 0) ? t0 : (ii == 1) ? t1 : (ii == 2) ? t2 : t3;
#pragma unroll
            for (int nf = 0; nf < 4; ++nf) {
                const int gn = bn * 128 + wn * 64 + nf * 16 + (lane & 15);
                const float tv = tsel[((size_t)b * 512 + jj) * 512 + gn];
                outp[(((size_t)ii * NB + b) * 512 + jj) * 512 + gn] = acc[mf][nf][j] + tv;
            }
        }
    }
}

// ---------------------------------------------------------------------------
extern "C" void kernel_launch(void* const* d_in, const int* in_sizes, int n_in,
                              void* d_out, int out_size, void* d_ws, size_t ws_size,
                              hipStream_t stream)
{
    const float* t0 = (const float*)d_in[0];
    const float* t1 = (const float*)d_in[1];
    const float* t2 = (const float*)d_in[2];
    const float* t3 = (const float*)d_in[3];
    const float* in_proj_w  = (const float*)d_in[4];
    const float* conv_w     = (const float*)d_in[5];
    const float* conv_b     = (const float*)d_in[6];
    const float* x_proj_w   = (const float*)d_in[7];
    const float* dt_w       = (const float*)d_in[8];
    const float* dt_b       = (const float*)d_in[9];
    const float* A_log      = (const float*)d_in[10];
    const float* D_param    = (const float*)d_in[11];
    const float* out_proj_w = (const float*)d_in[12];
    float* outp = (float*)d_out;

    // workspace carve (fp32). Aliasing (stream-ordered, verified):
    //  - part (8 MB) + wxb (128 KB) live in xc_raw region; written AFTER conv
    //    reads xc_raw, dead before scan_final writes yz (= xc_raw alias).
    //  - xc_b (8 MB bf16) lives in delta region; dead before dtproj writes delta.
    float* xc_raw = (float*)d_ws;                          // 4096*1024
    float* zbuf   = xc_raw + (size_t)MM * DINNER;          // 4096*1024
    float* xc_act = zbuf   + (size_t)MM * DINNER;          // 4096*1024
    float* delta  = xc_act + (size_t)MM * DINNER;          // 4096*1024
    float* dbc    = delta  + (size_t)MM * DINNER;          // 4096*64
    float* hfin   = dbc    + (size_t)MM * 64;              // NQ
    float* aprod  = hfin   + (size_t)NQ;                   // NQ
    float* yz     = xc_raw;                                // alias
    float* part   = xc_raw;                                // alias (8 MB)
    unsigned short* wxb  = (unsigned short*)(xc_raw + (size_t)KCH * MM * 64); // alias
    unsigned short* xc_b = (unsigned short*)delta;         // alias (8 MB)

    k_inproj<<<dim3(32, 16), 256, 0, stream>>>(t0, t1, t2, t3, in_proj_w, xc_raw, zbuf);
    k_conv<<<(MM * DINNER) / 256, 256, 0, stream>>>(xc_raw, conv_w, conv_b, xc_act, xc_b);
    k_cvt_wx<<<64, 256, 0, stream>>>(x_proj_w, wxb);
    k_xproj_mfma<<<dim3(32, KCH), 256, 0, stream>>>(xc_b, wxb, part);
    k_xreduce<<<(MM * 64) / 256, 256, 0, stream>>>(part, dbc);
    k_dtproj<<<MM * 4, 256, 0, stream>>>(dbc, dt_w, dt_b, delta);
    k_scan_partial<<<NQ / 256, 256, 0, stream>>>(delta, xc_act, dbc, A_log, hfin, aprod);
    k_scan_combine<<<(NB * DINNER * DSTATE) / 256, 256, 0, stream>>>(hfin, aprod);
    k_scan_final<<<NQ / 256, 256, 0, stream>>>(delta, xc_act, dbc, A_log, D_param, zbuf, hfin, yz);
    k_outproj<<<dim3(32, 4), 256, 0, stream>>>(yz, out_proj_w, t0, t1, t2, t3, outp);
}

// Round 6
// 260.277 us; speedup vs baseline: 3.3609x; 1.1499x over previous
//
#include <hip/hip_runtime.h>

// ---- problem constants ----
#define NB 2          // batch
#define LT 512        // per-tensor seq len
#define LL 2048       // concatenated seq len
#define MM 4096       // NB*LL rows
#define DMODEL 512
#define DINNER 1024
#define DTRANK 32
#define DSTATE 16
#define NSEG 64
#define SEGLEN 32     // NSEG*SEGLEN == LL
#define NST (NB * DINNER * DSTATE)         // 32768 (b,d,s) chains
#define NSCAN (NSEG * NB * DINNER)         // 131072 scan threads
#define KCH 8         // xproj K-chunks (split-K)

typedef short bf16x8 __attribute__((ext_vector_type(8)));
typedef float f32x4  __attribute__((ext_vector_type(4)));

__device__ __forceinline__ float silu_f(float x) { return x / (1.f + __expf(-x)); }
__device__ __forceinline__ short f2b(float f) {
    unsigned u = __float_as_uint(f);
    u += 0x7fffu + ((u >> 16) & 1u);   // RNE
    return (short)(u >> 16);
}

// ---------------------------------------------------------------------------
// K1: fused interleaved gather + in_proj GEMM (bf16 MFMA).
// ---------------------------------------------------------------------------
__global__ __launch_bounds__(256) void k_inproj(
    const float* __restrict__ t0, const float* __restrict__ t1,
    const float* __restrict__ t2, const float* __restrict__ t3,
    const float* __restrict__ W,
    float* __restrict__ xc_raw, float* __restrict__ zbuf)
{
    __shared__ short As[128 * 40];   // 32 cols + 8 pad (80B row stride)
    __shared__ short Bs[128 * 40];
    const int t = threadIdx.x;
    const int lane = t & 63;
    const int wid = t >> 6;
    const int wm = wid >> 1, wn = wid & 1;
    const int bm = blockIdx.x, bn = blockIdx.y;

    const int srow  = t >> 1;          // 0..127 staging row
    const int shalf = (t & 1) * 16;    // 0 or 16 (col offset)

    const int arow = bm * 128 + srow;
    const int gb = arow >> 11;
    const int gl = arow & 2047;
    const int gc = gl >> 7, gr = gl & 127;
    const int ti = gc & 3, ci = gc >> 2;
    const float* tp = (ti == 0) ? t0 : (ti == 1) ? t1 : (ti == 2) ? t2 : t3;
    const float* asrc = tp + ((size_t)gb * 512 + (size_t)(ci + 4 * gr)) * 512 + shalf;
    const float* bsrc = W + (size_t)(bn * 128 + srow) * 512 + shalf;

    f32x4 acc[4][4];
#pragma unroll
    for (int i = 0; i < 4; ++i)
#pragma unroll
        for (int j = 0; j < 4; ++j) acc[i][j] = (f32x4){0.f, 0.f, 0.f, 0.f};

    float4 ra[4], rb[4];
#pragma unroll
    for (int q = 0; q < 4; ++q) {
        ra[q] = *(const float4*)(asrc + q * 4);
        rb[q] = *(const float4*)(bsrc + q * 4);
    }

    const int ko = (lane >> 4) * 8;
    const int fr = lane & 15;

    for (int ks = 0; ks < 512 / 32; ++ks) {
        __syncthreads();
        {
            bf16x8 v0, v1, w0, w1;
            v0[0]=f2b(ra[0].x); v0[1]=f2b(ra[0].y); v0[2]=f2b(ra[0].z); v0[3]=f2b(ra[0].w);
            v0[4]=f2b(ra[1].x); v0[5]=f2b(ra[1].y); v0[6]=f2b(ra[1].z); v0[7]=f2b(ra[1].w);
            v1[0]=f2b(ra[2].x); v1[1]=f2b(ra[2].y); v1[2]=f2b(ra[2].z); v1[3]=f2b(ra[2].w);
            v1[4]=f2b(ra[3].x); v1[5]=f2b(ra[3].y); v1[6]=f2b(ra[3].z); v1[7]=f2b(ra[3].w);
            w0[0]=f2b(rb[0].x); w0[1]=f2b(rb[0].y); w0[2]=f2b(rb[0].z); w0[3]=f2b(rb[0].w);
            w0[4]=f2b(rb[1].x); w0[5]=f2b(rb[1].y); w0[6]=f2b(rb[1].z); w0[7]=f2b(rb[1].w);
            w1[0]=f2b(rb[2].x); w1[1]=f2b(rb[2].y); w1[2]=f2b(rb[2].z); w1[3]=f2b(rb[2].w);
            w1[4]=f2b(rb[3].x); w1[5]=f2b(rb[3].y); w1[6]=f2b(rb[3].z); w1[7]=f2b(rb[3].w);
            *(bf16x8*)&As[srow * 40 + shalf]     = v0;
            *(bf16x8*)&As[srow * 40 + shalf + 8] = v1;
            *(bf16x8*)&Bs[srow * 40 + shalf]     = w0;
            *(bf16x8*)&Bs[srow * 40 + shalf + 8] = w1;
        }
        __syncthreads();
        if (ks + 1 < 512 / 32) {
            const int k0 = (ks + 1) * 32;
#pragma unroll
            for (int q = 0; q < 4; ++q) {
                ra[q] = *(const float4*)(asrc + k0 + q * 4);
                rb[q] = *(const float4*)(bsrc + k0 + q * 4);
            }
        }
        bf16x8 af[4], bfr[4];
#pragma unroll
        for (int mf = 0; mf < 4; ++mf)
            af[mf] = *(const bf16x8*)&As[(wm * 64 + mf * 16 + fr) * 40 + ko];
#pragma unroll
        for (int nf = 0; nf < 4; ++nf)
            bfr[nf] = *(const bf16x8*)&Bs[(wn * 64 + nf * 16 + fr) * 40 + ko];
#pragma unroll
        for (int mf = 0; mf < 4; ++mf)
#pragma unroll
            for (int nf = 0; nf < 4; ++nf)
                acc[mf][nf] = __builtin_amdgcn_mfma_f32_16x16x32_bf16(
                    af[mf], bfr[nf], acc[mf][nf], 0, 0, 0);
    }

    float* dst = (bn < 8) ? xc_raw : zbuf;
    const int coladj = (bn < 8) ? 0 : 1024;
#pragma unroll
    for (int mf = 0; mf < 4; ++mf) {
        const int gmb = bm * 128 + wm * 64 + mf * 16 + (lane >> 4) * 4;
#pragma unroll
        for (int nf = 0; nf < 4; ++nf) {
            const int gn = bn * 128 + wn * 64 + nf * 16 + (lane & 15) - coladj;
#pragma unroll
            for (int j = 0; j < 4; ++j)
                dst[(size_t)(gmb + j) * DINNER + gn] = acc[mf][nf][j];
        }
    }
}

// ---------------------------------------------------------------------------
// K2: causal depthwise conv1d (K=4, left pad 3) + bias + SiLU.
// Dual write: xc_act (f32, scan) and xc_b (bf16, xproj A operand).
// ---------------------------------------------------------------------------
__global__ __launch_bounds__(256) void k_conv(
    const float* __restrict__ xc_raw, const float* __restrict__ cw,
    const float* __restrict__ cb, float* __restrict__ xc_act,
    unsigned short* __restrict__ xc_b)
{
    const int idx = blockIdx.x * 256 + threadIdx.x;   // < 4096*1024
    const int m = idx >> 10, d = idx & 1023;
    const int l = m & 2047;   // within-batch position
    float s = cb[d];
#pragma unroll
    for (int k = 0; k < 4; ++k) {
        const int ll = l - 3 + k;
        if (ll >= 0) s += cw[d * 4 + k] * xc_raw[(size_t)(m - 3 + k) * DINNER + d];
    }
    const float a = silu_f(s);
    xc_act[idx] = a;
    xc_b[idx] = (unsigned short)f2b(a);
}

// ---------------------------------------------------------------------------
// K2b: convert x_proj_w (64x1024 f32) -> bf16
// ---------------------------------------------------------------------------
__global__ __launch_bounds__(256) void k_cvt_wx(
    const float* __restrict__ Wx, unsigned short* __restrict__ wxb)
{
    const int i4 = blockIdx.x * 256 + threadIdx.x;    // < 16384
    float4 v = *(const float4*)(Wx + (size_t)i4 * 4);
    ushort4 o;
    o.x = (unsigned short)f2b(v.x);
    o.y = (unsigned short)f2b(v.y);
    o.z = (unsigned short)f2b(v.z);
    o.w = (unsigned short)f2b(v.w);
    *(ushort4*)(wxb + (size_t)i4 * 4) = o;
}

// ---------------------------------------------------------------------------
// K3: xproj split-K MFMA GEMM.
// ---------------------------------------------------------------------------
__global__ __launch_bounds__(256) void k_xproj_mfma(
    const unsigned short* __restrict__ xc_b, const unsigned short* __restrict__ wxb,
    float* __restrict__ part)
{
    __shared__ short As[128 * 136];   // 128 K-cols + 8 pad
    __shared__ short Bs[64 * 136];
    const int t = threadIdx.x;
    const int lane = t & 63;
    const int w = t >> 6;
    const int bm = blockIdx.x;        // 0..31
    const int kc = blockIdx.y;        // 0..7

    {
        const int row = t >> 1;
        const int cb0 = (t & 1) * 64;
        const unsigned short* src = xc_b + (size_t)(bm * 128 + row) * 1024 + kc * 128 + cb0;
#pragma unroll
        for (int q = 0; q < 8; ++q)
            *(bf16x8*)&As[row * 136 + cb0 + q * 8] = *(const bf16x8*)(src + q * 8);
    }
    {
        const int row = t >> 2;
        const int cb0 = (t & 3) * 32;
        const unsigned short* src = wxb + (size_t)row * 1024 + kc * 128 + cb0;
#pragma unroll
        for (int q = 0; q < 4; ++q)
            *(bf16x8*)&Bs[row * 136 + cb0 + q * 8] = *(const bf16x8*)(src + q * 8);
    }
    __syncthreads();

    const int fr = lane & 15;
    const int ko = (lane >> 4) * 8;

    f32x4 acc[2][4];
#pragma unroll
    for (int i = 0; i < 2; ++i)
#pragma unroll
        for (int j = 0; j < 4; ++j) acc[i][j] = (f32x4){0.f, 0.f, 0.f, 0.f};

#pragma unroll
    for (int ks = 0; ks < 4; ++ks) {
        const int kb = ks * 32 + ko;
        bf16x8 af[2], bfr[4];
#pragma unroll
        for (int mf = 0; mf < 2; ++mf)
            af[mf] = *(const bf16x8*)&As[(w * 32 + mf * 16 + fr) * 136 + kb];
#pragma unroll
        for (int nf = 0; nf < 4; ++nf)
            bfr[nf] = *(const bf16x8*)&Bs[(nf * 16 + fr) * 136 + kb];
#pragma unroll
        for (int mf = 0; mf < 2; ++mf)
#pragma unroll
            for (int nf = 0; nf < 4; ++nf)
                acc[mf][nf] = __builtin_amdgcn_mfma_f32_16x16x32_bf16(
                    af[mf], bfr[nf], acc[mf][nf], 0, 0, 0);
    }

    float* pb = part + (size_t)kc * (MM * 64);
#pragma unroll
    for (int mf = 0; mf < 2; ++mf) {
        const int rb = bm * 128 + w * 32 + mf * 16 + (lane >> 4) * 4;
#pragma unroll
        for (int nf = 0; nf < 4; ++nf) {
            const int col = nf * 16 + (lane & 15);
#pragma unroll
            for (int j = 0; j < 4; ++j)
                pb[(size_t)(rb + j) * 64 + col] = acc[mf][nf][j];
        }
    }
}

// ---------------------------------------------------------------------------
// K3b: reduce split-K partials -> dbc
// ---------------------------------------------------------------------------
__global__ __launch_bounds__(256) void k_xreduce(
    const float* __restrict__ part, float* __restrict__ dbc)
{
    const int i = blockIdx.x * 256 + threadIdx.x;    // < MM*64
    float s = 0.f;
#pragma unroll
    for (int kc = 0; kc < KCH; ++kc)
        s += part[(size_t)kc * (MM * 64) + i];
    dbc[i] = s;
}

// ---------------------------------------------------------------------------
// K4: delta[m][d] = softplus( sum_r dbc[m][r]*dt_w[d][r] + dt_b[d] ), K=32
// ---------------------------------------------------------------------------
__global__ __launch_bounds__(256) void k_dtproj(
    const float* __restrict__ dbc, const float* __restrict__ dtw,
    const float* __restrict__ dtb, float* __restrict__ delta)
{
    __shared__ float dr[DTRANK];
    const int blk = blockIdx.x;      // 4096*4
    const int m = blk >> 2;
    const int d = ((blk & 3) << 8) + threadIdx.x;
    if (threadIdx.x < DTRANK) dr[threadIdx.x] = dbc[(size_t)m * 64 + threadIdx.x];
    __syncthreads();
    const float* wr = dtw + (size_t)d * DTRANK;
    float s = dtb[d];
#pragma unroll
    for (int r0 = 0; r0 < DTRANK; r0 += 4) {
        float4 wv = *(const float4*)(wr + r0);
        s += dr[r0]     * wv.x;
        s += dr[r0 + 1] * wv.y;
        s += dr[r0 + 2] * wv.z;
        s += dr[r0 + 3] * wv.w;
    }
    const float sp = (s > 20.f) ? s : log1pf(__expf(s));
    delta[(size_t)m * DINNER + d] = sp;
}

// ---------------------------------------------------------------------------
// K5: scan phase A: one thread per (g, b, d), ALL 16 states in registers.
// gid = (g*NB + b)*DINNER + d.  Stores h_fin / prod(dA) at [(b*D+d)*16+s][g].
// ---------------------------------------------------------------------------
__global__ __launch_bounds__(256) void k_scan_partial(
    const float* __restrict__ delta, const float* __restrict__ xc_act,
    const float* __restrict__ dbc, const float* __restrict__ A_log,
    float* __restrict__ hfin, float* __restrict__ aprod)
{
    const int gid = blockIdx.x * 256 + threadIdx.x;   // < NSCAN
    const int d = gid & 1023;
    const int b = (gid >> 10) & (NB - 1);
    const int g = gid >> 11;                           // 0..63

    float Af[DSTATE];
#pragma unroll
    for (int q = 0; q < 4; ++q) {
        float4 a4 = *(const float4*)(A_log + d * DSTATE + q * 4);
        Af[q * 4 + 0] = -__expf(a4.x);
        Af[q * 4 + 1] = -__expf(a4.y);
        Af[q * 4 + 2] = -__expf(a4.z);
        Af[q * 4 + 3] = -__expf(a4.w);
    }

    float h[DSTATE], ap[DSTATE];
#pragma unroll
    for (int s = 0; s < DSTATE; ++s) { h[s] = 0.f; ap[s] = 1.f; }

    const int mbase = b * LL + g * SEGLEN;
    for (int ll = 0; ll < SEGLEN; ++ll) {
        const int m = mbase + ll;
        const float de = delta[(size_t)m * DINNER + d];
        const float x  = xc_act[(size_t)m * DINNER + d];
        const float dx = de * x;
        const float* bc = dbc + (size_t)m * 64 + 32;
        float Bv[DSTATE];
#pragma unroll
        for (int q = 0; q < 4; ++q) {
            float4 b4 = *(const float4*)(bc + q * 4);
            Bv[q * 4 + 0] = b4.x; Bv[q * 4 + 1] = b4.y;
            Bv[q * 4 + 2] = b4.z; Bv[q * 4 + 3] = b4.w;
        }
#pragma unroll
        for (int s = 0; s < DSTATE; ++s) {
            const float dA = __expf(de * Af[s]);
            ap[s] *= dA;
            h[s] = dA * h[s] + dx * Bv[s];
        }
    }
    const size_t base = (size_t)(b * DINNER + d) * DSTATE;
#pragma unroll
    for (int s = 0; s < DSTATE; ++s) {
        hfin [(base + s) * NSEG + g] = h[s];
        aprod[(base + s) * NSEG + g] = ap[s];
    }
}

// ---------------------------------------------------------------------------
// K6: combine: wave-parallel Hillis-Steele scan over 64 segments.
// One wave per (b,d,s), lane = segment g.  Affine maps (A,B): h_out = A*h + B.
// In-place: hfin[bds][g] <- h_in for segment g (exclusive prefix B).
// ---------------------------------------------------------------------------
__global__ __launch_bounds__(256) void k_scan_combine(
    float* __restrict__ hfin, const float* __restrict__ aprod)
{
    const int tid = blockIdx.x * 256 + threadIdx.x;   // < NST*NSEG
    const int g = tid & 63;
    const size_t bds = (size_t)(tid >> 6);
    float A = aprod[bds * NSEG + g];
    float B = hfin [bds * NSEG + g];
#pragma unroll
    for (int off = 1; off < 64; off <<= 1) {
        const float Ap = __shfl_up(A, off, 64);
        const float Bp = __shfl_up(B, off, 64);
        if (g >= off) { B = A * Bp + B; A = A * Ap; }
    }
    const float hprev = __shfl_up(B, 1, 64);
    hfin[bds * NSEG + g] = (g == 0) ? 0.f : hprev;
}

// ---------------------------------------------------------------------------
// K7: scan phase C: one thread per (g, b, d), 16 states in registers,
// in-thread y reduction, fused (y + D*x)*silu(z) write.
// ---------------------------------------------------------------------------
__global__ __launch_bounds__(256) void k_scan_final(
    const float* __restrict__ delta, const float* __restrict__ xc_act,
    const float* __restrict__ dbc, const float* __restrict__ A_log,
    const float* __restrict__ Dp, const float* __restrict__ zbuf,
    const float* __restrict__ hin, float* __restrict__ yz)
{
    const int gid = blockIdx.x * 256 + threadIdx.x;   // < NSCAN
    const int d = gid & 1023;
    const int b = (gid >> 10) & (NB - 1);
    const int g = gid >> 11;

    float Af[DSTATE];
#pragma unroll
    for (int q = 0; q < 4; ++q) {
        float4 a4 = *(const float4*)(A_log + d * DSTATE + q * 4);
        Af[q * 4 + 0] = -__expf(a4.x);
        Af[q * 4 + 1] = -__expf(a4.y);
        Af[q * 4 + 2] = -__expf(a4.z);
        Af[q * 4 + 3] = -__expf(a4.w);
    }
    const float Dd = Dp[d];

    const size_t base = (size_t)(b * DINNER + d) * DSTATE;
    float h[DSTATE];
#pragma unroll
    for (int s = 0; s < DSTATE; ++s) h[s] = hin[(base + s) * NSEG + g];

    const int mbase = b * LL + g * SEGLEN;
    for (int ll = 0; ll < SEGLEN; ++ll) {
        const int m = mbase + ll;
        const float de = delta[(size_t)m * DINNER + d];
        const float x  = xc_act[(size_t)m * DINNER + d];
        const float zz = zbuf[(size_t)m * DINNER + d];
        const float dx = de * x;
        const float* bc = dbc + (size_t)m * 64;
        float Bv[DSTATE], Cv[DSTATE];
#pragma unroll
        for (int q = 0; q < 4; ++q) {
            float4 b4 = *(const float4*)(bc + 32 + q * 4);
            float4 c4 = *(const float4*)(bc + 48 + q * 4);
            Bv[q * 4 + 0] = b4.x; Bv[q * 4 + 1] = b4.y;
            Bv[q * 4 + 2] = b4.z; Bv[q * 4 + 3] = b4.w;
            Cv[q * 4 + 0] = c4.x; Cv[q * 4 + 1] = c4.y;
            Cv[q * 4 + 2] = c4.z; Cv[q * 4 + 3] = c4.w;
        }
        float y0 = 0.f, y1 = 0.f, y2 = 0.f, y3 = 0.f;
#pragma unroll
        for (int s = 0; s < DSTATE; s += 4) {
            float dA;
            dA = __expf(de * Af[s + 0]); h[s + 0] = dA * h[s + 0] + dx * Bv[s + 0]; y0 += h[s + 0] * Cv[s + 0];
            dA = __expf(de * Af[s + 1]); h[s + 1] = dA * h[s + 1] + dx * Bv[s + 1]; y1 += h[s + 1] * Cv[s + 1];
            dA = __expf(de * Af[s + 2]); h[s + 2] = dA * h[s + 2] + dx * Bv[s + 2]; y2 += h[s + 2] * Cv[s + 2];
            dA = __expf(de * Af[s + 3]); h[s + 3] = dA * h[s + 3] + dx * Bv[s + 3]; y3 += h[s + 3] * Cv[s + 3];
        }
        const float y = (y0 + y1) + (y2 + y3);
        yz[(size_t)m * DINNER + d] = (y + Dd * x) * silu_f(zz);
    }
}

// ---------------------------------------------------------------------------
// K8: out_proj GEMM (bf16 MFMA) + de-interleave scatter + residual add.
// ---------------------------------------------------------------------------
__global__ __launch_bounds__(256) void k_outproj(
    const float* __restrict__ yz, const float* __restrict__ Wo,
    const float* __restrict__ t0, const float* __restrict__ t1,
    const float* __restrict__ t2, const float* __restrict__ t3,
    float* __restrict__ outp)
{
    __shared__ short As[128 * 40];
    __shared__ short Bs[128 * 40];
    const int t = threadIdx.x;
    const int lane = t & 63;
    const int wid = t >> 6;
    const int wm = wid >> 1, wn = wid & 1;
    const int bm = blockIdx.x, bn = blockIdx.y;

    const int srow  = t >> 1;
    const int shalf = (t & 1) * 16;

    const float* asrc = yz + (size_t)(bm * 128 + srow) * DINNER + shalf;
    const float* bsrc = Wo + (size_t)(bn * 128 + srow) * DINNER + shalf;

    f32x4 acc[4][4];
#pragma unroll
    for (int i = 0; i < 4; ++i)
#pragma unroll
        for (int j = 0; j < 4; ++j) acc[i][j] = (f32x4){0.f, 0.f, 0.f, 0.f};

    float4 ra[4], rb[4];
#pragma unroll
    for (int q = 0; q < 4; ++q) {
        ra[q] = *(const float4*)(asrc + q * 4);
        rb[q] = *(const float4*)(bsrc + q * 4);
    }

    const int ko = (lane >> 4) * 8;
    const int fr = lane & 15;

    for (int ks = 0; ks < DINNER / 32; ++ks) {
        __syncthreads();
        {
            bf16x8 v0, v1, w0, w1;
            v0[0]=f2b(ra[0].x); v0[1]=f2b(ra[0].y); v0[2]=f2b(ra[0].z); v0[3]=f2b(ra[0].w);
            v0[4]=f2b(ra[1].x); v0[5]=f2b(ra[1].y); v0[6]=f2b(ra[1].z); v0[7]=f2b(ra[1].w);
            v1[0]=f2b(ra[2].x); v1[1]=f2b(ra[2].y); v1[2]=f2b(ra[2].z); v1[3]=f2b(ra[2].w);
            v1[4]=f2b(ra[3].x); v1[5]=f2b(ra[3].y); v1[6]=f2b(ra[3].z); v1[7]=f2b(ra[3].w);
            w0[0]=f2b(rb[0].x); w0[1]=f2b(rb[0].y); w0[2]=f2b(rb[0].z); w0[3]=f2b(rb[0].w);
            w0[4]=f2b(rb[1].x); w0[5]=f2b(rb[1].y); w0[6]=f2b(rb[1].z); w0[7]=f2b(rb[1].w);
            w1[0]=f2b(rb[2].x); w1[1]=f2b(rb[2].y); w1[2]=f2b(rb[2].z); w1[3]=f2b(rb[2].w);
            w1[4]=f2b(rb[3].x); w1[5]=f2b(rb[3].y); w1[6]=f2b(rb[3].z); w1[7]=f2b(rb[3].w);
            *(bf16x8*)&As[srow * 40 + shalf]     = v0;
            *(bf16x8*)&As[srow * 40 + shalf + 8] = v1;
            *(bf16x8*)&Bs[srow * 40 + shalf]     = w0;
            *(bf16x8*)&Bs[srow * 40 + shalf + 8] = w1;
        }
        __syncthreads();
        if (ks + 1 < DINNER / 32) {
            const int k0 = (ks + 1) * 32;
#pragma unroll
            for (int q = 0; q < 4; ++q) {
                ra[q] = *(const float4*)(asrc + k0 + q * 4);
                rb[q] = *(const float4*)(bsrc + k0 + q * 4);
            }
        }
        bf16x8 af[4], bfr[4];
#pragma unroll
        for (int mf = 0; mf < 4; ++mf)
            af[mf] = *(const bf16x8*)&As[(wm * 64 + mf * 16 + fr) * 40 + ko];
#pragma unroll
        for (int nf = 0; nf < 4; ++nf)
            bfr[nf] = *(const bf16x8*)&Bs[(wn * 64 + nf * 16 + fr) * 40 + ko];
#pragma unroll
        for (int mf = 0; mf < 4; ++mf)
#pragma unroll
            for (int nf = 0; nf < 4; ++nf)
                acc[mf][nf] = __builtin_amdgcn_mfma_f32_16x16x32_bf16(
                    af[mf], bfr[nf], acc[mf][nf], 0, 0, 0);
    }

#pragma unroll
    for (int mf = 0; mf < 4; ++mf) {
#pragma unroll
        for (int j = 0; j < 4; ++j) {
            const int gm = bm * 128 + wm * 64 + mf * 16 + (lane >> 4) * 4 + j;
            const int b = gm >> 11;
            const int l = gm & 2047;
            const int ii = l & 3;
            const int jj = l >> 2;
            const float* tsel = (ii == 0) ? t0 : (ii == 1) ? t1 : (ii == 2) ? t2 : t3;
#pragma unroll
            for (int nf = 0; nf < 4; ++nf) {
                const int gn = bn * 128 + wn * 64 + nf * 16 + (lane & 15);
                const float tv = tsel[((size_t)b * 512 + jj) * 512 + gn];
                outp[(((size_t)ii * NB + b) * 512 + jj) * 512 + gn] = acc[mf][nf][j] + tv;
            }
        }
    }
}

// ---------------------------------------------------------------------------
extern "C" void kernel_launch(void* const* d_in, const int* in_sizes, int n_in,
                              void* d_out, int out_size, void* d_ws, size_t ws_size,
                              hipStream_t stream)
{
    const float* t0 = (const float*)d_in[0];
    const float* t1 = (const float*)d_in[1];
    const float* t2 = (const float*)d_in[2];
    const float* t3 = (const float*)d_in[3];
    const float* in_proj_w  = (const float*)d_in[4];
    const float* conv_w     = (const float*)d_in[5];
    const float* conv_b     = (const float*)d_in[6];
    const float* x_proj_w   = (const float*)d_in[7];
    const float* dt_w       = (const float*)d_in[8];
    const float* dt_b       = (const float*)d_in[9];
    const float* A_log      = (const float*)d_in[10];
    const float* D_param    = (const float*)d_in[11];
    const float* out_proj_w = (const float*)d_in[12];
    float* outp = (float*)d_out;

    // workspace carve (fp32).  Aliasing timeline (stream-ordered, audited):
    // 1 inproj:   W xc_raw, zbuf
    // 2 conv:     R xc_raw          -> W xc_act, xc_b (delta region)
    // 3 cvt_wx:   W wxb (xc_raw+2M) [xc_raw dead]
    // 4 xproj:    R xc_b, wxb       -> W part (xc_raw 0..2M)
    // 5 xreduce:  R part            -> W dbc
    // 6 dtproj:   R dbc             -> W delta [xc_b dead]
    // 7 scanA:    R delta,xc_act,dbc-> W hfin, aprod (xc_raw 0..2M, part dead)
    // 8 combine:  R hfin, aprod     -> W hfin (in place, wave-local)
    // 9 scanC:    R delta,xc_act,dbc,hfin,zbuf -> W yz (xc_raw; aprod/wxb dead)
    // 10 outproj: R yz, Wo, t*      -> W outp
    float* xc_raw = (float*)d_ws;                          // 4M floats
    float* zbuf   = xc_raw + (size_t)MM * DINNER;          // 4M
    float* xc_act = zbuf   + (size_t)MM * DINNER;          // 4M
    float* delta  = xc_act + (size_t)MM * DINNER;          // 4M
    float* dbc    = delta  + (size_t)MM * DINNER;          // 256K
    float* hfin   = dbc    + (size_t)MM * 64;              // 2M (NST*NSEG)
    float* yz     = xc_raw;                                // alias
    float* part   = xc_raw;                                // alias (2M floats)
    float* aprod  = xc_raw;                                // alias (2M floats)
    unsigned short* wxb  = (unsigned short*)(xc_raw + (size_t)KCH * MM * 64);
    unsigned short* xc_b = (unsigned short*)delta;         // alias (2M floats)

    k_inproj<<<dim3(32, 16), 256, 0, stream>>>(t0, t1, t2, t3, in_proj_w, xc_raw, zbuf);
    k_conv<<<(MM * DINNER) / 256, 256, 0, stream>>>(xc_raw, conv_w, conv_b, xc_act, xc_b);
    k_cvt_wx<<<64, 256, 0, stream>>>(x_proj_w, wxb);
    k_xproj_mfma<<<dim3(32, KCH), 256, 0, stream>>>(xc_b, wxb, part);
    k_xreduce<<<(MM * 64) / 256, 256, 0, stream>>>(part, dbc);
    k_dtproj<<<MM * 4, 256, 0, stream>>>(dbc, dt_w, dt_b, delta);
    k_scan_partial<<<NSCAN / 256, 256, 0, stream>>>(delta, xc_act, dbc, A_log, hfin, aprod);
    k_scan_combine<<<(NST * NSEG) / 256, 256, 0, stream>>>(hfin, aprod);
    k_scan_final<<<NSCAN / 256, 256, 0, stream>>>(delta, xc_act, dbc, A_log, D_param, zbuf, hfin, yz);
    k_outproj<<<dim3(32, 4), 256, 0, stream>>>(yz, out_proj_w, t0, t1, t2, t3, outp);
}

// Round 7
// 222.508 us; speedup vs baseline: 3.9314x; 1.1697x over previous
//
#include <hip/hip_runtime.h>

// ---- problem constants ----
#define NB 2          // batch
#define LT 512        // per-tensor seq len
#define LL 2048       // concatenated seq len
#define MM 4096       // NB*LL rows
#define DMODEL 512
#define DINNER 1024
#define DTRANK 32
#define DSTATE 16
#define NSEG 64
#define SEGLEN 32     // NSEG*SEGLEN == LL
#define NST (NB * DINNER * DSTATE)         // 32768 (b,d,s) chains
#define NSCAN (NSEG * NB * DINNER)         // 131072 scan threads
#define KCH 8         // xproj K-chunks (split-K)

typedef short bf16x8 __attribute__((ext_vector_type(8)));
typedef float f32x4  __attribute__((ext_vector_type(4)));

__device__ __forceinline__ float silu_f(float x) { return x / (1.f + __expf(-x)); }
__device__ __forceinline__ short f2b(float f) {
    unsigned u = __float_as_uint(f);
    u += 0x7fffu + ((u >> 16) & 1u);   // RNE
    return (short)(u >> 16);
}

// ---------------------------------------------------------------------------
// K1: fused interleaved gather + in_proj GEMM (bf16 MFMA).
// ---------------------------------------------------------------------------
__global__ __launch_bounds__(256) void k_inproj(
    const float* __restrict__ t0, const float* __restrict__ t1,
    const float* __restrict__ t2, const float* __restrict__ t3,
    const float* __restrict__ W,
    float* __restrict__ xc_raw, float* __restrict__ zbuf)
{
    __shared__ short As[128 * 40];   // 32 cols + 8 pad (80B row stride)
    __shared__ short Bs[128 * 40];
    const int t = threadIdx.x;
    const int lane = t & 63;
    const int wid = t >> 6;
    const int wm = wid >> 1, wn = wid & 1;
    const int bm = blockIdx.x, bn = blockIdx.y;

    const int srow  = t >> 1;          // 0..127 staging row
    const int shalf = (t & 1) * 16;    // 0 or 16 (col offset)

    const int arow = bm * 128 + srow;
    const int gb = arow >> 11;
    const int gl = arow & 2047;
    const int gc = gl >> 7, gr = gl & 127;
    const int ti = gc & 3, ci = gc >> 2;
    const float* tp = (ti == 0) ? t0 : (ti == 1) ? t1 : (ti == 2) ? t2 : t3;
    const float* asrc = tp + ((size_t)gb * 512 + (size_t)(ci + 4 * gr)) * 512 + shalf;
    const float* bsrc = W + (size_t)(bn * 128 + srow) * 512 + shalf;

    f32x4 acc[4][4];
#pragma unroll
    for (int i = 0; i < 4; ++i)
#pragma unroll
        for (int j = 0; j < 4; ++j) acc[i][j] = (f32x4){0.f, 0.f, 0.f, 0.f};

    float4 ra[4], rb[4];
#pragma unroll
    for (int q = 0; q < 4; ++q) {
        ra[q] = *(const float4*)(asrc + q * 4);
        rb[q] = *(const float4*)(bsrc + q * 4);
    }

    const int ko = (lane >> 4) * 8;
    const int fr = lane & 15;

    for (int ks = 0; ks < 512 / 32; ++ks) {
        __syncthreads();
        {
            bf16x8 v0, v1, w0, w1;
            v0[0]=f2b(ra[0].x); v0[1]=f2b(ra[0].y); v0[2]=f2b(ra[0].z); v0[3]=f2b(ra[0].w);
            v0[4]=f2b(ra[1].x); v0[5]=f2b(ra[1].y); v0[6]=f2b(ra[1].z); v0[7]=f2b(ra[1].w);
            v1[0]=f2b(ra[2].x); v1[1]=f2b(ra[2].y); v1[2]=f2b(ra[2].z); v1[3]=f2b(ra[2].w);
            v1[4]=f2b(ra[3].x); v1[5]=f2b(ra[3].y); v1[6]=f2b(ra[3].z); v1[7]=f2b(ra[3].w);
            w0[0]=f2b(rb[0].x); w0[1]=f2b(rb[0].y); w0[2]=f2b(rb[0].z); w0[3]=f2b(rb[0].w);
            w0[4]=f2b(rb[1].x); w0[5]=f2b(rb[1].y); w0[6]=f2b(rb[1].z); w0[7]=f2b(rb[1].w);
            w1[0]=f2b(rb[2].x); w1[1]=f2b(rb[2].y); w1[2]=f2b(rb[2].z); w1[3]=f2b(rb[2].w);
            w1[4]=f2b(rb[3].x); w1[5]=f2b(rb[3].y); w1[6]=f2b(rb[3].z); w1[7]=f2b(rb[3].w);
            *(bf16x8*)&As[srow * 40 + shalf]     = v0;
            *(bf16x8*)&As[srow * 40 + shalf + 8] = v1;
            *(bf16x8*)&Bs[srow * 40 + shalf]     = w0;
            *(bf16x8*)&Bs[srow * 40 + shalf + 8] = w1;
        }
        __syncthreads();
        if (ks + 1 < 512 / 32) {
            const int k0 = (ks + 1) * 32;
#pragma unroll
            for (int q = 0; q < 4; ++q) {
                ra[q] = *(const float4*)(asrc + k0 + q * 4);
                rb[q] = *(const float4*)(bsrc + k0 + q * 4);
            }
        }
        bf16x8 af[4], bfr[4];
#pragma unroll
        for (int mf = 0; mf < 4; ++mf)
            af[mf] = *(const bf16x8*)&As[(wm * 64 + mf * 16 + fr) * 40 + ko];
#pragma unroll
        for (int nf = 0; nf < 4; ++nf)
            bfr[nf] = *(const bf16x8*)&Bs[(wn * 64 + nf * 16 + fr) * 40 + ko];
#pragma unroll
        for (int mf = 0; mf < 4; ++mf)
#pragma unroll
            for (int nf = 0; nf < 4; ++nf)
                acc[mf][nf] = __builtin_amdgcn_mfma_f32_16x16x32_bf16(
                    af[mf], bfr[nf], acc[mf][nf], 0, 0, 0);
    }

    float* dst = (bn < 8) ? xc_raw : zbuf;
    const int coladj = (bn < 8) ? 0 : 1024;
#pragma unroll
    for (int mf = 0; mf < 4; ++mf) {
        const int gmb = bm * 128 + wm * 64 + mf * 16 + (lane >> 4) * 4;
#pragma unroll
        for (int nf = 0; nf < 4; ++nf) {
            const int gn = bn * 128 + wn * 64 + nf * 16 + (lane & 15) - coladj;
#pragma unroll
            for (int j = 0; j < 4; ++j)
                dst[(size_t)(gmb + j) * DINNER + gn] = acc[mf][nf][j];
        }
    }
}

// ---------------------------------------------------------------------------
// K2: causal depthwise conv1d (K=4, left pad 3) + bias + SiLU.
// One thread: 4 channels (float4 along d) x 4 timesteps (row reuse).
// Dual write: xc_act (f32) + xc_b (bf16).
// ---------------------------------------------------------------------------
__global__ __launch_bounds__(256) void k_conv(
    const float* __restrict__ xc_raw, const float* __restrict__ cw,
    const float* __restrict__ cb, float* __restrict__ xc_act,
    unsigned short* __restrict__ xc_b)
{
    const int d0 = threadIdx.x * 4;           // 0..1020
    const int m0 = blockIdx.x * 4;            // group of 4 rows, within one batch
    const int l0 = m0 & 2047;

    float4 w[4];
#pragma unroll
    for (int c = 0; c < 4; ++c) w[c] = *(const float4*)(cw + (size_t)(d0 + c) * 4);
    const float4 bb = *(const float4*)(cb + d0);

    float4 row[7];
#pragma unroll
    for (int o = 0; o < 7; ++o) {
        const int l = l0 + o - 3;
        if (l >= 0)
            row[o] = *(const float4*)(xc_raw + (size_t)(m0 + o - 3) * DINNER + d0);
        else
            row[o] = (float4){0.f, 0.f, 0.f, 0.f};
    }

#pragma unroll
    for (int mm = 0; mm < 4; ++mm) {
        float4 s = bb;
#pragma unroll
        for (int k = 0; k < 4; ++k) {
            const float4 r = row[mm + k];
            s.x += ((const float*)&w[0])[k] * r.x;
            s.y += ((const float*)&w[1])[k] * r.y;
            s.z += ((const float*)&w[2])[k] * r.z;
            s.w += ((const float*)&w[3])[k] * r.w;
        }
        float4 a;
        a.x = silu_f(s.x); a.y = silu_f(s.y); a.z = silu_f(s.z); a.w = silu_f(s.w);
        const size_t idx = (size_t)(m0 + mm) * DINNER + d0;
        *(float4*)(xc_act + idx) = a;
        ushort4 ob;
        ob.x = (unsigned short)f2b(a.x);
        ob.y = (unsigned short)f2b(a.y);
        ob.z = (unsigned short)f2b(a.z);
        ob.w = (unsigned short)f2b(a.w);
        *(ushort4*)(xc_b + idx) = ob;
    }
}

// ---------------------------------------------------------------------------
// K2b: convert x_proj_w (64x1024 f32) -> bf16
// ---------------------------------------------------------------------------
__global__ __launch_bounds__(256) void k_cvt_wx(
    const float* __restrict__ Wx, unsigned short* __restrict__ wxb)
{
    const int i4 = blockIdx.x * 256 + threadIdx.x;    // < 16384
    float4 v = *(const float4*)(Wx + (size_t)i4 * 4);
    ushort4 o;
    o.x = (unsigned short)f2b(v.x);
    o.y = (unsigned short)f2b(v.y);
    o.z = (unsigned short)f2b(v.z);
    o.w = (unsigned short)f2b(v.w);
    *(ushort4*)(wxb + (size_t)i4 * 4) = o;
}

// ---------------------------------------------------------------------------
// K3: xproj split-K MFMA GEMM.
// ---------------------------------------------------------------------------
__global__ __launch_bounds__(256) void k_xproj_mfma(
    const unsigned short* __restrict__ xc_b, const unsigned short* __restrict__ wxb,
    float* __restrict__ part)
{
    __shared__ short As[128 * 136];   // 128 K-cols + 8 pad
    __shared__ short Bs[64 * 136];
    const int t = threadIdx.x;
    const int lane = t & 63;
    const int w = t >> 6;
    const int bm = blockIdx.x;        // 0..31
    const int kc = blockIdx.y;        // 0..7

    {
        const int row = t >> 1;
        const int cb0 = (t & 1) * 64;
        const unsigned short* src = xc_b + (size_t)(bm * 128 + row) * 1024 + kc * 128 + cb0;
#pragma unroll
        for (int q = 0; q < 8; ++q)
            *(bf16x8*)&As[row * 136 + cb0 + q * 8] = *(const bf16x8*)(src + q * 8);
    }
    {
        const int row = t >> 2;
        const int cb0 = (t & 3) * 32;
        const unsigned short* src = wxb + (size_t)row * 1024 + kc * 128 + cb0;
#pragma unroll
        for (int q = 0; q < 4; ++q)
            *(bf16x8*)&Bs[row * 136 + cb0 + q * 8] = *(const bf16x8*)(src + q * 8);
    }
    __syncthreads();

    const int fr = lane & 15;
    const int ko = (lane >> 4) * 8;

    f32x4 acc[2][4];
#pragma unroll
    for (int i = 0; i < 2; ++i)
#pragma unroll
        for (int j = 0; j < 4; ++j) acc[i][j] = (f32x4){0.f, 0.f, 0.f, 0.f};

#pragma unroll
    for (int ks = 0; ks < 4; ++ks) {
        const int kb = ks * 32 + ko;
        bf16x8 af[2], bfr[4];
#pragma unroll
        for (int mf = 0; mf < 2; ++mf)
            af[mf] = *(const bf16x8*)&As[(w * 32 + mf * 16 + fr) * 136 + kb];
#pragma unroll
        for (int nf = 0; nf < 4; ++nf)
            bfr[nf] = *(const bf16x8*)&Bs[(nf * 16 + fr) * 136 + kb];
#pragma unroll
        for (int mf = 0; mf < 2; ++mf)
#pragma unroll
            for (int nf = 0; nf < 4; ++nf)
                acc[mf][nf] = __builtin_amdgcn_mfma_f32_16x16x32_bf16(
                    af[mf], bfr[nf], acc[mf][nf], 0, 0, 0);
    }

    float* pb = part + (size_t)kc * (MM * 64);
#pragma unroll
    for (int mf = 0; mf < 2; ++mf) {
        const int rb = bm * 128 + w * 32 + mf * 16 + (lane >> 4) * 4;
#pragma unroll
        for (int nf = 0; nf < 4; ++nf) {
            const int col = nf * 16 + (lane & 15);
#pragma unroll
            for (int j = 0; j < 4; ++j)
                pb[(size_t)(rb + j) * 64 + col] = acc[mf][nf][j];
        }
    }
}

// ---------------------------------------------------------------------------
// K3b: reduce split-K partials -> dbc
// ---------------------------------------------------------------------------
__global__ __launch_bounds__(256) void k_xreduce(
    const float* __restrict__ part, float* __restrict__ dbc)
{
    const int i = blockIdx.x * 256 + threadIdx.x;    // < MM*64
    float s = 0.f;
#pragma unroll
    for (int kc = 0; kc < KCH; ++kc)
        s += part[(size_t)kc * (MM * 64) + i];
    dbc[i] = s;
}

// ---------------------------------------------------------------------------
// K4: dtproj as MFMA GEMM: delta[m][d] = softplus(sum_r dbc[m][r]*dt_w[d][r] + dt_b[d])
// M=4096, N=1024, K=32 (one MFMA K-step). 128x128 tile, 4 waves 2x2.
// Stages dbc cols 0..31 and dt_w directly from f32 with in-kernel bf16 cvt.
// ---------------------------------------------------------------------------
__global__ __launch_bounds__(256) void k_dtproj_mfma(
    const float* __restrict__ dbc, const float* __restrict__ dtw,
    const float* __restrict__ dtb, float* __restrict__ delta)
{
    __shared__ short As[128 * 40];   // 32 cols + 8 pad
    __shared__ short Bs[128 * 40];
    const int t = threadIdx.x;
    const int lane = t & 63;
    const int wid = t >> 6;
    const int wm = wid >> 1, wn = wid & 1;
    const int bm = blockIdx.x;       // 0..31 (m)
    const int bn = blockIdx.y;       // 0..7  (d)

    const int srow  = t >> 1;          // 0..127
    const int shalf = (t & 1) * 16;    // 0 or 16

    // stage A: dbc[bm*128+srow][shalf..shalf+15]  (row stride 64)
    {
        const float* src = dbc + (size_t)(bm * 128 + srow) * 64 + shalf;
        float4 r0 = *(const float4*)(src + 0);
        float4 r1 = *(const float4*)(src + 4);
        float4 r2 = *(const float4*)(src + 8);
        float4 r3 = *(const float4*)(src + 12);
        bf16x8 v0, v1;
        v0[0]=f2b(r0.x); v0[1]=f2b(r0.y); v0[2]=f2b(r0.z); v0[3]=f2b(r0.w);
        v0[4]=f2b(r1.x); v0[5]=f2b(r1.y); v0[6]=f2b(r1.z); v0[7]=f2b(r1.w);
        v1[0]=f2b(r2.x); v1[1]=f2b(r2.y); v1[2]=f2b(r2.z); v1[3]=f2b(r2.w);
        v1[4]=f2b(r3.x); v1[5]=f2b(r3.y); v1[6]=f2b(r3.z); v1[7]=f2b(r3.w);
        *(bf16x8*)&As[srow * 40 + shalf]     = v0;
        *(bf16x8*)&As[srow * 40 + shalf + 8] = v1;
    }
    // stage B: dt_w[bn*128+srow][shalf..shalf+15]  (row stride 32)
    {
        const float* src = dtw + (size_t)(bn * 128 + srow) * DTRANK + shalf;
        float4 r0 = *(const float4*)(src + 0);
        float4 r1 = *(const float4*)(src + 4);
        float4 r2 = *(const float4*)(src + 8);
        float4 r3 = *(const float4*)(src + 12);
        bf16x8 v0, v1;
        v0[0]=f2b(r0.x); v0[1]=f2b(r0.y); v0[2]=f2b(r0.z); v0[3]=f2b(r0.w);
        v0[4]=f2b(r1.x); v0[5]=f2b(r1.y); v0[6]=f2b(r1.z); v0[7]=f2b(r1.w);
        v1[0]=f2b(r2.x); v1[1]=f2b(r2.y); v1[2]=f2b(r2.z); v1[3]=f2b(r2.w);
        v1[4]=f2b(r3.x); v1[5]=f2b(r3.y); v1[6]=f2b(r3.z); v1[7]=f2b(r3.w);
        *(bf16x8*)&Bs[srow * 40 + shalf]     = v0;
        *(bf16x8*)&Bs[srow * 40 + shalf + 8] = v1;
    }
    __syncthreads();

    const int ko = (lane >> 4) * 8;
    const int fr = lane & 15;

    f32x4 acc[4][4];
#pragma unroll
    for (int i = 0; i < 4; ++i)
#pragma unroll
        for (int j = 0; j < 4; ++j) acc[i][j] = (f32x4){0.f, 0.f, 0.f, 0.f};

    bf16x8 af[4], bfr[4];
#pragma unroll
    for (int mf = 0; mf < 4; ++mf)
        af[mf] = *(const bf16x8*)&As[(wm * 64 + mf * 16 + fr) * 40 + ko];
#pragma unroll
    for (int nf = 0; nf < 4; ++nf)
        bfr[nf] = *(const bf16x8*)&Bs[(wn * 64 + nf * 16 + fr) * 40 + ko];
#pragma unroll
    for (int mf = 0; mf < 4; ++mf)
#pragma unroll
        for (int nf = 0; nf < 4; ++nf)
            acc[mf][nf] = __builtin_amdgcn_mfma_f32_16x16x32_bf16(
                af[mf], bfr[nf], acc[mf][nf], 0, 0, 0);

#pragma unroll
    for (int mf = 0; mf < 4; ++mf) {
        const int gmb = bm * 128 + wm * 64 + mf * 16 + (lane >> 4) * 4;
#pragma unroll
        for (int nf = 0; nf < 4; ++nf) {
            const int gn = bn * 128 + wn * 64 + nf * 16 + (lane & 15);
            const float bias = dtb[gn];
#pragma unroll
            for (int j = 0; j < 4; ++j) {
                const float s = acc[mf][nf][j] + bias;
                const float sp = (s > 20.f) ? s : log1pf(__expf(s));
                delta[(size_t)(gmb + j) * DINNER + gn] = sp;
            }
        }
    }
}

// ---------------------------------------------------------------------------
// K5: scan phase A: one thread per (g, b, d), ALL 16 states in registers.
// ---------------------------------------------------------------------------
__global__ __launch_bounds__(256) void k_scan_partial(
    const float* __restrict__ delta, const float* __restrict__ xc_act,
    const float* __restrict__ dbc, const float* __restrict__ A_log,
    float* __restrict__ hfin, float* __restrict__ aprod)
{
    const int gid = blockIdx.x * 256 + threadIdx.x;   // < NSCAN
    const int d = gid & 1023;
    const int b = (gid >> 10) & (NB - 1);
    const int g = gid >> 11;                           // 0..63

    float Af[DSTATE];
#pragma unroll
    for (int q = 0; q < 4; ++q) {
        float4 a4 = *(const float4*)(A_log + d * DSTATE + q * 4);
        Af[q * 4 + 0] = -__expf(a4.x);
        Af[q * 4 + 1] = -__expf(a4.y);
        Af[q * 4 + 2] = -__expf(a4.z);
        Af[q * 4 + 3] = -__expf(a4.w);
    }

    float h[DSTATE], ap[DSTATE];
#pragma unroll
    for (int s = 0; s < DSTATE; ++s) { h[s] = 0.f; ap[s] = 1.f; }

    const int mbase = b * LL + g * SEGLEN;
    for (int ll = 0; ll < SEGLEN; ++ll) {
        const int m = mbase + ll;
        const float de = delta[(size_t)m * DINNER + d];
        const float x  = xc_act[(size_t)m * DINNER + d];
        const float dx = de * x;
        const float* bc = dbc + (size_t)m * 64 + 32;
        float Bv[DSTATE];
#pragma unroll
        for (int q = 0; q < 4; ++q) {
            float4 b4 = *(const float4*)(bc + q * 4);
            Bv[q * 4 + 0] = b4.x; Bv[q * 4 + 1] = b4.y;
            Bv[q * 4 + 2] = b4.z; Bv[q * 4 + 3] = b4.w;
        }
#pragma unroll
        for (int s = 0; s < DSTATE; ++s) {
            const float dA = __expf(de * Af[s]);
            ap[s] *= dA;
            h[s] = dA * h[s] + dx * Bv[s];
        }
    }
    const size_t base = (size_t)(b * DINNER + d) * DSTATE;
#pragma unroll
    for (int s = 0; s < DSTATE; ++s) {
        hfin [(base + s) * NSEG + g] = h[s];
        aprod[(base + s) * NSEG + g] = ap[s];
    }
}

// ---------------------------------------------------------------------------
// K6: combine: wave-parallel Hillis-Steele scan over 64 segments.
// ---------------------------------------------------------------------------
__global__ __launch_bounds__(256) void k_scan_combine(
    float* __restrict__ hfin, const float* __restrict__ aprod)
{
    const int tid = blockIdx.x * 256 + threadIdx.x;   // < NST*NSEG
    const int g = tid & 63;
    const size_t bds = (size_t)(tid >> 6);
    float A = aprod[bds * NSEG + g];
    float B = hfin [bds * NSEG + g];
#pragma unroll
    for (int off = 1; off < 64; off <<= 1) {
        const float Ap = __shfl_up(A, off, 64);
        const float Bp = __shfl_up(B, off, 64);
        if (g >= off) { B = A * Bp + B; A = A * Ap; }
    }
    const float hprev = __shfl_up(B, 1, 64);
    hfin[bds * NSEG + g] = (g == 0) ? 0.f : hprev;
}

// ---------------------------------------------------------------------------
// K7: scan phase C: one thread per (g, b, d), 16 states in registers.
// ---------------------------------------------------------------------------
__global__ __launch_bounds__(256) void k_scan_final(
    const float* __restrict__ delta, const float* __restrict__ xc_act,
    const float* __restrict__ dbc, const float* __restrict__ A_log,
    const float* __restrict__ Dp, const float* __restrict__ zbuf,
    const float* __restrict__ hin, float* __restrict__ yz)
{
    const int gid = blockIdx.x * 256 + threadIdx.x;   // < NSCAN
    const int d = gid & 1023;
    const int b = (gid >> 10) & (NB - 1);
    const int g = gid >> 11;

    float Af[DSTATE];
#pragma unroll
    for (int q = 0; q < 4; ++q) {
        float4 a4 = *(const float4*)(A_log + d * DSTATE + q * 4);
        Af[q * 4 + 0] = -__expf(a4.x);
        Af[q * 4 + 1] = -__expf(a4.y);
        Af[q * 4 + 2] = -__expf(a4.z);
        Af[q * 4 + 3] = -__expf(a4.w);
    }
    const float Dd = Dp[d];

    const size_t base = (size_t)(b * DINNER + d) * DSTATE;
    float h[DSTATE];
#pragma unroll
    for (int s = 0; s < DSTATE; ++s) h[s] = hin[(base + s) * NSEG + g];

    const int mbase = b * LL + g * SEGLEN;
    for (int ll = 0; ll < SEGLEN; ++ll) {
        const int m = mbase + ll;
        const float de = delta[(size_t)m * DINNER + d];
        const float x  = xc_act[(size_t)m * DINNER + d];
        const float zz = zbuf[(size_t)m * DINNER + d];
        const float dx = de * x;
        const float* bc = dbc + (size_t)m * 64;
        float Bv[DSTATE], Cv[DSTATE];
#pragma unroll
        for (int q = 0; q < 4; ++q) {
            float4 b4 = *(const float4*)(bc + 32 + q * 4);
            float4 c4 = *(const float4*)(bc + 48 + q * 4);
            Bv[q * 4 + 0] = b4.x; Bv[q * 4 + 1] = b4.y;
            Bv[q * 4 + 2] = b4.z; Bv[q * 4 + 3] = b4.w;
            Cv[q * 4 + 0] = c4.x; Cv[q * 4 + 1] = c4.y;
            Cv[q * 4 + 2] = c4.z; Cv[q * 4 + 3] = c4.w;
        }
        float y0 = 0.f, y1 = 0.f, y2 = 0.f, y3 = 0.f;
#pragma unroll
        for (int s = 0; s < DSTATE; s += 4) {
            float dA;
            dA = __expf(de * Af[s + 0]); h[s + 0] = dA * h[s + 0] + dx * Bv[s + 0]; y0 += h[s + 0] * Cv[s + 0];
            dA = __expf(de * Af[s + 1]); h[s + 1] = dA * h[s + 1] + dx * Bv[s + 1]; y1 += h[s + 1] * Cv[s + 1];
            dA = __expf(de * Af[s + 2]); h[s + 2] = dA * h[s + 2] + dx * Bv[s + 2]; y2 += h[s + 2] * Cv[s + 2];
            dA = __expf(de * Af[s + 3]); h[s + 3] = dA * h[s + 3] + dx * Bv[s + 3]; y3 += h[s + 3] * Cv[s + 3];
        }
        const float y = (y0 + y1) + (y2 + y3);
        yz[(size_t)m * DINNER + d] = (y + Dd * x) * silu_f(zz);
    }
}

// ---------------------------------------------------------------------------
// K8: out_proj GEMM (bf16 MFMA) + de-interleave scatter + residual add.
// ---------------------------------------------------------------------------
__global__ __launch_bounds__(256) void k_outproj(
    const float* __restrict__ yz, const float* __restrict__ Wo,
    const float* __restrict__ t0, const float* __restrict__ t1,
    const float* __restrict__ t2, const float* __restrict__ t3,
    float* __restrict__ outp)
{
    __shared__ short As[128 * 40];
    __shared__ short Bs[128 * 40];
    const int t = threadIdx.x;
    const int lane = t & 63;
    const int wid = t >> 6;
    const int wm = wid >> 1, wn = wid & 1;
    const int bm = blockIdx.x, bn = blockIdx.y;

    const int srow  = t >> 1;
    const int shalf = (t & 1) * 16;

    const float* asrc = yz + (size_t)(bm * 128 + srow) * DINNER + shalf;
    const float* bsrc = Wo + (size_t)(bn * 128 + srow) * DINNER + shalf;

    f32x4 acc[4][4];
#pragma unroll
    for (int i = 0; i < 4; ++i)
#pragma unroll
        for (int j = 0; j < 4; ++j) acc[i][j] = (f32x4){0.f, 0.f, 0.f, 0.f};

    float4 ra[4], rb[4];
#pragma unroll
    for (int q = 0; q < 4; ++q) {
        ra[q] = *(const float4*)(asrc + q * 4);
        rb[q] = *(const float4*)(bsrc + q * 4);
    }

    const int ko = (lane >> 4) * 8;
    const int fr = lane & 15;

    for (int ks = 0; ks < DINNER / 32; ++ks) {
        __syncthreads();
        {
            bf16x8 v0, v1, w0, w1;
            v0[0]=f2b(ra[0].x); v0[1]=f2b(ra[0].y); v0[2]=f2b(ra[0].z); v0[3]=f2b(ra[0].w);
            v0[4]=f2b(ra[1].x); v0[5]=f2b(ra[1].y); v0[6]=f2b(ra[1].z); v0[7]=f2b(ra[1].w);
            v1[0]=f2b(ra[2].x); v1[1]=f2b(ra[2].y); v1[2]=f2b(ra[2].z); v1[3]=f2b(ra[2].w);
            v1[4]=f2b(ra[3].x); v1[5]=f2b(ra[3].y); v1[6]=f2b(ra[3].z); v1[7]=f2b(ra[3].w);
            w0[0]=f2b(rb[0].x); w0[1]=f2b(rb[0].y); w0[2]=f2b(rb[0].z); w0[3]=f2b(rb[0].w);
            w0[4]=f2b(rb[1].x); w0[5]=f2b(rb[1].y); w0[6]=f2b(rb[1].z); w0[7]=f2b(rb[1].w);
            w1[0]=f2b(rb[2].x); w1[1]=f2b(rb[2].y); w1[2]=f2b(rb[2].z); w1[3]=f2b(rb[2].w);
            w1[4]=f2b(rb[3].x); w1[5]=f2b(rb[3].y); w1[6]=f2b(rb[3].z); w1[7]=f2b(rb[3].w);
            *(bf16x8*)&As[srow * 40 + shalf]     = v0;
            *(bf16x8*)&As[srow * 40 + shalf + 8] = v1;
            *(bf16x8*)&Bs[srow * 40 + shalf]     = w0;
            *(bf16x8*)&Bs[srow * 40 + shalf + 8] = w1;
        }
        __syncthreads();
        if (ks + 1 < DINNER / 32) {
            const int k0 = (ks + 1) * 32;
#pragma unroll
            for (int q = 0; q < 4; ++q) {
                ra[q] = *(const float4*)(asrc + k0 + q * 4);
                rb[q] = *(const float4*)(bsrc + k0 + q * 4);
            }
        }
        bf16x8 af[4], bfr[4];
#pragma unroll
        for (int mf = 0; mf < 4; ++mf)
            af[mf] = *(const bf16x8*)&As[(wm * 64 + mf * 16 + fr) * 40 + ko];
#pragma unroll
        for (int nf = 0; nf < 4; ++nf)
            bfr[nf] = *(const bf16x8*)&Bs[(wn * 64 + nf * 16 + fr) * 40 + ko];
#pragma unroll
        for (int mf = 0; mf < 4; ++mf)
#pragma unroll
            for (int nf = 0; nf < 4; ++nf)
                acc[mf][nf] = __builtin_amdgcn_mfma_f32_16x16x32_bf16(
                    af[mf], bfr[nf], acc[mf][nf], 0, 0, 0);
    }

#pragma unroll
    for (int mf = 0; mf < 4; ++mf) {
#pragma unroll
        for (int j = 0; j < 4; ++j) {
            const int gm = bm * 128 + wm * 64 + mf * 16 + (lane >> 4) * 4 + j;
            const int b = gm >> 11;
            const int l = gm & 2047;
            const int ii = l & 3;
            const int jj = l >> 2;
            const float* tsel = (ii == 0) ? t0 : (ii == 1) ? t1 : (ii == 2) ? t2 : t3;
#pragma unroll
            for (int nf = 0; nf < 4; ++nf) {
                const int gn = bn * 128 + wn * 64 + nf * 16 + (lane & 15);
                const float tv = tsel[((size_t)b * 512 + jj) * 512 + gn];
                outp[(((size_t)ii * NB + b) * 512 + jj) * 512 + gn] = acc[mf][nf][j] + tv;
            }
        }
    }
}

// ---------------------------------------------------------------------------
extern "C" void kernel_launch(void* const* d_in, const int* in_sizes, int n_in,
                              void* d_out, int out_size, void* d_ws, size_t ws_size,
                              hipStream_t stream)
{
    const float* t0 = (const float*)d_in[0];
    const float* t1 = (const float*)d_in[1];
    const float* t2 = (const float*)d_in[2];
    const float* t3 = (const float*)d_in[3];
    const float* in_proj_w  = (const float*)d_in[4];
    const float* conv_w     = (const float*)d_in[5];
    const float* conv_b     = (const float*)d_in[6];
    const float* x_proj_w   = (const float*)d_in[7];
    const float* dt_w       = (const float*)d_in[8];
    const float* dt_b       = (const float*)d_in[9];
    const float* A_log      = (const float*)d_in[10];
    const float* D_param    = (const float*)d_in[11];
    const float* out_proj_w = (const float*)d_in[12];
    float* outp = (float*)d_out;

    // workspace carve (fp32).  Aliasing timeline (stream-ordered, audited):
    // 1 inproj:   W xc_raw, zbuf
    // 2 conv:     R xc_raw          -> W xc_act, xc_b (delta region)
    // 3 cvt_wx:   W wxb (xc_raw+2M) [xc_raw dead]
    // 4 xproj:    R xc_b, wxb       -> W part (xc_raw 0..2M)
    // 5 xreduce:  R part            -> W dbc
    // 6 dtproj:   R dbc, dt_w       -> W delta [xc_b dead]
    // 7 scanA:    R delta,xc_act,dbc-> W hfin, aprod (xc_raw 0..2M, part dead)
    // 8 combine:  R hfin, aprod     -> W hfin (in place, wave-local)
    // 9 scanC:    R delta,xc_act,dbc,hfin,zbuf -> W yz (xc_raw; aprod dead)
    // 10 outproj: R yz, Wo, t*      -> W outp
    float* xc_raw = (float*)d_ws;                          // 4M floats
    float* zbuf   = xc_raw + (size_t)MM * DINNER;          // 4M
    float* xc_act = zbuf   + (size_t)MM * DINNER;          // 4M
    float* delta  = xc_act + (size_t)MM * DINNER;          // 4M
    float* dbc    = delta  + (size_t)MM * DINNER;          // 256K
    float* hfin   = dbc    + (size_t)MM * 64;              // 2M (NST*NSEG)
    float* yz     = xc_raw;                                // alias
    float* part   = xc_raw;                                // alias (2M floats)
    float* aprod  = xc_raw;                                // alias (2M floats)
    unsigned short* wxb  = (unsigned short*)(xc_raw + (size_t)KCH * MM * 64);
    unsigned short* xc_b = (unsigned short*)delta;         // alias (2M floats)

    k_inproj<<<dim3(32, 16), 256, 0, stream>>>(t0, t1, t2, t3, in_proj_w, xc_raw, zbuf);
    k_conv<<<MM / 4, 256, 0, stream>>>(xc_raw, conv_w, conv_b, xc_act, xc_b);
    k_cvt_wx<<<64, 256, 0, stream>>>(x_proj_w, wxb);
    k_xproj_mfma<<<dim3(32, KCH), 256, 0, stream>>>(xc_b, wxb, part);
    k_xreduce<<<(MM * 64) / 256, 256, 0, stream>>>(part, dbc);
    k_dtproj_mfma<<<dim3(32, 8), 256, 0, stream>>>(dbc, dt_w, dt_b, delta);
    k_scan_partial<<<NSCAN / 256, 256, 0, stream>>>(delta, xc_act, dbc, A_log, hfin, aprod);
    k_scan_combine<<<(NST * NSEG) / 256, 256, 0, stream>>>(hfin, aprod);
    k_scan_final<<<NSCAN / 256, 256, 0, stream>>>(delta, xc_act, dbc, A_log, D_param, zbuf, hfin, yz);
    k_outproj<<<dim3(32, 4), 256, 0, stream>>>(yz, out_proj_w, t0, t1, t2, t3, outp);
}

// Round 8
// 212.580 us; speedup vs baseline: 4.1150x; 1.0467x over previous
//
#include <hip/hip_runtime.h>

// ---- problem constants ----
#define NB 2          // batch
#define LT 512        // per-tensor seq len
#define LL 2048       // concatenated seq len
#define MM 4096       // NB*LL rows
#define DMODEL 512
#define DINNER 1024
#define DTRANK 32
#define DSTATE 16
#define NSEG 64
#define SEGLEN 32     // NSEG*SEGLEN == LL
#define NST (NB * DINNER * DSTATE)         // 32768 (b,d,s) chains
#define NSCAN (NSEG * NB * DINNER)         // 131072 scan threads
#define KCH 8         // xproj K-chunks (split-K)

typedef short bf16x8 __attribute__((ext_vector_type(8)));
typedef float f32x4  __attribute__((ext_vector_type(4)));

__device__ __forceinline__ float silu_f(float x) { return x / (1.f + __expf(-x)); }
__device__ __forceinline__ short f2b(float f) {
    unsigned u = __float_as_uint(f);
    u += 0x7fffu + ((u >> 16) & 1u);   // RNE
    return (short)(u >> 16);
}

// ---------------------------------------------------------------------------
// K1: fused interleaved gather + in_proj GEMM (bf16 MFMA).
// ---------------------------------------------------------------------------
__global__ __launch_bounds__(256) void k_inproj(
    const float* __restrict__ t0, const float* __restrict__ t1,
    const float* __restrict__ t2, const float* __restrict__ t3,
    const float* __restrict__ W,
    float* __restrict__ xc_raw, float* __restrict__ zbuf)
{
    __shared__ short As[128 * 40];   // 32 cols + 8 pad (80B row stride)
    __shared__ short Bs[128 * 40];
    const int t = threadIdx.x;
    const int lane = t & 63;
    const int wid = t >> 6;
    const int wm = wid >> 1, wn = wid & 1;
    const int bm = blockIdx.x, bn = blockIdx.y;

    const int srow  = t >> 1;          // 0..127 staging row
    const int shalf = (t & 1) * 16;    // 0 or 16 (col offset)

    const int arow = bm * 128 + srow;
    const int gb = arow >> 11;
    const int gl = arow & 2047;
    const int gc = gl >> 7, gr = gl & 127;
    const int ti = gc & 3, ci = gc >> 2;
    const float* tp = (ti == 0) ? t0 : (ti == 1) ? t1 : (ti == 2) ? t2 : t3;
    const float* asrc = tp + ((size_t)gb * 512 + (size_t)(ci + 4 * gr)) * 512 + shalf;
    const float* bsrc = W + (size_t)(bn * 128 + srow) * 512 + shalf;

    f32x4 acc[4][4];
#pragma unroll
    for (int i = 0; i < 4; ++i)
#pragma unroll
        for (int j = 0; j < 4; ++j) acc[i][j] = (f32x4){0.f, 0.f, 0.f, 0.f};

    float4 ra[4], rb[4];
#pragma unroll
    for (int q = 0; q < 4; ++q) {
        ra[q] = *(const float4*)(asrc + q * 4);
        rb[q] = *(const float4*)(bsrc + q * 4);
    }

    const int ko = (lane >> 4) * 8;
    const int fr = lane & 15;

    for (int ks = 0; ks < 512 / 32; ++ks) {
        __syncthreads();
        {
            bf16x8 v0, v1, w0, w1;
            v0[0]=f2b(ra[0].x); v0[1]=f2b(ra[0].y); v0[2]=f2b(ra[0].z); v0[3]=f2b(ra[0].w);
            v0[4]=f2b(ra[1].x); v0[5]=f2b(ra[1].y); v0[6]=f2b(ra[1].z); v0[7]=f2b(ra[1].w);
            v1[0]=f2b(ra[2].x); v1[1]=f2b(ra[2].y); v1[2]=f2b(ra[2].z); v1[3]=f2b(ra[2].w);
            v1[4]=f2b(ra[3].x); v1[5]=f2b(ra[3].y); v1[6]=f2b(ra[3].z); v1[7]=f2b(ra[3].w);
            w0[0]=f2b(rb[0].x); w0[1]=f2b(rb[0].y); w0[2]=f2b(rb[0].z); w0[3]=f2b(rb[0].w);
            w0[4]=f2b(rb[1].x); w0[5]=f2b(rb[1].y); w0[6]=f2b(rb[1].z); w0[7]=f2b(rb[1].w);
            w1[0]=f2b(rb[2].x); w1[1]=f2b(rb[2].y); w1[2]=f2b(rb[2].z); w1[3]=f2b(rb[2].w);
            w1[4]=f2b(rb[3].x); w1[5]=f2b(rb[3].y); w1[6]=f2b(rb[3].z); w1[7]=f2b(rb[3].w);
            *(bf16x8*)&As[srow * 40 + shalf]     = v0;
            *(bf16x8*)&As[srow * 40 + shalf + 8] = v1;
            *(bf16x8*)&Bs[srow * 40 + shalf]     = w0;
            *(bf16x8*)&Bs[srow * 40 + shalf + 8] = w1;
        }
        __syncthreads();
        if (ks + 1 < 512 / 32) {
            const int k0 = (ks + 1) * 32;
#pragma unroll
            for (int q = 0; q < 4; ++q) {
                ra[q] = *(const float4*)(asrc + k0 + q * 4);
                rb[q] = *(const float4*)(bsrc + k0 + q * 4);
            }
        }
        bf16x8 af[4], bfr[4];
#pragma unroll
        for (int mf = 0; mf < 4; ++mf)
            af[mf] = *(const bf16x8*)&As[(wm * 64 + mf * 16 + fr) * 40 + ko];
#pragma unroll
        for (int nf = 0; nf < 4; ++nf)
            bfr[nf] = *(const bf16x8*)&Bs[(wn * 64 + nf * 16 + fr) * 40 + ko];
#pragma unroll
        for (int mf = 0; mf < 4; ++mf)
#pragma unroll
            for (int nf = 0; nf < 4; ++nf)
                acc[mf][nf] = __builtin_amdgcn_mfma_f32_16x16x32_bf16(
                    af[mf], bfr[nf], acc[mf][nf], 0, 0, 0);
    }

    float* dst = (bn < 8) ? xc_raw : zbuf;
    const int coladj = (bn < 8) ? 0 : 1024;
#pragma unroll
    for (int mf = 0; mf < 4; ++mf) {
        const int gmb = bm * 128 + wm * 64 + mf * 16 + (lane >> 4) * 4;
#pragma unroll
        for (int nf = 0; nf < 4; ++nf) {
            const int gn = bn * 128 + wn * 64 + nf * 16 + (lane & 15) - coladj;
#pragma unroll
            for (int j = 0; j < 4; ++j)
                dst[(size_t)(gmb + j) * DINNER + gn] = acc[mf][nf][j];
        }
    }
}

// ---------------------------------------------------------------------------
// K2: causal depthwise conv1d (K=4, left pad 3) + bias + SiLU.
// One thread: 4 channels (float4 along d) x 4 timesteps (row reuse).
// ---------------------------------------------------------------------------
__global__ __launch_bounds__(256) void k_conv(
    const float* __restrict__ xc_raw, const float* __restrict__ cw,
    const float* __restrict__ cb, float* __restrict__ xc_act,
    unsigned short* __restrict__ xc_b)
{
    const int d0 = threadIdx.x * 4;           // 0..1020
    const int m0 = blockIdx.x * 4;            // group of 4 rows, within one batch
    const int l0 = m0 & 2047;

    float4 w[4];
#pragma unroll
    for (int c = 0; c < 4; ++c) w[c] = *(const float4*)(cw + (size_t)(d0 + c) * 4);
    const float4 bb = *(const float4*)(cb + d0);

    float4 row[7];
#pragma unroll
    for (int o = 0; o < 7; ++o) {
        const int l = l0 + o - 3;
        if (l >= 0)
            row[o] = *(const float4*)(xc_raw + (size_t)(m0 + o - 3) * DINNER + d0);
        else
            row[o] = (float4){0.f, 0.f, 0.f, 0.f};
    }

#pragma unroll
    for (int mm = 0; mm < 4; ++mm) {
        float4 s = bb;
#pragma unroll
        for (int k = 0; k < 4; ++k) {
            const float4 r = row[mm + k];
            s.x += ((const float*)&w[0])[k] * r.x;
            s.y += ((const float*)&w[1])[k] * r.y;
            s.z += ((const float*)&w[2])[k] * r.z;
            s.w += ((const float*)&w[3])[k] * r.w;
        }
        float4 a;
        a.x = silu_f(s.x); a.y = silu_f(s.y); a.z = silu_f(s.z); a.w = silu_f(s.w);
        const size_t idx = (size_t)(m0 + mm) * DINNER + d0;
        *(float4*)(xc_act + idx) = a;
        ushort4 ob;
        ob.x = (unsigned short)f2b(a.x);
        ob.y = (unsigned short)f2b(a.y);
        ob.z = (unsigned short)f2b(a.z);
        ob.w = (unsigned short)f2b(a.w);
        *(ushort4*)(xc_b + idx) = ob;
    }
}

// ---------------------------------------------------------------------------
// K2b: convert x_proj_w (64x1024 f32) -> bf16
// ---------------------------------------------------------------------------
__global__ __launch_bounds__(256) void k_cvt_wx(
    const float* __restrict__ Wx, unsigned short* __restrict__ wxb)
{
    const int i4 = blockIdx.x * 256 + threadIdx.x;    // < 16384
    float4 v = *(const float4*)(Wx + (size_t)i4 * 4);
    ushort4 o;
    o.x = (unsigned short)f2b(v.x);
    o.y = (unsigned short)f2b(v.y);
    o.z = (unsigned short)f2b(v.z);
    o.w = (unsigned short)f2b(v.w);
    *(ushort4*)(wxb + (size_t)i4 * 4) = o;
}

// ---------------------------------------------------------------------------
// K3: xproj split-K MFMA GEMM.
// ---------------------------------------------------------------------------
__global__ __launch_bounds__(256) void k_xproj_mfma(
    const unsigned short* __restrict__ xc_b, const unsigned short* __restrict__ wxb,
    float* __restrict__ part)
{
    __shared__ short As[128 * 136];   // 128 K-cols + 8 pad
    __shared__ short Bs[64 * 136];
    const int t = threadIdx.x;
    const int lane = t & 63;
    const int w = t >> 6;
    const int bm = blockIdx.x;        // 0..31
    const int kc = blockIdx.y;        // 0..7

    {
        const int row = t >> 1;
        const int cb0 = (t & 1) * 64;
        const unsigned short* src = xc_b + (size_t)(bm * 128 + row) * 1024 + kc * 128 + cb0;
#pragma unroll
        for (int q = 0; q < 8; ++q)
            *(bf16x8*)&As[row * 136 + cb0 + q * 8] = *(const bf16x8*)(src + q * 8);
    }
    {
        const int row = t >> 2;
        const int cb0 = (t & 3) * 32;
        const unsigned short* src = wxb + (size_t)row * 1024 + kc * 128 + cb0;
#pragma unroll
        for (int q = 0; q < 4; ++q)
            *(bf16x8*)&Bs[row * 136 + cb0 + q * 8] = *(const bf16x8*)(src + q * 8);
    }
    __syncthreads();

    const int fr = lane & 15;
    const int ko = (lane >> 4) * 8;

    f32x4 acc[2][4];
#pragma unroll
    for (int i = 0; i < 2; ++i)
#pragma unroll
        for (int j = 0; j < 4; ++j) acc[i][j] = (f32x4){0.f, 0.f, 0.f, 0.f};

#pragma unroll
    for (int ks = 0; ks < 4; ++ks) {
        const int kb = ks * 32 + ko;
        bf16x8 af[2], bfr[4];
#pragma unroll
        for (int mf = 0; mf < 2; ++mf)
            af[mf] = *(const bf16x8*)&As[(w * 32 + mf * 16 + fr) * 136 + kb];
#pragma unroll
        for (int nf = 0; nf < 4; ++nf)
            bfr[nf] = *(const bf16x8*)&Bs[(nf * 16 + fr) * 136 + kb];
#pragma unroll
        for (int mf = 0; mf < 2; ++mf)
#pragma unroll
            for (int nf = 0; nf < 4; ++nf)
                acc[mf][nf] = __builtin_amdgcn_mfma_f32_16x16x32_bf16(
                    af[mf], bfr[nf], acc[mf][nf], 0, 0, 0);
    }

    float* pb = part + (size_t)kc * (MM * 64);
#pragma unroll
    for (int mf = 0; mf < 2; ++mf) {
        const int rb = bm * 128 + w * 32 + mf * 16 + (lane >> 4) * 4;
#pragma unroll
        for (int nf = 0; nf < 4; ++nf) {
            const int col = nf * 16 + (lane & 15);
#pragma unroll
            for (int j = 0; j < 4; ++j)
                pb[(size_t)(rb + j) * 64 + col] = acc[mf][nf][j];
        }
    }
}

// ---------------------------------------------------------------------------
// K3b: reduce split-K partials -> dbc
// ---------------------------------------------------------------------------
__global__ __launch_bounds__(256) void k_xreduce(
    const float* __restrict__ part, float* __restrict__ dbc)
{
    const int i = blockIdx.x * 256 + threadIdx.x;    // < MM*64
    float s = 0.f;
#pragma unroll
    for (int kc = 0; kc < KCH; ++kc)
        s += part[(size_t)kc * (MM * 64) + i];
    dbc[i] = s;
}

// ---------------------------------------------------------------------------
// K4: dtproj, broadcast-LDS VALU version (fp32 exact).
// delta[m][d] = softplus(sum_r dbc[m][r]*dt_w[d][r] + dt_b[d]), K=32.
// Block: 32 m-rows x 256 d-cols; grid (128, 4) = 512 blocks, 2/CU.
// dbc rows staged in LDS (broadcast reads); dt_w row per thread in regs.
// ---------------------------------------------------------------------------
__global__ __launch_bounds__(256) void k_dtproj(
    const float* __restrict__ dbc, const float* __restrict__ dtw,
    const float* __restrict__ dtb, float* __restrict__ delta)
{
    __shared__ float dbcS[32 * 32];
    const int tid = threadIdx.x;
    const int m0 = blockIdx.x * 32;
    const int d  = blockIdx.y * 256 + tid;

    // stage dbc[m0..m0+31][0..31]: 1024 floats, one float4 per thread
    {
        const int r = tid >> 3;          // 0..31
        const int c = (tid & 7) * 4;     // 0..28
        *(float4*)&dbcS[r * 32 + c] = *(const float4*)(dbc + (size_t)(m0 + r) * 64 + c);
    }

    float w[DTRANK];
#pragma unroll
    for (int q = 0; q < 8; ++q) {
        float4 v = *(const float4*)(dtw + (size_t)d * DTRANK + q * 4);
        w[q * 4 + 0] = v.x; w[q * 4 + 1] = v.y;
        w[q * 4 + 2] = v.z; w[q * 4 + 3] = v.w;
    }
    const float bias = dtb[d];
    __syncthreads();

    for (int m = 0; m < 32; ++m) {
        float s0 = bias, s1 = 0.f, s2 = 0.f, s3 = 0.f;
#pragma unroll
        for (int r = 0; r < DTRANK; r += 4) {
            float4 bv = *(const float4*)&dbcS[m * 32 + r];
            s0 += bv.x * w[r + 0];
            s1 += bv.y * w[r + 1];
            s2 += bv.z * w[r + 2];
            s3 += bv.w * w[r + 3];
        }
        const float s = (s0 + s1) + (s2 + s3);
        const float sp = (s > 20.f) ? s : log1pf(__expf(s));
        delta[(size_t)(m0 + m) * DINNER + d] = sp;
    }
}

// ---------------------------------------------------------------------------
// K5: scan phase A: one thread per (g, b, d), ALL 16 states in registers.
// ---------------------------------------------------------------------------
__global__ __launch_bounds__(256) void k_scan_partial(
    const float* __restrict__ delta, const float* __restrict__ xc_act,
    const float* __restrict__ dbc, const float* __restrict__ A_log,
    float* __restrict__ hfin, float* __restrict__ aprod)
{
    const int gid = blockIdx.x * 256 + threadIdx.x;   // < NSCAN
    const int d = gid & 1023;
    const int b = (gid >> 10) & (NB - 1);
    const int g = gid >> 11;                           // 0..63

    float Af[DSTATE];
#pragma unroll
    for (int q = 0; q < 4; ++q) {
        float4 a4 = *(const float4*)(A_log + d * DSTATE + q * 4);
        Af[q * 4 + 0] = -__expf(a4.x);
        Af[q * 4 + 1] = -__expf(a4.y);
        Af[q * 4 + 2] = -__expf(a4.z);
        Af[q * 4 + 3] = -__expf(a4.w);
    }

    float h[DSTATE], ap[DSTATE];
#pragma unroll
    for (int s = 0; s < DSTATE; ++s) { h[s] = 0.f; ap[s] = 1.f; }

    const int mbase = b * LL + g * SEGLEN;
    for (int ll = 0; ll < SEGLEN; ++ll) {
        const int m = mbase + ll;
        const float de = delta[(size_t)m * DINNER + d];
        const float x  = xc_act[(size_t)m * DINNER + d];
        const float dx = de * x;
        const float* bc = dbc + (size_t)m * 64 + 32;
        float Bv[DSTATE];
#pragma unroll
        for (int q = 0; q < 4; ++q) {
            float4 b4 = *(const float4*)(bc + q * 4);
            Bv[q * 4 + 0] = b4.x; Bv[q * 4 + 1] = b4.y;
            Bv[q * 4 + 2] = b4.z; Bv[q * 4 + 3] = b4.w;
        }
#pragma unroll
        for (int s = 0; s < DSTATE; ++s) {
            const float dA = __expf(de * Af[s]);
            ap[s] *= dA;
            h[s] = dA * h[s] + dx * Bv[s];
        }
    }
    const size_t base = (size_t)(b * DINNER + d) * DSTATE;
#pragma unroll
    for (int s = 0; s < DSTATE; ++s) {
        hfin [(base + s) * NSEG + g] = h[s];
        aprod[(base + s) * NSEG + g] = ap[s];
    }
}

// ---------------------------------------------------------------------------
// K6: combine: wave-parallel Hillis-Steele scan over 64 segments.
// ---------------------------------------------------------------------------
__global__ __launch_bounds__(256) void k_scan_combine(
    float* __restrict__ hfin, const float* __restrict__ aprod)
{
    const int tid = blockIdx.x * 256 + threadIdx.x;   // < NST*NSEG
    const int g = tid & 63;
    const size_t bds = (size_t)(tid >> 6);
    float A = aprod[bds * NSEG + g];
    float B = hfin [bds * NSEG + g];
#pragma unroll
    for (int off = 1; off < 64; off <<= 1) {
        const float Ap = __shfl_up(A, off, 64);
        const float Bp = __shfl_up(B, off, 64);
        if (g >= off) { B = A * Bp + B; A = A * Ap; }
    }
    const float hprev = __shfl_up(B, 1, 64);
    hfin[bds * NSEG + g] = (g == 0) ? 0.f : hprev;
}

// ---------------------------------------------------------------------------
// K7: scan phase C: one thread per (g, b, d), 16 states in registers.
// ---------------------------------------------------------------------------
__global__ __launch_bounds__(256) void k_scan_final(
    const float* __restrict__ delta, const float* __restrict__ xc_act,
    const float* __restrict__ dbc, const float* __restrict__ A_log,
    const float* __restrict__ Dp, const float* __restrict__ zbuf,
    const float* __restrict__ hin, float* __restrict__ yz)
{
    const int gid = blockIdx.x * 256 + threadIdx.x;   // < NSCAN
    const int d = gid & 1023;
    const int b = (gid >> 10) & (NB - 1);
    const int g = gid >> 11;

    float Af[DSTATE];
#pragma unroll
    for (int q = 0; q < 4; ++q) {
        float4 a4 = *(const float4*)(A_log + d * DSTATE + q * 4);
        Af[q * 4 + 0] = -__expf(a4.x);
        Af[q * 4 + 1] = -__expf(a4.y);
        Af[q * 4 + 2] = -__expf(a4.z);
        Af[q * 4 + 3] = -__expf(a4.w);
    }
    const float Dd = Dp[d];

    const size_t base = (size_t)(b * DINNER + d) * DSTATE;
    float h[DSTATE];
#pragma unroll
    for (int s = 0; s < DSTATE; ++s) h[s] = hin[(base + s) * NSEG + g];

    const int mbase = b * LL + g * SEGLEN;
    for (int ll = 0; ll < SEGLEN; ++ll) {
        const int m = mbase + ll;
        const float de = delta[(size_t)m * DINNER + d];
        const float x  = xc_act[(size_t)m * DINNER + d];
        const float zz = zbuf[(size_t)m * DINNER + d];
        const float dx = de * x;
        const float* bc = dbc + (size_t)m * 64;
        float Bv[DSTATE], Cv[DSTATE];
#pragma unroll
        for (int q = 0; q < 4; ++q) {
            float4 b4 = *(const float4*)(bc + 32 + q * 4);
            float4 c4 = *(const float4*)(bc + 48 + q * 4);
            Bv[q * 4 + 0] = b4.x; Bv[q * 4 + 1] = b4.y;
            Bv[q * 4 + 2] = b4.z; Bv[q * 4 + 3] = b4.w;
            Cv[q * 4 + 0] = c4.x; Cv[q * 4 + 1] = c4.y;
            Cv[q * 4 + 2] = c4.z; Cv[q * 4 + 3] = c4.w;
        }
        float y0 = 0.f, y1 = 0.f, y2 = 0.f, y3 = 0.f;
#pragma unroll
        for (int s = 0; s < DSTATE; s += 4) {
            float dA;
            dA = __expf(de * Af[s + 0]); h[s + 0] = dA * h[s + 0] + dx * Bv[s + 0]; y0 += h[s + 0] * Cv[s + 0];
            dA = __expf(de * Af[s + 1]); h[s + 1] = dA * h[s + 1] + dx * Bv[s + 1]; y1 += h[s + 1] * Cv[s + 1];
            dA = __expf(de * Af[s + 2]); h[s + 2] = dA * h[s + 2] + dx * Bv[s + 2]; y2 += h[s + 2] * Cv[s + 2];
            dA = __expf(de * Af[s + 3]); h[s + 3] = dA * h[s + 3] + dx * Bv[s + 3]; y3 += h[s + 3] * Cv[s + 3];
        }
        const float y = (y0 + y1) + (y2 + y3);
        yz[(size_t)m * DINNER + d] = (y + Dd * x) * silu_f(zz);
    }
}

// ---------------------------------------------------------------------------
// K8: out_proj GEMM (bf16 MFMA) + de-interleave scatter + residual add.
// ---------------------------------------------------------------------------
__global__ __launch_bounds__(256) void k_outproj(
    const float* __restrict__ yz, const float* __restrict__ Wo,
    const float* __restrict__ t0, const float* __restrict__ t1,
    const float* __restrict__ t2, const float* __restrict__ t3,
    float* __restrict__ outp)
{
    __shared__ short As[128 * 40];
    __shared__ short Bs[128 * 40];
    const int t = threadIdx.x;
    const int lane = t & 63;
    const int wid = t >> 6;
    const int wm = wid >> 1, wn = wid & 1;
    const int bm = blockIdx.x, bn = blockIdx.y;

    const int srow  = t >> 1;
    const int shalf = (t & 1) * 16;

    const float* asrc = yz + (size_t)(bm * 128 + srow) * DINNER + shalf;
    const float* bsrc = Wo + (size_t)(bn * 128 + srow) * DINNER + shalf;

    f32x4 acc[4][4];
#pragma unroll
    for (int i = 0; i < 4; ++i)
#pragma unroll
        for (int j = 0; j < 4; ++j) acc[i][j] = (f32x4){0.f, 0.f, 0.f, 0.f};

    float4 ra[4], rb[4];
#pragma unroll
    for (int q = 0; q < 4; ++q) {
        ra[q] = *(const float4*)(asrc + q * 4);
        rb[q] = *(const float4*)(bsrc + q * 4);
    }

    const int ko = (lane >> 4) * 8;
    const int fr = lane & 15;

    for (int ks = 0; ks < DINNER / 32; ++ks) {
        __syncthreads();
        {
            bf16x8 v0, v1, w0, w1;
            v0[0]=f2b(ra[0].x); v0[1]=f2b(ra[0].y); v0[2]=f2b(ra[0].z); v0[3]=f2b(ra[0].w);
            v0[4]=f2b(ra[1].x); v0[5]=f2b(ra[1].y); v0[6]=f2b(ra[1].z); v0[7]=f2b(ra[1].w);
            v1[0]=f2b(ra[2].x); v1[1]=f2b(ra[2].y); v1[2]=f2b(ra[2].z); v1[3]=f2b(ra[2].w);
            v1[4]=f2b(ra[3].x); v1[5]=f2b(ra[3].y); v1[6]=f2b(ra[3].z); v1[7]=f2b(ra[3].w);
            w0[0]=f2b(rb[0].x); w0[1]=f2b(rb[0].y); w0[2]=f2b(rb[0].z); w0[3]=f2b(rb[0].w);
            w0[4]=f2b(rb[1].x); w0[5]=f2b(rb[1].y); w0[6]=f2b(rb[1].z); w0[7]=f2b(rb[1].w);
            w1[0]=f2b(rb[2].x); w1[1]=f2b(rb[2].y); w1[2]=f2b(rb[2].z); w1[3]=f2b(rb[2].w);
            w1[4]=f2b(rb[3].x); w1[5]=f2b(rb[3].y); w1[6]=f2b(rb[3].z); w1[7]=f2b(rb[3].w);
            *(bf16x8*)&As[srow * 40 + shalf]     = v0;
            *(bf16x8*)&As[srow * 40 + shalf + 8] = v1;
            *(bf16x8*)&Bs[srow * 40 + shalf]     = w0;
            *(bf16x8*)&Bs[srow * 40 + shalf + 8] = w1;
        }
        __syncthreads();
        if (ks + 1 < DINNER / 32) {
            const int k0 = (ks + 1) * 32;
#pragma unroll
            for (int q = 0; q < 4; ++q) {
                ra[q] = *(const float4*)(asrc + k0 + q * 4);
                rb[q] = *(const float4*)(bsrc + k0 + q * 4);
            }
        }
        bf16x8 af[4], bfr[4];
#pragma unroll
        for (int mf = 0; mf < 4; ++mf)
            af[mf] = *(const bf16x8*)&As[(wm * 64 + mf * 16 + fr) * 40 + ko];
#pragma unroll
        for (int nf = 0; nf < 4; ++nf)
            bfr[nf] = *(const bf16x8*)&Bs[(wn * 64 + nf * 16 + fr) * 40 + ko];
#pragma unroll
        for (int mf = 0; mf < 4; ++mf)
#pragma unroll
            for (int nf = 0; nf < 4; ++nf)
                acc[mf][nf] = __builtin_amdgcn_mfma_f32_16x16x32_bf16(
                    af[mf], bfr[nf], acc[mf][nf], 0, 0, 0);
    }

#pragma unroll
    for (int mf = 0; mf < 4; ++mf) {
#pragma unroll
        for (int j = 0; j < 4; ++j) {
            const int gm = bm * 128 + wm * 64 + mf * 16 + (lane >> 4) * 4 + j;
            const int b = gm >> 11;
            const int l = gm & 2047;
            const int ii = l & 3;
            const int jj = l >> 2;
            const float* tsel = (ii == 0) ? t0 : (ii == 1) ? t1 : (ii == 2) ? t2 : t3;
#pragma unroll
            for (int nf = 0; nf < 4; ++nf) {
                const int gn = bn * 128 + wn * 64 + nf * 16 + (lane & 15);
                const float tv = tsel[((size_t)b * 512 + jj) * 512 + gn];
                outp[(((size_t)ii * NB + b) * 512 + jj) * 512 + gn] = acc[mf][nf][j] + tv;
            }
        }
    }
}

// ---------------------------------------------------------------------------
extern "C" void kernel_launch(void* const* d_in, const int* in_sizes, int n_in,
                              void* d_out, int out_size, void* d_ws, size_t ws_size,
                              hipStream_t stream)
{
    const float* t0 = (const float*)d_in[0];
    const float* t1 = (const float*)d_in[1];
    const float* t2 = (const float*)d_in[2];
    const float* t3 = (const float*)d_in[3];
    const float* in_proj_w  = (const float*)d_in[4];
    const float* conv_w     = (const float*)d_in[5];
    const float* conv_b     = (const float*)d_in[6];
    const float* x_proj_w   = (const float*)d_in[7];
    const float* dt_w       = (const float*)d_in[8];
    const float* dt_b       = (const float*)d_in[9];
    const float* A_log      = (const float*)d_in[10];
    const float* D_param    = (const float*)d_in[11];
    const float* out_proj_w = (const float*)d_in[12];
    float* outp = (float*)d_out;

    // workspace carve (fp32).  Aliasing timeline (stream-ordered, audited):
    // 1 inproj:   W xc_raw, zbuf
    // 2 conv:     R xc_raw          -> W xc_act, xc_b (delta region)
    // 3 cvt_wx:   W wxb (xc_raw+2M) [xc_raw dead]
    // 4 xproj:    R xc_b, wxb       -> W part (xc_raw 0..2M)
    // 5 xreduce:  R part            -> W dbc
    // 6 dtproj:   R dbc, dt_w       -> W delta [xc_b dead]
    // 7 scanA:    R delta,xc_act,dbc-> W hfin, aprod (xc_raw 0..2M, part dead)
    // 8 combine:  R hfin, aprod     -> W hfin (in place, wave-local)
    // 9 scanC:    R delta,xc_act,dbc,hfin,zbuf -> W yz (xc_raw; aprod dead)
    // 10 outproj: R yz, Wo, t*      -> W outp
    float* xc_raw = (float*)d_ws;                          // 4M floats
    float* zbuf   = xc_raw + (size_t)MM * DINNER;          // 4M
    float* xc_act = zbuf   + (size_t)MM * DINNER;          // 4M
    float* delta  = xc_act + (size_t)MM * DINNER;          // 4M
    float* dbc    = delta  + (size_t)MM * DINNER;          // 256K
    float* hfin   = dbc    + (size_t)MM * 64;              // 2M (NST*NSEG)
    float* yz     = xc_raw;                                // alias
    float* part   = xc_raw;                                // alias (2M floats)
    float* aprod  = xc_raw;                                // alias (2M floats)
    unsigned short* wxb  = (unsigned short*)(xc_raw + (size_t)KCH * MM * 64);
    unsigned short* xc_b = (unsigned short*)delta;         // alias (2M floats)

    k_inproj<<<dim3(32, 16), 256, 0, stream>>>(t0, t1, t2, t3, in_proj_w, xc_raw, zbuf);
    k_conv<<<MM / 4, 256, 0, stream>>>(xc_raw, conv_w, conv_b, xc_act, xc_b);
    k_cvt_wx<<<64, 256, 0, stream>>>(x_proj_w, wxb);
    k_xproj_mfma<<<dim3(32, KCH), 256, 0, stream>>>(xc_b, wxb, part);
    k_xreduce<<<(MM * 64) / 256, 256, 0, stream>>>(part, dbc);
    k_dtproj<<<dim3(128, 4), 256, 0, stream>>>(dbc, dt_w, dt_b, delta);
    k_scan_partial<<<NSCAN / 256, 256, 0, stream>>>(delta, xc_act, dbc, A_log, hfin, aprod);
    k_scan_combine<<<(NST * NSEG) / 256, 256, 0, stream>>>(hfin, aprod);
    k_scan_final<<<NSCAN / 256, 256, 0, stream>>>(delta, xc_act, dbc, A_log, D_param, zbuf, hfin, yz);
    k_outproj<<<dim3(32, 4), 256, 0, stream>>>(yz, out_proj_w, t0, t1, t2, t3, outp);
}

// Round 9
// 201.522 us; speedup vs baseline: 4.3408x; 1.0549x over previous
//
#include <hip/hip_runtime.h>

// ---- problem constants ----
#define NB 2          // batch
#define LT 512        // per-tensor seq len
#define LL 2048       // concatenated seq len
#define MM 4096       // NB*LL rows
#define DMODEL 512
#define DINNER 1024
#define DTRANK 32
#define DSTATE 16
#define NSEG 64
#define SEGLEN 32     // NSEG*SEGLEN == LL
#define NST (NB * DINNER * DSTATE)         // 32768 (b,d,s) chains
#define NSCAN (NSEG * NB * DINNER)         // 131072 scan threads
#define KCH 8         // xproj K-chunks (split-K)

typedef short bf16x8 __attribute__((ext_vector_type(8)));
typedef float f32x4  __attribute__((ext_vector_type(4)));

__device__ __forceinline__ float silu_f(float x) { return x / (1.f + __expf(-x)); }
__device__ __forceinline__ short f2b(float f) {
    unsigned u = __float_as_uint(f);
    u += 0x7fffu + ((u >> 16) & 1u);   // RNE
    return (short)(u >> 16);
}

// ---------------------------------------------------------------------------
// K1: fused interleaved gather + in_proj GEMM (bf16 MFMA).
// ---------------------------------------------------------------------------
__global__ __launch_bounds__(256) void k_inproj(
    const float* __restrict__ t0, const float* __restrict__ t1,
    const float* __restrict__ t2, const float* __restrict__ t3,
    const float* __restrict__ W,
    float* __restrict__ xc_raw, float* __restrict__ zbuf)
{
    __shared__ short As[128 * 40];   // 32 cols + 8 pad (80B row stride)
    __shared__ short Bs[128 * 40];
    const int t = threadIdx.x;
    const int lane = t & 63;
    const int wid = t >> 6;
    const int wm = wid >> 1, wn = wid & 1;
    const int bm = blockIdx.x, bn = blockIdx.y;

    const int srow  = t >> 1;          // 0..127 staging row
    const int shalf = (t & 1) * 16;    // 0 or 16 (col offset)

    const int arow = bm * 128 + srow;
    const int gb = arow >> 11;
    const int gl = arow & 2047;
    const int gc = gl >> 7, gr = gl & 127;
    const int ti = gc & 3, ci = gc >> 2;
    const float* tp = (ti == 0) ? t0 : (ti == 1) ? t1 : (ti == 2) ? t2 : t3;
    const float* asrc = tp + ((size_t)gb * 512 + (size_t)(ci + 4 * gr)) * 512 + shalf;
    const float* bsrc = W + (size_t)(bn * 128 + srow) * 512 + shalf;

    f32x4 acc[4][4];
#pragma unroll
    for (int i = 0; i < 4; ++i)
#pragma unroll
        for (int j = 0; j < 4; ++j) acc[i][j] = (f32x4){0.f, 0.f, 0.f, 0.f};

    float4 ra[4], rb[4];
#pragma unroll
    for (int q = 0; q < 4; ++q) {
        ra[q] = *(const float4*)(asrc + q * 4);
        rb[q] = *(const float4*)(bsrc + q * 4);
    }

    const int ko = (lane >> 4) * 8;
    const int fr = lane & 15;

    for (int ks = 0; ks < 512 / 32; ++ks) {
        __syncthreads();
        {
            bf16x8 v0, v1, w0, w1;
            v0[0]=f2b(ra[0].x); v0[1]=f2b(ra[0].y); v0[2]=f2b(ra[0].z); v0[3]=f2b(ra[0].w);
            v0[4]=f2b(ra[1].x); v0[5]=f2b(ra[1].y); v0[6]=f2b(ra[1].z); v0[7]=f2b(ra[1].w);
            v1[0]=f2b(ra[2].x); v1[1]=f2b(ra[2].y); v1[2]=f2b(ra[2].z); v1[3]=f2b(ra[2].w);
            v1[4]=f2b(ra[3].x); v1[5]=f2b(ra[3].y); v1[6]=f2b(ra[3].z); v1[7]=f2b(ra[3].w);
            w0[0]=f2b(rb[0].x); w0[1]=f2b(rb[0].y); w0[2]=f2b(rb[0].z); w0[3]=f2b(rb[0].w);
            w0[4]=f2b(rb[1].x); w0[5]=f2b(rb[1].y); w0[6]=f2b(rb[1].z); w0[7]=f2b(rb[1].w);
            w1[0]=f2b(rb[2].x); w1[1]=f2b(rb[2].y); w1[2]=f2b(rb[2].z); w1[3]=f2b(rb[2].w);
            w1[4]=f2b(rb[3].x); w1[5]=f2b(rb[3].y); w1[6]=f2b(rb[3].z); w1[7]=f2b(rb[3].w);
            *(bf16x8*)&As[srow * 40 + shalf]     = v0;
            *(bf16x8*)&As[srow * 40 + shalf + 8] = v1;
            *(bf16x8*)&Bs[srow * 40 + shalf]     = w0;
            *(bf16x8*)&Bs[srow * 40 + shalf + 8] = w1;
        }
        __syncthreads();
        if (ks + 1 < 512 / 32) {
            const int k0 = (ks + 1) * 32;
#pragma unroll
            for (int q = 0; q < 4; ++q) {
                ra[q] = *(const float4*)(asrc + k0 + q * 4);
                rb[q] = *(const float4*)(bsrc + k0 + q * 4);
            }
        }
        bf16x8 af[4], bfr[4];
#pragma unroll
        for (int mf = 0; mf < 4; ++mf)
            af[mf] = *(const bf16x8*)&As[(wm * 64 + mf * 16 + fr) * 40 + ko];
#pragma unroll
        for (int nf = 0; nf < 4; ++nf)
            bfr[nf] = *(const bf16x8*)&Bs[(wn * 64 + nf * 16 + fr) * 40 + ko];
#pragma unroll
        for (int mf = 0; mf < 4; ++mf)
#pragma unroll
            for (int nf = 0; nf < 4; ++nf)
                acc[mf][nf] = __builtin_amdgcn_mfma_f32_16x16x32_bf16(
                    af[mf], bfr[nf], acc[mf][nf], 0, 0, 0);
    }

    float* dst = (bn < 8) ? xc_raw : zbuf;
    const int coladj = (bn < 8) ? 0 : 1024;
#pragma unroll
    for (int mf = 0; mf < 4; ++mf) {
        const int gmb = bm * 128 + wm * 64 + mf * 16 + (lane >> 4) * 4;
#pragma unroll
        for (int nf = 0; nf < 4; ++nf) {
            const int gn = bn * 128 + wn * 64 + nf * 16 + (lane & 15) - coladj;
#pragma unroll
            for (int j = 0; j < 4; ++j)
                dst[(size_t)(gmb + j) * DINNER + gn] = acc[mf][nf][j];
        }
    }
}

// ---------------------------------------------------------------------------
// K2: causal depthwise conv1d (K=4, left pad 3) + bias + SiLU.
// One thread: 4 channels (float4 along d) x 4 timesteps (row reuse).
// ---------------------------------------------------------------------------
__global__ __launch_bounds__(256) void k_conv(
    const float* __restrict__ xc_raw, const float* __restrict__ cw,
    const float* __restrict__ cb, float* __restrict__ xc_act,
    unsigned short* __restrict__ xc_b)
{
    const int d0 = threadIdx.x * 4;           // 0..1020
    const int m0 = blockIdx.x * 4;            // group of 4 rows, within one batch
    const int l0 = m0 & 2047;

    float4 w[4];
#pragma unroll
    for (int c = 0; c < 4; ++c) w[c] = *(const float4*)(cw + (size_t)(d0 + c) * 4);
    const float4 bb = *(const float4*)(cb + d0);

    float4 row[7];
#pragma unroll
    for (int o = 0; o < 7; ++o) {
        const int l = l0 + o - 3;
        if (l >= 0)
            row[o] = *(const float4*)(xc_raw + (size_t)(m0 + o - 3) * DINNER + d0);
        else
            row[o] = (float4){0.f, 0.f, 0.f, 0.f};
    }

#pragma unroll
    for (int mm = 0; mm < 4; ++mm) {
        float4 s = bb;
#pragma unroll
        for (int k = 0; k < 4; ++k) {
            const float4 r = row[mm + k];
            s.x += ((const float*)&w[0])[k] * r.x;
            s.y += ((const float*)&w[1])[k] * r.y;
            s.z += ((const float*)&w[2])[k] * r.z;
            s.w += ((const float*)&w[3])[k] * r.w;
        }
        float4 a;
        a.x = silu_f(s.x); a.y = silu_f(s.y); a.z = silu_f(s.z); a.w = silu_f(s.w);
        const size_t idx = (size_t)(m0 + mm) * DINNER + d0;
        *(float4*)(xc_act + idx) = a;
        ushort4 ob;
        ob.x = (unsigned short)f2b(a.x);
        ob.y = (unsigned short)f2b(a.y);
        ob.z = (unsigned short)f2b(a.z);
        ob.w = (unsigned short)f2b(a.w);
        *(ushort4*)(xc_b + idx) = ob;
    }
}

// ---------------------------------------------------------------------------
// K2b: convert x_proj_w (64x1024 f32) -> bf16
// ---------------------------------------------------------------------------
__global__ __launch_bounds__(256) void k_cvt_wx(
    const float* __restrict__ Wx, unsigned short* __restrict__ wxb)
{
    const int i4 = blockIdx.x * 256 + threadIdx.x;    // < 16384
    float4 v = *(const float4*)(Wx + (size_t)i4 * 4);
    ushort4 o;
    o.x = (unsigned short)f2b(v.x);
    o.y = (unsigned short)f2b(v.y);
    o.z = (unsigned short)f2b(v.z);
    o.w = (unsigned short)f2b(v.w);
    *(ushort4*)(wxb + (size_t)i4 * 4) = o;
}

// ---------------------------------------------------------------------------
// K3: xproj split-K MFMA GEMM.
// ---------------------------------------------------------------------------
__global__ __launch_bounds__(256) void k_xproj_mfma(
    const unsigned short* __restrict__ xc_b, const unsigned short* __restrict__ wxb,
    float* __restrict__ part)
{
    __shared__ short As[128 * 136];   // 128 K-cols + 8 pad
    __shared__ short Bs[64 * 136];
    const int t = threadIdx.x;
    const int lane = t & 63;
    const int w = t >> 6;
    const int bm = blockIdx.x;        // 0..31
    const int kc = blockIdx.y;        // 0..7

    {
        const int row = t >> 1;
        const int cb0 = (t & 1) * 64;
        const unsigned short* src = xc_b + (size_t)(bm * 128 + row) * 1024 + kc * 128 + cb0;
#pragma unroll
        for (int q = 0; q < 8; ++q)
            *(bf16x8*)&As[row * 136 + cb0 + q * 8] = *(const bf16x8*)(src + q * 8);
    }
    {
        const int row = t >> 2;
        const int cb0 = (t & 3) * 32;
        const unsigned short* src = wxb + (size_t)row * 1024 + kc * 128 + cb0;
#pragma unroll
        for (int q = 0; q < 4; ++q)
            *(bf16x8*)&Bs[row * 136 + cb0 + q * 8] = *(const bf16x8*)(src + q * 8);
    }
    __syncthreads();

    const int fr = lane & 15;
    const int ko = (lane >> 4) * 8;

    f32x4 acc[2][4];
#pragma unroll
    for (int i = 0; i < 2; ++i)
#pragma unroll
        for (int j = 0; j < 4; ++j) acc[i][j] = (f32x4){0.f, 0.f, 0.f, 0.f};

#pragma unroll
    for (int ks = 0; ks < 4; ++ks) {
        const int kb = ks * 32 + ko;
        bf16x8 af[2], bfr[4];
#pragma unroll
        for (int mf = 0; mf < 2; ++mf)
            af[mf] = *(const bf16x8*)&As[(w * 32 + mf * 16 + fr) * 136 + kb];
#pragma unroll
        for (int nf = 0; nf < 4; ++nf)
            bfr[nf] = *(const bf16x8*)&Bs[(nf * 16 + fr) * 136 + kb];
#pragma unroll
        for (int mf = 0; mf < 2; ++mf)
#pragma unroll
            for (int nf = 0; nf < 4; ++nf)
                acc[mf][nf] = __builtin_amdgcn_mfma_f32_16x16x32_bf16(
                    af[mf], bfr[nf], acc[mf][nf], 0, 0, 0);
    }

    float* pb = part + (size_t)kc * (MM * 64);
#pragma unroll
    for (int mf = 0; mf < 2; ++mf) {
        const int rb = bm * 128 + w * 32 + mf * 16 + (lane >> 4) * 4;
#pragma unroll
        for (int nf = 0; nf < 4; ++nf) {
            const int col = nf * 16 + (lane & 15);
#pragma unroll
            for (int j = 0; j < 4; ++j)
                pb[(size_t)(rb + j) * 64 + col] = acc[mf][nf][j];
        }
    }
}

// ---------------------------------------------------------------------------
// K3b: reduce split-K partials -> dbc
// ---------------------------------------------------------------------------
__global__ __launch_bounds__(256) void k_xreduce(
    const float* __restrict__ part, float* __restrict__ dbc)
{
    const int i = blockIdx.x * 256 + threadIdx.x;    // < MM*64
    float s = 0.f;
#pragma unroll
    for (int kc = 0; kc < KCH; ++kc)
        s += part[(size_t)kc * (MM * 64) + i];
    dbc[i] = s;
}

// ---------------------------------------------------------------------------
// K4: dtproj v3 — scalar-uniform dbc loads (SGPR), fast softplus, no LDS.
// delta[m][d] = softplus(sum_r dbc[m][r]*dt_w[d][r] + dt_b[d]), K=32.
// Grid (256, 4): 16 m-rows x 256 d-cols per block, 4 blocks/CU.
// dbc row address is wave-uniform -> compiler emits s_load (SGPR broadcast).
// ---------------------------------------------------------------------------
__global__ __launch_bounds__(256) void k_dtproj(
    const float* __restrict__ dbc, const float* __restrict__ dtw,
    const float* __restrict__ dtb, float* __restrict__ delta)
{
    const int tid = threadIdx.x;
    const int m0 = blockIdx.x * 16;
    const int d  = blockIdx.y * 256 + tid;

    float w[DTRANK];
#pragma unroll
    for (int q = 0; q < 8; ++q) {
        float4 v = *(const float4*)(dtw + (size_t)d * DTRANK + q * 4);
        w[q * 4 + 0] = v.x; w[q * 4 + 1] = v.y;
        w[q * 4 + 2] = v.z; w[q * 4 + 3] = v.w;
    }
    const float bias = dtb[d];

#pragma unroll 4
    for (int m = 0; m < 16; ++m) {
        const float* bc = dbc + (size_t)(m0 + m) * 64;   // wave-uniform address
        float s0 = bias, s1 = 0.f, s2 = 0.f, s3 = 0.f;
#pragma unroll
        for (int r = 0; r < DTRANK; r += 4) {
            s0 += bc[r + 0] * w[r + 0];
            s1 += bc[r + 1] * w[r + 1];
            s2 += bc[r + 2] * w[r + 2];
            s3 += bc[r + 3] * w[r + 3];
        }
        const float s = (s0 + s1) + (s2 + s3);
        const float sp = (s > 20.f) ? s : __logf(1.f + __expf(s));
        delta[(size_t)(m0 + m) * DINNER + d] = sp;
    }
}

// ---------------------------------------------------------------------------
// K5: scan phase A: one thread per (g, b, d), ALL 16 states in registers.
// ---------------------------------------------------------------------------
__global__ __launch_bounds__(256) void k_scan_partial(
    const float* __restrict__ delta, const float* __restrict__ xc_act,
    const float* __restrict__ dbc, const float* __restrict__ A_log,
    float* __restrict__ hfin, float* __restrict__ aprod)
{
    const int gid = blockIdx.x * 256 + threadIdx.x;   // < NSCAN
    const int d = gid & 1023;
    const int b = (gid >> 10) & (NB - 1);
    const int g = gid >> 11;                           // 0..63

    float Af[DSTATE];
#pragma unroll
    for (int q = 0; q < 4; ++q) {
        float4 a4 = *(const float4*)(A_log + d * DSTATE + q * 4);
        Af[q * 4 + 0] = -__expf(a4.x);
        Af[q * 4 + 1] = -__expf(a4.y);
        Af[q * 4 + 2] = -__expf(a4.z);
        Af[q * 4 + 3] = -__expf(a4.w);
    }

    float h[DSTATE], ap[DSTATE];
#pragma unroll
    for (int s = 0; s < DSTATE; ++s) { h[s] = 0.f; ap[s] = 1.f; }

    const int mbase = b * LL + g * SEGLEN;
    for (int ll = 0; ll < SEGLEN; ++ll) {
        const int m = mbase + ll;
        const float de = delta[(size_t)m * DINNER + d];
        const float x  = xc_act[(size_t)m * DINNER + d];
        const float dx = de * x;
        const float* bc = dbc + (size_t)m * 64 + 32;
        float Bv[DSTATE];
#pragma unroll
        for (int q = 0; q < 4; ++q) {
            float4 b4 = *(const float4*)(bc + q * 4);
            Bv[q * 4 + 0] = b4.x; Bv[q * 4 + 1] = b4.y;
            Bv[q * 4 + 2] = b4.z; Bv[q * 4 + 3] = b4.w;
        }
#pragma unroll
        for (int s = 0; s < DSTATE; ++s) {
            const float dA = __expf(de * Af[s]);
            ap[s] *= dA;
            h[s] = dA * h[s] + dx * Bv[s];
        }
    }
    const size_t base = (size_t)(b * DINNER + d) * DSTATE;
#pragma unroll
    for (int s = 0; s < DSTATE; ++s) {
        hfin [(base + s) * NSEG + g] = h[s];
        aprod[(base + s) * NSEG + g] = ap[s];
    }
}

// ---------------------------------------------------------------------------
// K6: combine: wave-parallel Hillis-Steele scan over 64 segments.
// ---------------------------------------------------------------------------
__global__ __launch_bounds__(256) void k_scan_combine(
    float* __restrict__ hfin, const float* __restrict__ aprod)
{
    const int tid = blockIdx.x * 256 + threadIdx.x;   // < NST*NSEG
    const int g = tid & 63;
    const size_t bds = (size_t)(tid >> 6);
    float A = aprod[bds * NSEG + g];
    float B = hfin [bds * NSEG + g];
#pragma unroll
    for (int off = 1; off < 64; off <<= 1) {
        const float Ap = __shfl_up(A, off, 64);
        const float Bp = __shfl_up(B, off, 64);
        if (g >= off) { B = A * Bp + B; A = A * Ap; }
    }
    const float hprev = __shfl_up(B, 1, 64);
    hfin[bds * NSEG + g] = (g == 0) ? 0.f : hprev;
}

// ---------------------------------------------------------------------------
// K7: scan phase C: one thread per (g, b, d), 16 states in registers.
// ---------------------------------------------------------------------------
__global__ __launch_bounds__(256) void k_scan_final(
    const float* __restrict__ delta, const float* __restrict__ xc_act,
    const float* __restrict__ dbc, const float* __restrict__ A_log,
    const float* __restrict__ Dp, const float* __restrict__ zbuf,
    const float* __restrict__ hin, float* __restrict__ yz)
{
    const int gid = blockIdx.x * 256 + threadIdx.x;   // < NSCAN
    const int d = gid & 1023;
    const int b = (gid >> 10) & (NB - 1);
    const int g = gid >> 11;

    float Af[DSTATE];
#pragma unroll
    for (int q = 0; q < 4; ++q) {
        float4 a4 = *(const float4*)(A_log + d * DSTATE + q * 4);
        Af[q * 4 + 0] = -__expf(a4.x);
        Af[q * 4 + 1] = -__expf(a4.y);
        Af[q * 4 + 2] = -__expf(a4.z);
        Af[q * 4 + 3] = -__expf(a4.w);
    }
    const float Dd = Dp[d];

    const size_t base = (size_t)(b * DINNER + d) * DSTATE;
    float h[DSTATE];
#pragma unroll
    for (int s = 0; s < DSTATE; ++s) h[s] = hin[(base + s) * NSEG + g];

    const int mbase = b * LL + g * SEGLEN;
    for (int ll = 0; ll < SEGLEN; ++ll) {
        const int m = mbase + ll;
        const float de = delta[(size_t)m * DINNER + d];
        const float x  = xc_act[(size_t)m * DINNER + d];
        const float zz = zbuf[(size_t)m * DINNER + d];
        const float dx = de * x;
        const float* bc = dbc + (size_t)m * 64;
        float Bv[DSTATE], Cv[DSTATE];
#pragma unroll
        for (int q = 0; q < 4; ++q) {
            float4 b4 = *(const float4*)(bc + 32 + q * 4);
            float4 c4 = *(const float4*)(bc + 48 + q * 4);
            Bv[q * 4 + 0] = b4.x; Bv[q * 4 + 1] = b4.y;
            Bv[q * 4 + 2] = b4.z; Bv[q * 4 + 3] = b4.w;
            Cv[q * 4 + 0] = c4.x; Cv[q * 4 + 1] = c4.y;
            Cv[q * 4 + 2] = c4.z; Cv[q * 4 + 3] = c4.w;
        }
        float y0 = 0.f, y1 = 0.f, y2 = 0.f, y3 = 0.f;
#pragma unroll
        for (int s = 0; s < DSTATE; s += 4) {
            float dA;
            dA = __expf(de * Af[s + 0]); h[s + 0] = dA * h[s + 0] + dx * Bv[s + 0]; y0 += h[s + 0] * Cv[s + 0];
            dA = __expf(de * Af[s + 1]); h[s + 1] = dA * h[s + 1] + dx * Bv[s + 1]; y1 += h[s + 1] * Cv[s + 1];
            dA = __expf(de * Af[s + 2]); h[s + 2] = dA * h[s + 2] + dx * Bv[s + 2]; y2 += h[s + 2] * Cv[s + 2];
            dA = __expf(de * Af[s + 3]); h[s + 3] = dA * h[s + 3] + dx * Bv[s + 3]; y3 += h[s + 3] * Cv[s + 3];
        }
        const float y = (y0 + y1) + (y2 + y3);
        yz[(size_t)m * DINNER + d] = (y + Dd * x) * silu_f(zz);
    }
}

// ---------------------------------------------------------------------------
// K8: out_proj GEMM (bf16 MFMA) + de-interleave scatter + residual add.
// ---------------------------------------------------------------------------
__global__ __launch_bounds__(256) void k_outproj(
    const float* __restrict__ yz, const float* __restrict__ Wo,
    const float* __restrict__ t0, const float* __restrict__ t1,
    const float* __restrict__ t2, const float* __restrict__ t3,
    float* __restrict__ outp)
{
    __shared__ short As[128 * 40];
    __shared__ short Bs[128 * 40];
    const int t = threadIdx.x;
    const int lane = t & 63;
    const int wid = t >> 6;
    const int wm = wid >> 1, wn = wid & 1;
    const int bm = blockIdx.x, bn = blockIdx.y;

    const int srow  = t >> 1;
    const int shalf = (t & 1) * 16;

    const float* asrc = yz + (size_t)(bm * 128 + srow) * DINNER + shalf;
    const float* bsrc = Wo + (size_t)(bn * 128 + srow) * DINNER + shalf;

    f32x4 acc[4][4];
#pragma unroll
    for (int i = 0; i < 4; ++i)
#pragma unroll
        for (int j = 0; j < 4; ++j) acc[i][j] = (f32x4){0.f, 0.f, 0.f, 0.f};

    float4 ra[4], rb[4];
#pragma unroll
    for (int q = 0; q < 4; ++q) {
        ra[q] = *(const float4*)(asrc + q * 4);
        rb[q] = *(const float4*)(bsrc + q * 4);
    }

    const int ko = (lane >> 4) * 8;
    const int fr = lane & 15;

    for (int ks = 0; ks < DINNER / 32; ++ks) {
        __syncthreads();
        {
            bf16x8 v0, v1, w0, w1;
            v0[0]=f2b(ra[0].x); v0[1]=f2b(ra[0].y); v0[2]=f2b(ra[0].z); v0[3]=f2b(ra[0].w);
            v0[4]=f2b(ra[1].x); v0[5]=f2b(ra[1].y); v0[6]=f2b(ra[1].z); v0[7]=f2b(ra[1].w);
            v1[0]=f2b(ra[2].x); v1[1]=f2b(ra[2].y); v1[2]=f2b(ra[2].z); v1[3]=f2b(ra[2].w);
            v1[4]=f2b(ra[3].x); v1[5]=f2b(ra[3].y); v1[6]=f2b(ra[3].z); v1[7]=f2b(ra[3].w);
            w0[0]=f2b(rb[0].x); w0[1]=f2b(rb[0].y); w0[2]=f2b(rb[0].z); w0[3]=f2b(rb[0].w);
            w0[4]=f2b(rb[1].x); w0[5]=f2b(rb[1].y); w0[6]=f2b(rb[1].z); w0[7]=f2b(rb[1].w);
            w1[0]=f2b(rb[2].x); w1[1]=f2b(rb[2].y); w1[2]=f2b(rb[2].z); w1[3]=f2b(rb[2].w);
            w1[4]=f2b(rb[3].x); w1[5]=f2b(rb[3].y); w1[6]=f2b(rb[3].z); w1[7]=f2b(rb[3].w);
            *(bf16x8*)&As[srow * 40 + shalf]     = v0;
            *(bf16x8*)&As[srow * 40 + shalf + 8] = v1;
            *(bf16x8*)&Bs[srow * 40 + shalf]     = w0;
            *(bf16x8*)&Bs[srow * 40 + shalf + 8] = w1;
        }
        __syncthreads();
        if (ks + 1 < DINNER / 32) {
            const int k0 = (ks + 1) * 32;
#pragma unroll
            for (int q = 0; q < 4; ++q) {
                ra[q] = *(const float4*)(asrc + k0 + q * 4);
                rb[q] = *(const float4*)(bsrc + k0 + q * 4);
            }
        }
        bf16x8 af[4], bfr[4];
#pragma unroll
        for (int mf = 0; mf < 4; ++mf)
            af[mf] = *(const bf16x8*)&As[(wm * 64 + mf * 16 + fr) * 40 + ko];
#pragma unroll
        for (int nf = 0; nf < 4; ++nf)
            bfr[nf] = *(const bf16x8*)&Bs[(wn * 64 + nf * 16 + fr) * 40 + ko];
#pragma unroll
        for (int mf = 0; mf < 4; ++mf)
#pragma unroll
            for (int nf = 0; nf < 4; ++nf)
                acc[mf][nf] = __builtin_amdgcn_mfma_f32_16x16x32_bf16(
                    af[mf], bfr[nf], acc[mf][nf], 0, 0, 0);
    }

#pragma unroll
    for (int mf = 0; mf < 4; ++mf) {
#pragma unroll
        for (int j = 0; j < 4; ++j) {
            const int gm = bm * 128 + wm * 64 + mf * 16 + (lane >> 4) * 4 + j;
            const int b = gm >> 11;
            const int l = gm & 2047;
            const int ii = l & 3;
            const int jj = l >> 2;
            const float* tsel = (ii == 0) ? t0 : (ii == 1) ? t1 : (ii == 2) ? t2 : t3;
#pragma unroll
            for (int nf = 0; nf < 4; ++nf) {
                const int gn = bn * 128 + wn * 64 + nf * 16 + (lane & 15);
                const float tv = tsel[((size_t)b * 512 + jj) * 512 + gn];
                outp[(((size_t)ii * NB + b) * 512 + jj) * 512 + gn] = acc[mf][nf][j] + tv;
            }
        }
    }
}

// ---------------------------------------------------------------------------
extern "C" void kernel_launch(void* const* d_in, const int* in_sizes, int n_in,
                              void* d_out, int out_size, void* d_ws, size_t ws_size,
                              hipStream_t stream)
{
    const float* t0 = (const float*)d_in[0];
    const float* t1 = (const float*)d_in[1];
    const float* t2 = (const float*)d_in[2];
    const float* t3 = (const float*)d_in[3];
    const float* in_proj_w  = (const float*)d_in[4];
    const float* conv_w     = (const float*)d_in[5];
    const float* conv_b     = (const float*)d_in[6];
    const float* x_proj_w   = (const float*)d_in[7];
    const float* dt_w       = (const float*)d_in[8];
    const float* dt_b       = (const float*)d_in[9];
    const float* A_log      = (const float*)d_in[10];
    const float* D_param    = (const float*)d_in[11];
    const float* out_proj_w = (const float*)d_in[12];
    float* outp = (float*)d_out;

    // workspace carve (fp32).  Aliasing timeline (stream-ordered, audited):
    // 1 inproj:   W xc_raw, zbuf
    // 2 conv:     R xc_raw          -> W xc_act, xc_b (delta region)
    // 3 cvt_wx:   W wxb (xc_raw+2M) [xc_raw dead]
    // 4 xproj:    R xc_b, wxb       -> W part (xc_raw 0..2M)
    // 5 xreduce:  R part            -> W dbc
    // 6 dtproj:   R dbc, dt_w       -> W delta [xc_b dead]
    // 7 scanA:    R delta,xc_act,dbc-> W hfin, aprod (xc_raw 0..2M, part dead)
    // 8 combine:  R hfin, aprod     -> W hfin (in place, wave-local)
    // 9 scanC:    R delta,xc_act,dbc,hfin,zbuf -> W yz (xc_raw; aprod dead)
    // 10 outproj: R yz, Wo, t*      -> W outp
    float* xc_raw = (float*)d_ws;                          // 4M floats
    float* zbuf   = xc_raw + (size_t)MM * DINNER;          // 4M
    float* xc_act = zbuf   + (size_t)MM * DINNER;          // 4M
    float* delta  = xc_act + (size_t)MM * DINNER;          // 4M
    float* dbc    = delta  + (size_t)MM * DINNER;          // 256K
    float* hfin   = dbc    + (size_t)MM * 64;              // 2M (NST*NSEG)
    float* yz     = xc_raw;                                // alias
    float* part   = xc_raw;                                // alias (2M floats)
    float* aprod  = xc_raw;                                // alias (2M floats)
    unsigned short* wxb  = (unsigned short*)(xc_raw + (size_t)KCH * MM * 64);
    unsigned short* xc_b = (unsigned short*)delta;         // alias (2M floats)

    k_inproj<<<dim3(32, 16), 256, 0, stream>>>(t0, t1, t2, t3, in_proj_w, xc_raw, zbuf);
    k_conv<<<MM / 4, 256, 0, stream>>>(xc_raw, conv_w, conv_b, xc_act, xc_b);
    k_cvt_wx<<<64, 256, 0, stream>>>(x_proj_w, wxb);
    k_xproj_mfma<<<dim3(32, KCH), 256, 0, stream>>>(xc_b, wxb, part);
    k_xreduce<<<(MM * 64) / 256, 256, 0, stream>>>(part, dbc);
    k_dtproj<<<dim3(MM / 16, 4), 256, 0, stream>>>(dbc, dt_w, dt_b, delta);
    k_scan_partial<<<NSCAN / 256, 256, 0, stream>>>(delta, xc_act, dbc, A_log, hfin, aprod);
    k_scan_combine<<<(NST * NSEG) / 256, 256, 0, stream>>>(hfin, aprod);
    k_scan_final<<<NSCAN / 256, 256, 0, stream>>>(delta, xc_act, dbc, A_log, D_param, zbuf, hfin, yz);
    k_outproj<<<dim3(32, 4), 256, 0, stream>>>(yz, out_proj_w, t0, t1, t2, t3, outp);
}

// Round 10
// 184.535 us; speedup vs baseline: 4.7404x; 1.0921x over previous
//
#include <hip/hip_runtime.h>

// ---- problem constants ----
#define NB 2          // batch
#define LT 512        // per-tensor seq len
#define LL 2048       // concatenated seq len
#define MM 4096       // NB*LL rows
#define DMODEL 512
#define DINNER 1024
#define DTRANK 32
#define DSTATE 16
#define NSEG 64
#define SEGLEN 32     // NSEG*SEGLEN == LL
#define NST (NB * DINNER * DSTATE)         // 32768 (b,d,s) chains
#define NSCAN (NSEG * NB * DINNER)         // 131072 scan threads
#define KCH 8         // xproj K-chunks (split-K)

typedef short bf16x8 __attribute__((ext_vector_type(8)));
typedef float f32x4  __attribute__((ext_vector_type(4)));

__device__ __forceinline__ float silu_f(float x) { return x / (1.f + __expf(-x)); }
__device__ __forceinline__ short f2b(float f) {
    unsigned u = __float_as_uint(f);
    u += 0x7fffu + ((u >> 16) & 1u);   // RNE
    return (short)(u >> 16);
}

// ---------------------------------------------------------------------------
// K1: fused interleaved gather + in_proj GEMM (bf16 MFMA).
// ---------------------------------------------------------------------------
__global__ __launch_bounds__(256) void k_inproj(
    const float* __restrict__ t0, const float* __restrict__ t1,
    const float* __restrict__ t2, const float* __restrict__ t3,
    const float* __restrict__ W,
    float* __restrict__ xc_raw, float* __restrict__ zbuf)
{
    __shared__ short As[128 * 40];   // 32 cols + 8 pad (80B row stride)
    __shared__ short Bs[128 * 40];
    const int t = threadIdx.x;
    const int lane = t & 63;
    const int wid = t >> 6;
    const int wm = wid >> 1, wn = wid & 1;
    const int bm = blockIdx.x, bn = blockIdx.y;

    const int srow  = t >> 1;          // 0..127 staging row
    const int shalf = (t & 1) * 16;    // 0 or 16 (col offset)

    const int arow = bm * 128 + srow;
    const int gb = arow >> 11;
    const int gl = arow & 2047;
    const int gc = gl >> 7, gr = gl & 127;
    const int ti = gc & 3, ci = gc >> 2;
    const float* tp = (ti == 0) ? t0 : (ti == 1) ? t1 : (ti == 2) ? t2 : t3;
    const float* asrc = tp + ((size_t)gb * 512 + (size_t)(ci + 4 * gr)) * 512 + shalf;
    const float* bsrc = W + (size_t)(bn * 128 + srow) * 512 + shalf;

    f32x4 acc[4][4];
#pragma unroll
    for (int i = 0; i < 4; ++i)
#pragma unroll
        for (int j = 0; j < 4; ++j) acc[i][j] = (f32x4){0.f, 0.f, 0.f, 0.f};

    float4 ra[4], rb[4];
#pragma unroll
    for (int q = 0; q < 4; ++q) {
        ra[q] = *(const float4*)(asrc + q * 4);
        rb[q] = *(const float4*)(bsrc + q * 4);
    }

    const int ko = (lane >> 4) * 8;
    const int fr = lane & 15;

    for (int ks = 0; ks < 512 / 32; ++ks) {
        __syncthreads();
        {
            bf16x8 v0, v1, w0, w1;
            v0[0]=f2b(ra[0].x); v0[1]=f2b(ra[0].y); v0[2]=f2b(ra[0].z); v0[3]=f2b(ra[0].w);
            v0[4]=f2b(ra[1].x); v0[5]=f2b(ra[1].y); v0[6]=f2b(ra[1].z); v0[7]=f2b(ra[1].w);
            v1[0]=f2b(ra[2].x); v1[1]=f2b(ra[2].y); v1[2]=f2b(ra[2].z); v1[3]=f2b(ra[2].w);
            v1[4]=f2b(ra[3].x); v1[5]=f2b(ra[3].y); v1[6]=f2b(ra[3].z); v1[7]=f2b(ra[3].w);
            w0[0]=f2b(rb[0].x); w0[1]=f2b(rb[0].y); w0[2]=f2b(rb[0].z); w0[3]=f2b(rb[0].w);
            w0[4]=f2b(rb[1].x); w0[5]=f2b(rb[1].y); w0[6]=f2b(rb[1].z); w0[7]=f2b(rb[1].w);
            w1[0]=f2b(rb[2].x); w1[1]=f2b(rb[2].y); w1[2]=f2b(rb[2].z); w1[3]=f2b(rb[2].w);
            w1[4]=f2b(rb[3].x); w1[5]=f2b(rb[3].y); w1[6]=f2b(rb[3].z); w1[7]=f2b(rb[3].w);
            *(bf16x8*)&As[srow * 40 + shalf]     = v0;
            *(bf16x8*)&As[srow * 40 + shalf + 8] = v1;
            *(bf16x8*)&Bs[srow * 40 + shalf]     = w0;
            *(bf16x8*)&Bs[srow * 40 + shalf + 8] = w1;
        }
        __syncthreads();
        if (ks + 1 < 512 / 32) {
            const int k0 = (ks + 1) * 32;
#pragma unroll
            for (int q = 0; q < 4; ++q) {
                ra[q] = *(const float4*)(asrc + k0 + q * 4);
                rb[q] = *(const float4*)(bsrc + k0 + q * 4);
            }
        }
        bf16x8 af[4], bfr[4];
#pragma unroll
        for (int mf = 0; mf < 4; ++mf)
            af[mf] = *(const bf16x8*)&As[(wm * 64 + mf * 16 + fr) * 40 + ko];
#pragma unroll
        for (int nf = 0; nf < 4; ++nf)
            bfr[nf] = *(const bf16x8*)&Bs[(wn * 64 + nf * 16 + fr) * 40 + ko];
#pragma unroll
        for (int mf = 0; mf < 4; ++mf)
#pragma unroll
            for (int nf = 0; nf < 4; ++nf)
                acc[mf][nf] = __builtin_amdgcn_mfma_f32_16x16x32_bf16(
                    af[mf], bfr[nf], acc[mf][nf], 0, 0, 0);
    }

    float* dst = (bn < 8) ? xc_raw : zbuf;
    const int coladj = (bn < 8) ? 0 : 1024;
#pragma unroll
    for (int mf = 0; mf < 4; ++mf) {
        const int gmb = bm * 128 + wm * 64 + mf * 16 + (lane >> 4) * 4;
#pragma unroll
        for (int nf = 0; nf < 4; ++nf) {
            const int gn = bn * 128 + wn * 64 + nf * 16 + (lane & 15) - coladj;
#pragma unroll
            for (int j = 0; j < 4; ++j)
                dst[(size_t)(gmb + j) * DINNER + gn] = acc[mf][nf][j];
        }
    }
}

// ---------------------------------------------------------------------------
// K2: causal depthwise conv1d (K=4, left pad 3) + bias + SiLU.
// ---------------------------------------------------------------------------
__global__ __launch_bounds__(256) void k_conv(
    const float* __restrict__ xc_raw, const float* __restrict__ cw,
    const float* __restrict__ cb, float* __restrict__ xc_act,
    unsigned short* __restrict__ xc_b)
{
    const int d0 = threadIdx.x * 4;           // 0..1020
    const int m0 = blockIdx.x * 4;            // group of 4 rows, within one batch
    const int l0 = m0 & 2047;

    float4 w[4];
#pragma unroll
    for (int c = 0; c < 4; ++c) w[c] = *(const float4*)(cw + (size_t)(d0 + c) * 4);
    const float4 bb = *(const float4*)(cb + d0);

    float4 row[7];
#pragma unroll
    for (int o = 0; o < 7; ++o) {
        const int l = l0 + o - 3;
        if (l >= 0)
            row[o] = *(const float4*)(xc_raw + (size_t)(m0 + o - 3) * DINNER + d0);
        else
            row[o] = (float4){0.f, 0.f, 0.f, 0.f};
    }

#pragma unroll
    for (int mm = 0; mm < 4; ++mm) {
        float4 s = bb;
#pragma unroll
        for (int k = 0; k < 4; ++k) {
            const float4 r = row[mm + k];
            s.x += ((const float*)&w[0])[k] * r.x;
            s.y += ((const float*)&w[1])[k] * r.y;
            s.z += ((const float*)&w[2])[k] * r.z;
            s.w += ((const float*)&w[3])[k] * r.w;
        }
        float4 a;
        a.x = silu_f(s.x); a.y = silu_f(s.y); a.z = silu_f(s.z); a.w = silu_f(s.w);
        const size_t idx = (size_t)(m0 + mm) * DINNER + d0;
        *(float4*)(xc_act + idx) = a;
        ushort4 ob;
        ob.x = (unsigned short)f2b(a.x);
        ob.y = (unsigned short)f2b(a.y);
        ob.z = (unsigned short)f2b(a.z);
        ob.w = (unsigned short)f2b(a.w);
        *(ushort4*)(xc_b + idx) = ob;
    }
}

// ---------------------------------------------------------------------------
// K2b: convert x_proj_w (64x1024 f32) -> bf16
// ---------------------------------------------------------------------------
__global__ __launch_bounds__(256) void k_cvt_wx(
    const float* __restrict__ Wx, unsigned short* __restrict__ wxb)
{
    const int i4 = blockIdx.x * 256 + threadIdx.x;    // < 16384
    float4 v = *(const float4*)(Wx + (size_t)i4 * 4);
    ushort4 o;
    o.x = (unsigned short)f2b(v.x);
    o.y = (unsigned short)f2b(v.y);
    o.z = (unsigned short)f2b(v.z);
    o.w = (unsigned short)f2b(v.w);
    *(ushort4*)(wxb + (size_t)i4 * 4) = o;
}

// ---------------------------------------------------------------------------
// K3: xproj split-K MFMA GEMM.
// ---------------------------------------------------------------------------
__global__ __launch_bounds__(256) void k_xproj_mfma(
    const unsigned short* __restrict__ xc_b, const unsigned short* __restrict__ wxb,
    float* __restrict__ part)
{
    __shared__ short As[128 * 136];   // 128 K-cols + 8 pad
    __shared__ short Bs[64 * 136];
    const int t = threadIdx.x;
    const int lane = t & 63;
    const int w = t >> 6;
    const int bm = blockIdx.x;        // 0..31
    const int kc = blockIdx.y;        // 0..7

    {
        const int row = t >> 1;
        const int cb0 = (t & 1) * 64;
        const unsigned short* src = xc_b + (size_t)(bm * 128 + row) * 1024 + kc * 128 + cb0;
#pragma unroll
        for (int q = 0; q < 8; ++q)
            *(bf16x8*)&As[row * 136 + cb0 + q * 8] = *(const bf16x8*)(src + q * 8);
    }
    {
        const int row = t >> 2;
        const int cb0 = (t & 3) * 32;
        const unsigned short* src = wxb + (size_t)row * 1024 + kc * 128 + cb0;
#pragma unroll
        for (int q = 0; q < 4; ++q)
            *(bf16x8*)&Bs[row * 136 + cb0 + q * 8] = *(const bf16x8*)(src + q * 8);
    }
    __syncthreads();

    const int fr = lane & 15;
    const int ko = (lane >> 4) * 8;

    f32x4 acc[2][4];
#pragma unroll
    for (int i = 0; i < 2; ++i)
#pragma unroll
        for (int j = 0; j < 4; ++j) acc[i][j] = (f32x4){0.f, 0.f, 0.f, 0.f};

#pragma unroll
    for (int ks = 0; ks < 4; ++ks) {
        const int kb = ks * 32 + ko;
        bf16x8 af[2], bfr[4];
#pragma unroll
        for (int mf = 0; mf < 2; ++mf)
            af[mf] = *(const bf16x8*)&As[(w * 32 + mf * 16 + fr) * 136 + kb];
#pragma unroll
        for (int nf = 0; nf < 4; ++nf)
            bfr[nf] = *(const bf16x8*)&Bs[(nf * 16 + fr) * 136 + kb];
#pragma unroll
        for (int mf = 0; mf < 2; ++mf)
#pragma unroll
            for (int nf = 0; nf < 4; ++nf)
                acc[mf][nf] = __builtin_amdgcn_mfma_f32_16x16x32_bf16(
                    af[mf], bfr[nf], acc[mf][nf], 0, 0, 0);
    }

    float* pb = part + (size_t)kc * (MM * 64);
#pragma unroll
    for (int mf = 0; mf < 2; ++mf) {
        const int rb = bm * 128 + w * 32 + mf * 16 + (lane >> 4) * 4;
#pragma unroll
        for (int nf = 0; nf < 4; ++nf) {
            const int col = nf * 16 + (lane & 15);
#pragma unroll
            for (int j = 0; j < 4; ++j)
                pb[(size_t)(rb + j) * 64 + col] = acc[mf][nf][j];
        }
    }
}

// ---------------------------------------------------------------------------
// K3b: reduce split-K partials -> dbc
// ---------------------------------------------------------------------------
__global__ __launch_bounds__(256) void k_xreduce(
    const float* __restrict__ part, float* __restrict__ dbc)
{
    const int i = blockIdx.x * 256 + threadIdx.x;    // < MM*64
    float s = 0.f;
#pragma unroll
    for (int kc = 0; kc < KCH; ++kc)
        s += part[(size_t)kc * (MM * 64) + i];
    dbc[i] = s;
}

// ---------------------------------------------------------------------------
// K4: dtproj — scalar-uniform dbc loads (SGPR), fast softplus, no LDS.
// ---------------------------------------------------------------------------
__global__ __launch_bounds__(256) void k_dtproj(
    const float* __restrict__ dbc, const float* __restrict__ dtw,
    const float* __restrict__ dtb, float* __restrict__ delta)
{
    const int tid = threadIdx.x;
    const int m0 = blockIdx.x * 16;
    const int d  = blockIdx.y * 256 + tid;

    float w[DTRANK];
#pragma unroll
    for (int q = 0; q < 8; ++q) {
        float4 v = *(const float4*)(dtw + (size_t)d * DTRANK + q * 4);
        w[q * 4 + 0] = v.x; w[q * 4 + 1] = v.y;
        w[q * 4 + 2] = v.z; w[q * 4 + 3] = v.w;
    }
    const float bias = dtb[d];

#pragma unroll 4
    for (int m = 0; m < 16; ++m) {
        const float* bc = dbc + (size_t)(m0 + m) * 64;   // wave-uniform address
        float s0 = bias, s1 = 0.f, s2 = 0.f, s3 = 0.f;
#pragma unroll
        for (int r = 0; r < DTRANK; r += 4) {
            s0 += bc[r + 0] * w[r + 0];
            s1 += bc[r + 1] * w[r + 1];
            s2 += bc[r + 2] * w[r + 2];
            s3 += bc[r + 3] * w[r + 3];
        }
        const float s = (s0 + s1) + (s2 + s3);
        const float sp = (s > 20.f) ? s : __logf(1.f + __expf(s));
        delta[(size_t)(m0 + m) * DINNER + d] = sp;
    }
}

// ---------------------------------------------------------------------------
// K5: scan phase A with 1-step prefetch + scalar (readfirstlane) dbc loads.
// One thread per (g, b, d), all 16 states in registers.
// ---------------------------------------------------------------------------
__global__ __launch_bounds__(256) void k_scan_partial(
    const float* __restrict__ delta, const float* __restrict__ xc_act,
    const float* __restrict__ dbc, const float* __restrict__ A_log,
    float* __restrict__ hfin, float* __restrict__ aprod)
{
    const int gid = blockIdx.x * 256 + threadIdx.x;   // < NSCAN
    const int d = gid & 1023;
    const int b = (gid >> 10) & (NB - 1);
    const int g = gid >> 11;                           // 0..63

    float Af[DSTATE];
#pragma unroll
    for (int q = 0; q < 4; ++q) {
        float4 a4 = *(const float4*)(A_log + d * DSTATE + q * 4);
        Af[q * 4 + 0] = -__expf(a4.x);
        Af[q * 4 + 1] = -__expf(a4.y);
        Af[q * 4 + 2] = -__expf(a4.z);
        Af[q * 4 + 3] = -__expf(a4.w);
    }

    float h[DSTATE], ap[DSTATE];
#pragma unroll
    for (int s = 0; s < DSTATE; ++s) { h[s] = 0.f; ap[s] = 1.f; }

    const int mbase = b * LL + g * SEGLEN;
    const int mlast = mbase + SEGLEN - 1;

    // prime step 0
    int m = mbase;
    float de = delta [(size_t)m * DINNER + d];
    float x  = xc_act[(size_t)m * DINNER + d];
    float Bv[DSTATE];
    {
        const int mu = __builtin_amdgcn_readfirstlane(m);
        const float* bc = dbc + (size_t)mu * 64 + 32;   // uniform -> s_load
#pragma unroll
        for (int q = 0; q < 4; ++q) {
            float4 b4 = *(const float4*)(bc + q * 4);
            Bv[q * 4 + 0] = b4.x; Bv[q * 4 + 1] = b4.y;
            Bv[q * 4 + 2] = b4.z; Bv[q * 4 + 3] = b4.w;
        }
    }

#pragma unroll 2
    for (int ll = 0; ll < SEGLEN; ++ll) {
        // prefetch step ll+1 (clamped; last iter re-reads, discarded)
        const int mn = (m < mlast) ? m + 1 : mlast;
        const float de_n = delta [(size_t)mn * DINNER + d];
        const float x_n  = xc_act[(size_t)mn * DINNER + d];
        float Bn[DSTATE];
        {
            const int mun = __builtin_amdgcn_readfirstlane(mn);
            const float* bcn = dbc + (size_t)mun * 64 + 32;
#pragma unroll
            for (int q = 0; q < 4; ++q) {
                float4 b4 = *(const float4*)(bcn + q * 4);
                Bn[q * 4 + 0] = b4.x; Bn[q * 4 + 1] = b4.y;
                Bn[q * 4 + 2] = b4.z; Bn[q * 4 + 3] = b4.w;
            }
        }
        // compute current step
        const float dx = de * x;
#pragma unroll
        for (int s = 0; s < DSTATE; ++s) {
            const float dA = __expf(de * Af[s]);
            ap[s] *= dA;
            h[s] = dA * h[s] + dx * Bv[s];
        }
        // shift
        de = de_n; x = x_n;
#pragma unroll
        for (int s = 0; s < DSTATE; ++s) Bv[s] = Bn[s];
        ++m;
    }

    const size_t base = (size_t)(b * DINNER + d) * DSTATE;
#pragma unroll
    for (int s = 0; s < DSTATE; ++s) {
        hfin [(base + s) * NSEG + g] = h[s];
        aprod[(base + s) * NSEG + g] = ap[s];
    }
}

// ---------------------------------------------------------------------------
// K6: combine: wave-parallel Hillis-Steele scan over 64 segments.
// ---------------------------------------------------------------------------
__global__ __launch_bounds__(256) void k_scan_combine(
    float* __restrict__ hfin, const float* __restrict__ aprod)
{
    const int tid = blockIdx.x * 256 + threadIdx.x;   // < NST*NSEG
    const int g = tid & 63;
    const size_t bds = (size_t)(tid >> 6);
    float A = aprod[bds * NSEG + g];
    float B = hfin [bds * NSEG + g];
#pragma unroll
    for (int off = 1; off < 64; off <<= 1) {
        const float Ap = __shfl_up(A, off, 64);
        const float Bp = __shfl_up(B, off, 64);
        if (g >= off) { B = A * Bp + B; A = A * Ap; }
    }
    const float hprev = __shfl_up(B, 1, 64);
    hfin[bds * NSEG + g] = (g == 0) ? 0.f : hprev;
}

// ---------------------------------------------------------------------------
// K7: scan phase C with 1-step prefetch + scalar dbc loads.
// ---------------------------------------------------------------------------
__global__ __launch_bounds__(256) void k_scan_final(
    const float* __restrict__ delta, const float* __restrict__ xc_act,
    const float* __restrict__ dbc, const float* __restrict__ A_log,
    const float* __restrict__ Dp, const float* __restrict__ zbuf,
    const float* __restrict__ hin, float* __restrict__ yz)
{
    const int gid = blockIdx.x * 256 + threadIdx.x;   // < NSCAN
    const int d = gid & 1023;
    const int b = (gid >> 10) & (NB - 1);
    const int g = gid >> 11;

    float Af[DSTATE];
#pragma unroll
    for (int q = 0; q < 4; ++q) {
        float4 a4 = *(const float4*)(A_log + d * DSTATE + q * 4);
        Af[q * 4 + 0] = -__expf(a4.x);
        Af[q * 4 + 1] = -__expf(a4.y);
        Af[q * 4 + 2] = -__expf(a4.z);
        Af[q * 4 + 3] = -__expf(a4.w);
    }
    const float Dd = Dp[d];

    const size_t base = (size_t)(b * DINNER + d) * DSTATE;
    float h[DSTATE];
#pragma unroll
    for (int s = 0; s < DSTATE; ++s) h[s] = hin[(base + s) * NSEG + g];

    const int mbase = b * LL + g * SEGLEN;
    const int mlast = mbase + SEGLEN - 1;

    // prime step 0
    int m = mbase;
    float de = delta [(size_t)m * DINNER + d];
    float x  = xc_act[(size_t)m * DINNER + d];
    float zz = zbuf  [(size_t)m * DINNER + d];
    float Bv[DSTATE], Cv[DSTATE];
    {
        const int mu = __builtin_amdgcn_readfirstlane(m);
        const float* bc = dbc + (size_t)mu * 64;
#pragma unroll
        for (int q = 0; q < 4; ++q) {
            float4 b4 = *(const float4*)(bc + 32 + q * 4);
            float4 c4 = *(const float4*)(bc + 48 + q * 4);
            Bv[q * 4 + 0] = b4.x; Bv[q * 4 + 1] = b4.y;
            Bv[q * 4 + 2] = b4.z; Bv[q * 4 + 3] = b4.w;
            Cv[q * 4 + 0] = c4.x; Cv[q * 4 + 1] = c4.y;
            Cv[q * 4 + 2] = c4.z; Cv[q * 4 + 3] = c4.w;
        }
    }

#pragma unroll 2
    for (int ll = 0; ll < SEGLEN; ++ll) {
        // prefetch step ll+1
        const int mn = (m < mlast) ? m + 1 : mlast;
        const float de_n = delta [(size_t)mn * DINNER + d];
        const float x_n  = xc_act[(size_t)mn * DINNER + d];
        const float z_n  = zbuf  [(size_t)mn * DINNER + d];
        float Bn[DSTATE], Cn[DSTATE];
        {
            const int mun = __builtin_amdgcn_readfirstlane(mn);
            const float* bcn = dbc + (size_t)mun * 64;
#pragma unroll
            for (int q = 0; q < 4; ++q) {
                float4 b4 = *(const float4*)(bcn + 32 + q * 4);
                float4 c4 = *(const float4*)(bcn + 48 + q * 4);
                Bn[q * 4 + 0] = b4.x; Bn[q * 4 + 1] = b4.y;
                Bn[q * 4 + 2] = b4.z; Bn[q * 4 + 3] = b4.w;
                Cn[q * 4 + 0] = c4.x; Cn[q * 4 + 1] = c4.y;
                Cn[q * 4 + 2] = c4.z; Cn[q * 4 + 3] = c4.w;
            }
        }
        // compute current step
        const float dx = de * x;
        float y0 = 0.f, y1 = 0.f, y2 = 0.f, y3 = 0.f;
#pragma unroll
        for (int s = 0; s < DSTATE; s += 4) {
            float dA;
            dA = __expf(de * Af[s + 0]); h[s + 0] = dA * h[s + 0] + dx * Bv[s + 0]; y0 += h[s + 0] * Cv[s + 0];
            dA = __expf(de * Af[s + 1]); h[s + 1] = dA * h[s + 1] + dx * Bv[s + 1]; y1 += h[s + 1] * Cv[s + 1];
            dA = __expf(de * Af[s + 2]); h[s + 2] = dA * h[s + 2] + dx * Bv[s + 2]; y2 += h[s + 2] * Cv[s + 2];
            dA = __expf(de * Af[s + 3]); h[s + 3] = dA * h[s + 3] + dx * Bv[s + 3]; y3 += h[s + 3] * Cv[s + 3];
        }
        const float y = (y0 + y1) + (y2 + y3);
        yz[(size_t)m * DINNER + d] = (y + Dd * x) * silu_f(zz);
        // shift
        de = de_n; x = x_n; zz = z_n;
#pragma unroll
        for (int s = 0; s < DSTATE; ++s) { Bv[s] = Bn[s]; Cv[s] = Cn[s]; }
        ++m;
    }
}

// ---------------------------------------------------------------------------
// K8: out_proj GEMM (bf16 MFMA) + de-interleave scatter + residual add.
// ---------------------------------------------------------------------------
__global__ __launch_bounds__(256) void k_outproj(
    const float* __restrict__ yz, const float* __restrict__ Wo,
    const float* __restrict__ t0, const float* __restrict__ t1,
    const float* __restrict__ t2, const float* __restrict__ t3,
    float* __restrict__ outp)
{
    __shared__ short As[128 * 40];
    __shared__ short Bs[128 * 40];
    const int t = threadIdx.x;
    const int lane = t & 63;
    const int wid = t >> 6;
    const int wm = wid >> 1, wn = wid & 1;
    const int bm = blockIdx.x, bn = blockIdx.y;

    const int srow  = t >> 1;
    const int shalf = (t & 1) * 16;

    const float* asrc = yz + (size_t)(bm * 128 + srow) * DINNER + shalf;
    const float* bsrc = Wo + (size_t)(bn * 128 + srow) * DINNER + shalf;

    f32x4 acc[4][4];
#pragma unroll
    for (int i = 0; i < 4; ++i)
#pragma unroll
        for (int j = 0; j < 4; ++j) acc[i][j] = (f32x4){0.f, 0.f, 0.f, 0.f};

    float4 ra[4], rb[4];
#pragma unroll
    for (int q = 0; q < 4; ++q) {
        ra[q] = *(const float4*)(asrc + q * 4);
        rb[q] = *(const float4*)(bsrc + q * 4);
    }

    const int ko = (lane >> 4) * 8;
    const int fr = lane & 15;

    for (int ks = 0; ks < DINNER / 32; ++ks) {
        __syncthreads();
        {
            bf16x8 v0, v1, w0, w1;
            v0[0]=f2b(ra[0].x); v0[1]=f2b(ra[0].y); v0[2]=f2b(ra[0].z); v0[3]=f2b(ra[0].w);
            v0[4]=f2b(ra[1].x); v0[5]=f2b(ra[1].y); v0[6]=f2b(ra[1].z); v0[7]=f2b(ra[1].w);
            v1[0]=f2b(ra[2].x); v1[1]=f2b(ra[2].y); v1[2]=f2b(ra[2].z); v1[3]=f2b(ra[2].w);
            v1[4]=f2b(ra[3].x); v1[5]=f2b(ra[3].y); v1[6]=f2b(ra[3].z); v1[7]=f2b(ra[3].w);
            w0[0]=f2b(rb[0].x); w0[1]=f2b(rb[0].y); w0[2]=f2b(rb[0].z); w0[3]=f2b(rb[0].w);
            w0[4]=f2b(rb[1].x); w0[5]=f2b(rb[1].y); w0[6]=f2b(rb[1].z); w0[7]=f2b(rb[1].w);
            w1[0]=f2b(rb[2].x); w1[1]=f2b(rb[2].y); w1[2]=f2b(rb[2].z); w1[3]=f2b(rb[2].w);
            w1[4]=f2b(rb[3].x); w1[5]=f2b(rb[3].y); w1[6]=f2b(rb[3].z); w1[7]=f2b(rb[3].w);
            *(bf16x8*)&As[srow * 40 + shalf]     = v0;
            *(bf16x8*)&As[srow * 40 + shalf + 8] = v1;
            *(bf16x8*)&Bs[srow * 40 + shalf]     = w0;
            *(bf16x8*)&Bs[srow * 40 + shalf + 8] = w1;
        }
        __syncthreads();
        if (ks + 1 < DINNER / 32) {
            const int k0 = (ks + 1) * 32;
#pragma unroll
            for (int q = 0; q < 4; ++q) {
                ra[q] = *(const float4*)(asrc + k0 + q * 4);
                rb[q] = *(const float4*)(bsrc + k0 + q * 4);
            }
        }
        bf16x8 af[4], bfr[4];
#pragma unroll
        for (int mf = 0; mf < 4; ++mf)
            af[mf] = *(const bf16x8*)&As[(wm * 64 + mf * 16 + fr) * 40 + ko];
#pragma unroll
        for (int nf = 0; nf < 4; ++nf)
            bfr[nf] = *(const bf16x8*)&Bs[(wn * 64 + nf * 16 + fr) * 40 + ko];
#pragma unroll
        for (int mf = 0; mf < 4; ++mf)
#pragma unroll
            for (int nf = 0; nf < 4; ++nf)
                acc[mf][nf] = __builtin_amdgcn_mfma_f32_16x16x32_bf16(
                    af[mf], bfr[nf], acc[mf][nf], 0, 0, 0);
    }

#pragma unroll
    for (int mf = 0; mf < 4; ++mf) {
#pragma unroll
        for (int j = 0; j < 4; ++j) {
            const int gm = bm * 128 + wm * 64 + mf * 16 + (lane >> 4) * 4 + j;
            const int b = gm >> 11;
            const int l = gm & 2047;
            const int ii = l & 3;
            const int jj = l >> 2;
            const float* tsel = (ii == 0) ? t0 : (ii == 1) ? t1 : (ii == 2) ? t2 : t3;
#pragma unroll
            for (int nf = 0; nf < 4; ++nf) {
                const int gn = bn * 128 + wn * 64 + nf * 16 + (lane & 15);
                const float tv = tsel[((size_t)b * 512 + jj) * 512 + gn];
                outp[(((size_t)ii * NB + b) * 512 + jj) * 512 + gn] = acc[mf][nf][j] + tv;
            }
        }
    }
}

// ---------------------------------------------------------------------------
extern "C" void kernel_launch(void* const* d_in, const int* in_sizes, int n_in,
                              void* d_out, int out_size, void* d_ws, size_t ws_size,
                              hipStream_t stream)
{
    const float* t0 = (const float*)d_in[0];
    const float* t1 = (const float*)d_in[1];
    const float* t2 = (const float*)d_in[2];
    const float* t3 = (const float*)d_in[3];
    const float* in_proj_w  = (const float*)d_in[4];
    const float* conv_w     = (const float*)d_in[5];
    const float* conv_b     = (const float*)d_in[6];
    const float* x_proj_w   = (const float*)d_in[7];
    const float* dt_w       = (const float*)d_in[8];
    const float* dt_b       = (const float*)d_in[9];
    const float* A_log      = (const float*)d_in[10];
    const float* D_param    = (const float*)d_in[11];
    const float* out_proj_w = (const float*)d_in[12];
    float* outp = (float*)d_out;

    // workspace carve (fp32).  Aliasing timeline (stream-ordered, audited):
    // 1 inproj:   W xc_raw, zbuf
    // 2 conv:     R xc_raw          -> W xc_act, xc_b (delta region)
    // 3 cvt_wx:   W wxb (xc_raw+2M) [xc_raw dead]
    // 4 xproj:    R xc_b, wxb       -> W part (xc_raw 0..2M)
    // 5 xreduce:  R part            -> W dbc
    // 6 dtproj:   R dbc, dt_w       -> W delta [xc_b dead]
    // 7 scanA:    R delta,xc_act,dbc-> W hfin, aprod (xc_raw 0..2M, part dead)
    // 8 combine:  R hfin, aprod     -> W hfin (in place, wave-local)
    // 9 scanC:    R delta,xc_act,dbc,hfin,zbuf -> W yz (xc_raw; aprod dead)
    // 10 outproj: R yz, Wo, t*      -> W outp
    float* xc_raw = (float*)d_ws;                          // 4M floats
    float* zbuf   = xc_raw + (size_t)MM * DINNER;          // 4M
    float* xc_act = zbuf   + (size_t)MM * DINNER;          // 4M
    float* delta  = xc_act + (size_t)MM * DINNER;          // 4M
    float* dbc    = delta  + (size_t)MM * DINNER;          // 256K
    float* hfin   = dbc    + (size_t)MM * 64;              // 2M (NST*NSEG)
    float* yz     = xc_raw;                                // alias
    float* part   = xc_raw;                                // alias (2M floats)
    float* aprod  = xc_raw;                                // alias (2M floats)
    unsigned short* wxb  = (unsigned short*)(xc_raw + (size_t)KCH * MM * 64);
    unsigned short* xc_b = (unsigned short*)delta;         // alias (2M floats)

    k_inproj<<<dim3(32, 16), 256, 0, stream>>>(t0, t1, t2, t3, in_proj_w, xc_raw, zbuf);
    k_conv<<<MM / 4, 256, 0, stream>>>(xc_raw, conv_w, conv_b, xc_act, xc_b);
    k_cvt_wx<<<64, 256, 0, stream>>>(x_proj_w, wxb);
    k_xproj_mfma<<<dim3(32, KCH), 256, 0, stream>>>(xc_b, wxb, part);
    k_xreduce<<<(MM * 64) / 256, 256, 0, stream>>>(part, dbc);
    k_dtproj<<<dim3(MM / 16, 4), 256, 0, stream>>>(dbc, dt_w, dt_b, delta);
    k_scan_partial<<<NSCAN / 256, 256, 0, stream>>>(delta, xc_act, dbc, A_log, hfin, aprod);
    k_scan_combine<<<(NST * NSEG) / 256, 256, 0, stream>>>(hfin, aprod);
    k_scan_final<<<NSCAN / 256, 256, 0, stream>>>(delta, xc_act, dbc, A_log, D_param, zbuf, hfin, yz);
    k_outproj<<<dim3(32, 4), 256, 0, stream>>>(yz, out_proj_w, t0, t1, t2, t3, outp);
}

// Round 11
// 171.117 us; speedup vs baseline: 5.1121x; 1.0784x over previous
//
#include <hip/hip_runtime.h>

// ---- problem constants ----
#define NB 2          // batch
#define LT 512        // per-tensor seq len
#define LL 2048       // concatenated seq len
#define MM 4096       // NB*LL rows
#define DMODEL 512
#define DINNER 1024
#define DTRANK 32
#define DSTATE 16
#define NSEG 64
#define SEGLEN 32     // NSEG*SEGLEN == LL
#define NST (NB * DINNER * DSTATE)         // 32768 (b,d,s) chains
#define NSCAN (NSEG * NB * DINNER)         // 131072 scan threads
#define KCH 8         // xproj K-chunks (split-K)

typedef short bf16x8 __attribute__((ext_vector_type(8)));
typedef float f32x4  __attribute__((ext_vector_type(4)));

__device__ __forceinline__ float silu_f(float x) { return x / (1.f + __expf(-x)); }
__device__ __forceinline__ short f2b(float f) {
    unsigned u = __float_as_uint(f);
    u += 0x7fffu + ((u >> 16) & 1u);   // RNE
    return (short)(u >> 16);
}

// ---------------------------------------------------------------------------
// K1: fused interleaved gather + in_proj GEMM (bf16 MFMA).
// ---------------------------------------------------------------------------
__global__ __launch_bounds__(256) void k_inproj(
    const float* __restrict__ t0, const float* __restrict__ t1,
    const float* __restrict__ t2, const float* __restrict__ t3,
    const float* __restrict__ W,
    float* __restrict__ xc_raw, float* __restrict__ zbuf)
{
    __shared__ short As[128 * 40];   // 32 cols + 8 pad (80B row stride)
    __shared__ short Bs[128 * 40];
    const int t = threadIdx.x;
    const int lane = t & 63;
    const int wid = t >> 6;
    const int wm = wid >> 1, wn = wid & 1;
    const int bm = blockIdx.x, bn = blockIdx.y;

    const int srow  = t >> 1;          // 0..127 staging row
    const int shalf = (t & 1) * 16;    // 0 or 16 (col offset)

    const int arow = bm * 128 + srow;
    const int gb = arow >> 11;
    const int gl = arow & 2047;
    const int gc = gl >> 7, gr = gl & 127;
    const int ti = gc & 3, ci = gc >> 2;
    const float* tp = (ti == 0) ? t0 : (ti == 1) ? t1 : (ti == 2) ? t2 : t3;
    const float* asrc = tp + ((size_t)gb * 512 + (size_t)(ci + 4 * gr)) * 512 + shalf;
    const float* bsrc = W + (size_t)(bn * 128 + srow) * 512 + shalf;

    f32x4 acc[4][4];
#pragma unroll
    for (int i = 0; i < 4; ++i)
#pragma unroll
        for (int j = 0; j < 4; ++j) acc[i][j] = (f32x4){0.f, 0.f, 0.f, 0.f};

    float4 ra[4], rb[4];
#pragma unroll
    for (int q = 0; q < 4; ++q) {
        ra[q] = *(const float4*)(asrc + q * 4);
        rb[q] = *(const float4*)(bsrc + q * 4);
    }

    const int ko = (lane >> 4) * 8;
    const int fr = lane & 15;

    for (int ks = 0; ks < 512 / 32; ++ks) {
        __syncthreads();
        {
            bf16x8 v0, v1, w0, w1;
            v0[0]=f2b(ra[0].x); v0[1]=f2b(ra[0].y); v0[2]=f2b(ra[0].z); v0[3]=f2b(ra[0].w);
            v0[4]=f2b(ra[1].x); v0[5]=f2b(ra[1].y); v0[6]=f2b(ra[1].z); v0[7]=f2b(ra[1].w);
            v1[0]=f2b(ra[2].x); v1[1]=f2b(ra[2].y); v1[2]=f2b(ra[2].z); v1[3]=f2b(ra[2].w);
            v1[4]=f2b(ra[3].x); v1[5]=f2b(ra[3].y); v1[6]=f2b(ra[3].z); v1[7]=f2b(ra[3].w);
            w0[0]=f2b(rb[0].x); w0[1]=f2b(rb[0].y); w0[2]=f2b(rb[0].z); w0[3]=f2b(rb[0].w);
            w0[4]=f2b(rb[1].x); w0[5]=f2b(rb[1].y); w0[6]=f2b(rb[1].z); w0[7]=f2b(rb[1].w);
            w1[0]=f2b(rb[2].x); w1[1]=f2b(rb[2].y); w1[2]=f2b(rb[2].z); w1[3]=f2b(rb[2].w);
            w1[4]=f2b(rb[3].x); w1[5]=f2b(rb[3].y); w1[6]=f2b(rb[3].z); w1[7]=f2b(rb[3].w);
            *(bf16x8*)&As[srow * 40 + shalf]     = v0;
            *(bf16x8*)&As[srow * 40 + shalf + 8] = v1;
            *(bf16x8*)&Bs[srow * 40 + shalf]     = w0;
            *(bf16x8*)&Bs[srow * 40 + shalf + 8] = w1;
        }
        __syncthreads();
        if (ks + 1 < 512 / 32) {
            const int k0 = (ks + 1) * 32;
#pragma unroll
            for (int q = 0; q < 4; ++q) {
                ra[q] = *(const float4*)(asrc + k0 + q * 4);
                rb[q] = *(const float4*)(bsrc + k0 + q * 4);
            }
        }
        bf16x8 af[4], bfr[4];
#pragma unroll
        for (int mf = 0; mf < 4; ++mf)
            af[mf] = *(const bf16x8*)&As[(wm * 64 + mf * 16 + fr) * 40 + ko];
#pragma unroll
        for (int nf = 0; nf < 4; ++nf)
            bfr[nf] = *(const bf16x8*)&Bs[(wn * 64 + nf * 16 + fr) * 40 + ko];
#pragma unroll
        for (int mf = 0; mf < 4; ++mf)
#pragma unroll
            for (int nf = 0; nf < 4; ++nf)
                acc[mf][nf] = __builtin_amdgcn_mfma_f32_16x16x32_bf16(
                    af[mf], bfr[nf], acc[mf][nf], 0, 0, 0);
    }

    float* dst = (bn < 8) ? xc_raw : zbuf;
    const int coladj = (bn < 8) ? 0 : 1024;
#pragma unroll
    for (int mf = 0; mf < 4; ++mf) {
        const int gmb = bm * 128 + wm * 64 + mf * 16 + (lane >> 4) * 4;
#pragma unroll
        for (int nf = 0; nf < 4; ++nf) {
            const int gn = bn * 128 + wn * 64 + nf * 16 + (lane & 15) - coladj;
#pragma unroll
            for (int j = 0; j < 4; ++j)
                dst[(size_t)(gmb + j) * DINNER + gn] = acc[mf][nf][j];
        }
    }
}

// ---------------------------------------------------------------------------
// K2: causal depthwise conv1d (K=4, left pad 3) + bias + SiLU.
// ---------------------------------------------------------------------------
__global__ __launch_bounds__(256) void k_conv(
    const float* __restrict__ xc_raw, const float* __restrict__ cw,
    const float* __restrict__ cb, float* __restrict__ xc_act,
    unsigned short* __restrict__ xc_b)
{
    const int d0 = threadIdx.x * 4;           // 0..1020
    const int m0 = blockIdx.x * 4;            // group of 4 rows, within one batch
    const int l0 = m0 & 2047;

    float4 w[4];
#pragma unroll
    for (int c = 0; c < 4; ++c) w[c] = *(const float4*)(cw + (size_t)(d0 + c) * 4);
    const float4 bb = *(const float4*)(cb + d0);

    float4 row[7];
#pragma unroll
    for (int o = 0; o < 7; ++o) {
        const int l = l0 + o - 3;
        if (l >= 0)
            row[o] = *(const float4*)(xc_raw + (size_t)(m0 + o - 3) * DINNER + d0);
        else
            row[o] = (float4){0.f, 0.f, 0.f, 0.f};
    }

#pragma unroll
    for (int mm = 0; mm < 4; ++mm) {
        float4 s = bb;
#pragma unroll
        for (int k = 0; k < 4; ++k) {
            const float4 r = row[mm + k];
            s.x += ((const float*)&w[0])[k] * r.x;
            s.y += ((const float*)&w[1])[k] * r.y;
            s.z += ((const float*)&w[2])[k] * r.z;
            s.w += ((const float*)&w[3])[k] * r.w;
        }
        float4 a;
        a.x = silu_f(s.x); a.y = silu_f(s.y); a.z = silu_f(s.z); a.w = silu_f(s.w);
        const size_t idx = (size_t)(m0 + mm) * DINNER + d0;
        *(float4*)(xc_act + idx) = a;
        ushort4 ob;
        ob.x = (unsigned short)f2b(a.x);
        ob.y = (unsigned short)f2b(a.y);
        ob.z = (unsigned short)f2b(a.z);
        ob.w = (unsigned short)f2b(a.w);
        *(ushort4*)(xc_b + idx) = ob;
    }
}

// ---------------------------------------------------------------------------
// K2b: convert x_proj_w (64x1024 f32) -> bf16
// ---------------------------------------------------------------------------
__global__ __launch_bounds__(256) void k_cvt_wx(
    const float* __restrict__ Wx, unsigned short* __restrict__ wxb)
{
    const int i4 = blockIdx.x * 256 + threadIdx.x;    // < 16384
    float4 v = *(const float4*)(Wx + (size_t)i4 * 4);
    ushort4 o;
    o.x = (unsigned short)f2b(v.x);
    o.y = (unsigned short)f2b(v.y);
    o.z = (unsigned short)f2b(v.z);
    o.w = (unsigned short)f2b(v.w);
    *(ushort4*)(wxb + (size_t)i4 * 4) = o;
}

// ---------------------------------------------------------------------------
// K3: xproj split-K MFMA GEMM.
// ---------------------------------------------------------------------------
__global__ __launch_bounds__(256) void k_xproj_mfma(
    const unsigned short* __restrict__ xc_b, const unsigned short* __restrict__ wxb,
    float* __restrict__ part)
{
    __shared__ short As[128 * 136];   // 128 K-cols + 8 pad
    __shared__ short Bs[64 * 136];
    const int t = threadIdx.x;
    const int lane = t & 63;
    const int w = t >> 6;
    const int bm = blockIdx.x;        // 0..31
    const int kc = blockIdx.y;        // 0..7

    {
        const int row = t >> 1;
        const int cb0 = (t & 1) * 64;
        const unsigned short* src = xc_b + (size_t)(bm * 128 + row) * 1024 + kc * 128 + cb0;
#pragma unroll
        for (int q = 0; q < 8; ++q)
            *(bf16x8*)&As[row * 136 + cb0 + q * 8] = *(const bf16x8*)(src + q * 8);
    }
    {
        const int row = t >> 2;
        const int cb0 = (t & 3) * 32;
        const unsigned short* src = wxb + (size_t)row * 1024 + kc * 128 + cb0;
#pragma unroll
        for (int q = 0; q < 4; ++q)
            *(bf16x8*)&Bs[row * 136 + cb0 + q * 8] = *(const bf16x8*)(src + q * 8);
    }
    __syncthreads();

    const int fr = lane & 15;
    const int ko = (lane >> 4) * 8;

    f32x4 acc[2][4];
#pragma unroll
    for (int i = 0; i < 2; ++i)
#pragma unroll
        for (int j = 0; j < 4; ++j) acc[i][j] = (f32x4){0.f, 0.f, 0.f, 0.f};

#pragma unroll
    for (int ks = 0; ks < 4; ++ks) {
        const int kb = ks * 32 + ko;
        bf16x8 af[2], bfr[4];
#pragma unroll
        for (int mf = 0; mf < 2; ++mf)
            af[mf] = *(const bf16x8*)&As[(w * 32 + mf * 16 + fr) * 136 + kb];
#pragma unroll
        for (int nf = 0; nf < 4; ++nf)
            bfr[nf] = *(const bf16x8*)&Bs[(nf * 16 + fr) * 136 + kb];
#pragma unroll
        for (int mf = 0; mf < 2; ++mf)
#pragma unroll
            for (int nf = 0; nf < 4; ++nf)
                acc[mf][nf] = __builtin_amdgcn_mfma_f32_16x16x32_bf16(
                    af[mf], bfr[nf], acc[mf][nf], 0, 0, 0);
    }

    float* pb = part + (size_t)kc * (MM * 64);
#pragma unroll
    for (int mf = 0; mf < 2; ++mf) {
        const int rb = bm * 128 + w * 32 + mf * 16 + (lane >> 4) * 4;
#pragma unroll
        for (int nf = 0; nf < 4; ++nf) {
            const int col = nf * 16 + (lane & 15);
#pragma unroll
            for (int j = 0; j < 4; ++j)
                pb[(size_t)(rb + j) * 64 + col] = acc[mf][nf][j];
        }
    }
}

// ---------------------------------------------------------------------------
// K3b: reduce split-K partials -> dbc
// ---------------------------------------------------------------------------
__global__ __launch_bounds__(256) void k_xreduce(
    const float* __restrict__ part, float* __restrict__ dbc)
{
    const int i = blockIdx.x * 256 + threadIdx.x;    // < MM*64
    float s = 0.f;
#pragma unroll
    for (int kc = 0; kc < KCH; ++kc)
        s += part[(size_t)kc * (MM * 64) + i];
    dbc[i] = s;
}

// ---------------------------------------------------------------------------
// K4: dtproj — scalar-uniform dbc loads (SGPR), fast softplus, no LDS.
// ---------------------------------------------------------------------------
__global__ __launch_bounds__(256) void k_dtproj(
    const float* __restrict__ dbc, const float* __restrict__ dtw,
    const float* __restrict__ dtb, float* __restrict__ delta)
{
    const int tid = threadIdx.x;
    const int m0 = blockIdx.x * 16;
    const int d  = blockIdx.y * 256 + tid;

    float w[DTRANK];
#pragma unroll
    for (int q = 0; q < 8; ++q) {
        float4 v = *(const float4*)(dtw + (size_t)d * DTRANK + q * 4);
        w[q * 4 + 0] = v.x; w[q * 4 + 1] = v.y;
        w[q * 4 + 2] = v.z; w[q * 4 + 3] = v.w;
    }
    const float bias = dtb[d];

#pragma unroll 4
    for (int m = 0; m < 16; ++m) {
        const float* bc = dbc + (size_t)(m0 + m) * 64;   // wave-uniform address
        float s0 = bias, s1 = 0.f, s2 = 0.f, s3 = 0.f;
#pragma unroll
        for (int r = 0; r < DTRANK; r += 4) {
            s0 += bc[r + 0] * w[r + 0];
            s1 += bc[r + 1] * w[r + 1];
            s2 += bc[r + 2] * w[r + 2];
            s3 += bc[r + 3] * w[r + 3];
        }
        const float s = (s0 + s1) + (s2 + s3);
        const float sp = (s > 20.f) ? s : __logf(1.f + __expf(s));
        delta[(size_t)(m0 + m) * DINNER + d] = sp;
    }
}

// ---------------------------------------------------------------------------
// K5: scan phase A with 1-step prefetch + scalar (readfirstlane) dbc loads.
// ---------------------------------------------------------------------------
__global__ __launch_bounds__(256) void k_scan_partial(
    const float* __restrict__ delta, const float* __restrict__ xc_act,
    const float* __restrict__ dbc, const float* __restrict__ A_log,
    float* __restrict__ hfin, float* __restrict__ aprod)
{
    const int gid = blockIdx.x * 256 + threadIdx.x;   // < NSCAN
    const int d = gid & 1023;
    const int b = (gid >> 10) & (NB - 1);
    const int g = gid >> 11;                           // 0..63

    float Af[DSTATE];
#pragma unroll
    for (int q = 0; q < 4; ++q) {
        float4 a4 = *(const float4*)(A_log + d * DSTATE + q * 4);
        Af[q * 4 + 0] = -__expf(a4.x);
        Af[q * 4 + 1] = -__expf(a4.y);
        Af[q * 4 + 2] = -__expf(a4.z);
        Af[q * 4 + 3] = -__expf(a4.w);
    }

    float h[DSTATE], ap[DSTATE];
#pragma unroll
    for (int s = 0; s < DSTATE; ++s) { h[s] = 0.f; ap[s] = 1.f; }

    const int mbase = b * LL + g * SEGLEN;
    const int mlast = mbase + SEGLEN - 1;

    int m = mbase;
    float de = delta [(size_t)m * DINNER + d];
    float x  = xc_act[(size_t)m * DINNER + d];
    float Bv[DSTATE];
    {
        const int mu = __builtin_amdgcn_readfirstlane(m);
        const float* bc = dbc + (size_t)mu * 64 + 32;   // uniform -> s_load
#pragma unroll
        for (int q = 0; q < 4; ++q) {
            float4 b4 = *(const float4*)(bc + q * 4);
            Bv[q * 4 + 0] = b4.x; Bv[q * 4 + 1] = b4.y;
            Bv[q * 4 + 2] = b4.z; Bv[q * 4 + 3] = b4.w;
        }
    }

#pragma unroll 2
    for (int ll = 0; ll < SEGLEN; ++ll) {
        const int mn = (m < mlast) ? m + 1 : mlast;
        const float de_n = delta [(size_t)mn * DINNER + d];
        const float x_n  = xc_act[(size_t)mn * DINNER + d];
        float Bn[DSTATE];
        {
            const int mun = __builtin_amdgcn_readfirstlane(mn);
            const float* bcn = dbc + (size_t)mun * 64 + 32;
#pragma unroll
            for (int q = 0; q < 4; ++q) {
                float4 b4 = *(const float4*)(bcn + q * 4);
                Bn[q * 4 + 0] = b4.x; Bn[q * 4 + 1] = b4.y;
                Bn[q * 4 + 2] = b4.z; Bn[q * 4 + 3] = b4.w;
            }
        }
        const float dx = de * x;
#pragma unroll
        for (int s = 0; s < DSTATE; ++s) {
            const float dA = __expf(de * Af[s]);
            ap[s] *= dA;
            h[s] = dA * h[s] + dx * Bv[s];
        }
        de = de_n; x = x_n;
#pragma unroll
        for (int s = 0; s < DSTATE; ++s) Bv[s] = Bn[s];
        ++m;
    }

    const size_t base = (size_t)(b * DINNER + d) * DSTATE;
#pragma unroll
    for (int s = 0; s < DSTATE; ++s) {
        hfin [(base + s) * NSEG + g] = h[s];
        aprod[(base + s) * NSEG + g] = ap[s];
    }
}

// ---------------------------------------------------------------------------
// K6: combine: wave-parallel Hillis-Steele scan over 64 segments.
// ---------------------------------------------------------------------------
__global__ __launch_bounds__(256) void k_scan_combine(
    float* __restrict__ hfin, const float* __restrict__ aprod)
{
    const int tid = blockIdx.x * 256 + threadIdx.x;   // < NST*NSEG
    const int g = tid & 63;
    const size_t bds = (size_t)(tid >> 6);
    float A = aprod[bds * NSEG + g];
    float B = hfin [bds * NSEG + g];
#pragma unroll
    for (int off = 1; off < 64; off <<= 1) {
        const float Ap = __shfl_up(A, off, 64);
        const float Bp = __shfl_up(B, off, 64);
        if (g >= off) { B = A * Bp + B; A = A * Ap; }
    }
    const float hprev = __shfl_up(B, 1, 64);
    hfin[bds * NSEG + g] = (g == 0) ? 0.f : hprev;
}

// ---------------------------------------------------------------------------
// K7: scan phase C with 1-step prefetch + scalar dbc loads.
// ---------------------------------------------------------------------------
__global__ __launch_bounds__(256) void k_scan_final(
    const float* __restrict__ delta, const float* __restrict__ xc_act,
    const float* __restrict__ dbc, const float* __restrict__ A_log,
    const float* __restrict__ Dp, const float* __restrict__ zbuf,
    const float* __restrict__ hin, float* __restrict__ yz)
{
    const int gid = blockIdx.x * 256 + threadIdx.x;   // < NSCAN
    const int d = gid & 1023;
    const int b = (gid >> 10) & (NB - 1);
    const int g = gid >> 11;

    float Af[DSTATE];
#pragma unroll
    for (int q = 0; q < 4; ++q) {
        float4 a4 = *(const float4*)(A_log + d * DSTATE + q * 4);
        Af[q * 4 + 0] = -__expf(a4.x);
        Af[q * 4 + 1] = -__expf(a4.y);
        Af[q * 4 + 2] = -__expf(a4.z);
        Af[q * 4 + 3] = -__expf(a4.w);
    }
    const float Dd = Dp[d];

    const size_t base = (size_t)(b * DINNER + d) * DSTATE;
    float h[DSTATE];
#pragma unroll
    for (int s = 0; s < DSTATE; ++s) h[s] = hin[(base + s) * NSEG + g];

    const int mbase = b * LL + g * SEGLEN;
    const int mlast = mbase + SEGLEN - 1;

    int m = mbase;
    float de = delta [(size_t)m * DINNER + d];
    float x  = xc_act[(size_t)m * DINNER + d];
    float zz = zbuf  [(size_t)m * DINNER + d];
    float Bv[DSTATE], Cv[DSTATE];
    {
        const int mu = __builtin_amdgcn_readfirstlane(m);
        const float* bc = dbc + (size_t)mu * 64;
#pragma unroll
        for (int q = 0; q < 4; ++q) {
            float4 b4 = *(const float4*)(bc + 32 + q * 4);
            float4 c4 = *(const float4*)(bc + 48 + q * 4);
            Bv[q * 4 + 0] = b4.x; Bv[q * 4 + 1] = b4.y;
            Bv[q * 4 + 2] = b4.z; Bv[q * 4 + 3] = b4.w;
            Cv[q * 4 + 0] = c4.x; Cv[q * 4 + 1] = c4.y;
            Cv[q * 4 + 2] = c4.z; Cv[q * 4 + 3] = c4.w;
        }
    }

#pragma unroll 2
    for (int ll = 0; ll < SEGLEN; ++ll) {
        const int mn = (m < mlast) ? m + 1 : mlast;
        const float de_n = delta [(size_t)mn * DINNER + d];
        const float x_n  = xc_act[(size_t)mn * DINNER + d];
        const float z_n  = zbuf  [(size_t)mn * DINNER + d];
        float Bn[DSTATE], Cn[DSTATE];
        {
            const int mun = __builtin_amdgcn_readfirstlane(mn);
            const float* bcn = dbc + (size_t)mun * 64;
#pragma unroll
            for (int q = 0; q < 4; ++q) {
                float4 b4 = *(const float4*)(bcn + 32 + q * 4);
                float4 c4 = *(const float4*)(bcn + 48 + q * 4);
                Bn[q * 4 + 0] = b4.x; Bn[q * 4 + 1] = b4.y;
                Bn[q * 4 + 2] = b4.z; Bn[q * 4 + 3] = b4.w;
                Cn[q * 4 + 0] = c4.x; Cn[q * 4 + 1] = c4.y;
                Cn[q * 4 + 2] = c4.z; Cn[q * 4 + 3] = c4.w;
            }
        }
        const float dx = de * x;
        float y0 = 0.f, y1 = 0.f, y2 = 0.f, y3 = 0.f;
#pragma unroll
        for (int s = 0; s < DSTATE; s += 4) {
            float dA;
            dA = __expf(de * Af[s + 0]); h[s + 0] = dA * h[s + 0] + dx * Bv[s + 0]; y0 += h[s + 0] * Cv[s + 0];
            dA = __expf(de * Af[s + 1]); h[s + 1] = dA * h[s + 1] + dx * Bv[s + 1]; y1 += h[s + 1] * Cv[s + 1];
            dA = __expf(de * Af[s + 2]); h[s + 2] = dA * h[s + 2] + dx * Bv[s + 2]; y2 += h[s + 2] * Cv[s + 2];
            dA = __expf(de * Af[s + 3]); h[s + 3] = dA * h[s + 3] + dx * Bv[s + 3]; y3 += h[s + 3] * Cv[s + 3];
        }
        const float y = (y0 + y1) + (y2 + y3);
        yz[(size_t)m * DINNER + d] = (y + Dd * x) * silu_f(zz);
        de = de_n; x = x_n; zz = z_n;
#pragma unroll
        for (int s = 0; s < DSTATE; ++s) { Bv[s] = Bn[s]; Cv[s] = Cn[s]; }
        ++m;
    }
}

// ---------------------------------------------------------------------------
// K8: out_proj GEMM (bf16 MFMA), 64x64 tiles, grid (64,8)=512 blocks.
// 4 waves 2x2, each wave 32x32 output. Fused de-interleave scatter + residual.
// ---------------------------------------------------------------------------
__global__ __launch_bounds__(256) void k_outproj(
    const float* __restrict__ yz, const float* __restrict__ Wo,
    const float* __restrict__ t0, const float* __restrict__ t1,
    const float* __restrict__ t2, const float* __restrict__ t3,
    float* __restrict__ outp)
{
    __shared__ short As[64 * 40];   // 64 rows x (32 + 8 pad) shorts
    __shared__ short Bs[64 * 40];
    const int t = threadIdx.x;
    const int lane = t & 63;
    const int wid = t >> 6;
    const int wm = wid >> 1, wn = wid & 1;
    const int bm = blockIdx.x;      // 0..63
    const int bn = blockIdx.y;      // 0..7

    const int srow = t >> 2;          // 0..63
    const int scol = (t & 3) * 8;     // 0,8,16,24 (floats/shorts)

    const float* asrc = yz + (size_t)(bm * 64 + srow) * DINNER + scol;
    const float* bsrc = Wo + (size_t)(bn * 64 + srow) * DINNER + scol;

    f32x4 acc[2][2];
#pragma unroll
    for (int i = 0; i < 2; ++i)
#pragma unroll
        for (int j = 0; j < 2; ++j) acc[i][j] = (f32x4){0.f, 0.f, 0.f, 0.f};

    float4 ra[2], rb[2];
#pragma unroll
    for (int q = 0; q < 2; ++q) {
        ra[q] = *(const float4*)(asrc + q * 4);
        rb[q] = *(const float4*)(bsrc + q * 4);
    }

    const int ko = (lane >> 4) * 8;
    const int fr = lane & 15;

    for (int ks = 0; ks < DINNER / 32; ++ks) {
        __syncthreads();
        {
            bf16x8 v0, w0;
            v0[0]=f2b(ra[0].x); v0[1]=f2b(ra[0].y); v0[2]=f2b(ra[0].z); v0[3]=f2b(ra[0].w);
            v0[4]=f2b(ra[1].x); v0[5]=f2b(ra[1].y); v0[6]=f2b(ra[1].z); v0[7]=f2b(ra[1].w);
            w0[0]=f2b(rb[0].x); w0[1]=f2b(rb[0].y); w0[2]=f2b(rb[0].z); w0[3]=f2b(rb[0].w);
            w0[4]=f2b(rb[1].x); w0[5]=f2b(rb[1].y); w0[6]=f2b(rb[1].z); w0[7]=f2b(rb[1].w);
            *(bf16x8*)&As[srow * 40 + scol] = v0;
            *(bf16x8*)&Bs[srow * 40 + scol] = w0;
        }
        __syncthreads();
        if (ks + 1 < DINNER / 32) {
            const int k0 = (ks + 1) * 32;
#pragma unroll
            for (int q = 0; q < 2; ++q) {
                ra[q] = *(const float4*)(asrc + k0 + q * 4);
                rb[q] = *(const float4*)(bsrc + k0 + q * 4);
            }
        }
        bf16x8 af[2], bfr[2];
#pragma unroll
        for (int mf = 0; mf < 2; ++mf)
            af[mf] = *(const bf16x8*)&As[(wm * 32 + mf * 16 + fr) * 40 + ko];
#pragma unroll
        for (int nf = 0; nf < 2; ++nf)
            bfr[nf] = *(const bf16x8*)&Bs[(wn * 32 + nf * 16 + fr) * 40 + ko];
#pragma unroll
        for (int mf = 0; mf < 2; ++mf)
#pragma unroll
            for (int nf = 0; nf < 2; ++nf)
                acc[mf][nf] = __builtin_amdgcn_mfma_f32_16x16x32_bf16(
                    af[mf], bfr[nf], acc[mf][nf], 0, 0, 0);
    }

#pragma unroll
    for (int mf = 0; mf < 2; ++mf) {
#pragma unroll
        for (int j = 0; j < 4; ++j) {
            const int gm = bm * 64 + wm * 32 + mf * 16 + (lane >> 4) * 4 + j;
            const int b = gm >> 11;
            const int l = gm & 2047;
            const int ii = l & 3;
            const int jj = l >> 2;
            const float* tsel = (ii == 0) ? t0 : (ii == 1) ? t1 : (ii == 2) ? t2 : t3;
#pragma unroll
            for (int nf = 0; nf < 2; ++nf) {
                const int gn = bn * 64 + wn * 32 + nf * 16 + (lane & 15);
                const float tv = tsel[((size_t)b * 512 + jj) * 512 + gn];
                outp[(((size_t)ii * NB + b) * 512 + jj) * 512 + gn] = acc[mf][nf][j] + tv;
            }
        }
    }
}

// ---------------------------------------------------------------------------
extern "C" void kernel_launch(void* const* d_in, const int* in_sizes, int n_in,
                              void* d_out, int out_size, void* d_ws, size_t ws_size,
                              hipStream_t stream)
{
    const float* t0 = (const float*)d_in[0];
    const float* t1 = (const float*)d_in[1];
    const float* t2 = (const float*)d_in[2];
    const float* t3 = (const float*)d_in[3];
    const float* in_proj_w  = (const float*)d_in[4];
    const float* conv_w     = (const float*)d_in[5];
    const float* conv_b     = (const float*)d_in[6];
    const float* x_proj_w   = (const float*)d_in[7];
    const float* dt_w       = (const float*)d_in[8];
    const float* dt_b       = (const float*)d_in[9];
    const float* A_log      = (const float*)d_in[10];
    const float* D_param    = (const float*)d_in[11];
    const float* out_proj_w = (const float*)d_in[12];
    float* outp = (float*)d_out;

    // workspace carve (fp32).  Aliasing timeline (stream-ordered, audited):
    // 1 inproj:   W xc_raw, zbuf
    // 2 conv:     R xc_raw          -> W xc_act, xc_b (delta region)
    // 3 cvt_wx:   W wxb (xc_raw+2M) [xc_raw dead]
    // 4 xproj:    R xc_b, wxb       -> W part (xc_raw 0..2M)
    // 5 xreduce:  R part            -> W dbc
    // 6 dtproj:   R dbc, dt_w       -> W delta [xc_b dead]
    // 7 scanA:    R delta,xc_act,dbc-> W hfin, aprod (xc_raw 0..2M, part dead)
    // 8 combine:  R hfin, aprod     -> W hfin (in place, wave-local)
    // 9 scanC:    R delta,xc_act,dbc,hfin,zbuf -> W yz (xc_raw; aprod dead)
    // 10 outproj: R yz, Wo, t*      -> W outp
    float* xc_raw = (float*)d_ws;                          // 4M floats
    float* zbuf   = xc_raw + (size_t)MM * DINNER;          // 4M
    float* xc_act = zbuf   + (size_t)MM * DINNER;          // 4M
    float* delta  = xc_act + (size_t)MM * DINNER;          // 4M
    float* dbc    = delta  + (size_t)MM * DINNER;          // 256K
    float* hfin   = dbc    + (size_t)MM * 64;              // 2M (NST*NSEG)
    float* yz     = xc_raw;                                // alias
    float* part   = xc_raw;                                // alias (2M floats)
    float* aprod  = xc_raw;                                // alias (2M floats)
    unsigned short* wxb  = (unsigned short*)(xc_raw + (size_t)KCH * MM * 64);
    unsigned short* xc_b = (unsigned short*)delta;         // alias (2M floats)

    k_inproj<<<dim3(32, 16), 256, 0, stream>>>(t0, t1, t2, t3, in_proj_w, xc_raw, zbuf);
    k_conv<<<MM / 4, 256, 0, stream>>>(xc_raw, conv_w, conv_b, xc_act, xc_b);
    k_cvt_wx<<<64, 256, 0, stream>>>(x_proj_w, wxb);
    k_xproj_mfma<<<dim3(32, KCH), 256, 0, stream>>>(xc_b, wxb, part);
    k_xreduce<<<(MM * 64) / 256, 256, 0, stream>>>(part, dbc);
    k_dtproj<<<dim3(MM / 16, 4), 256, 0, stream>>>(dbc, dt_w, dt_b, delta);
    k_scan_partial<<<NSCAN / 256, 256, 0, stream>>>(delta, xc_act, dbc, A_log, hfin, aprod);
    k_scan_combine<<<(NST * NSEG) / 256, 256, 0, stream>>>(hfin, aprod);
    k_scan_final<<<NSCAN / 256, 256, 0, stream>>>(delta, xc_act, dbc, A_log, D_param, zbuf, hfin, yz);
    k_outproj<<<dim3(64, 8), 256, 0, stream>>>(yz, out_proj_w, t0, t1, t2, t3, outp);
}

// Round 12
// 169.108 us; speedup vs baseline: 5.1728x; 1.0119x over previous
//
#include <hip/hip_runtime.h>

// ---- problem constants ----
#define NB 2          // batch
#define LT 512        // per-tensor seq len
#define LL 2048       // concatenated seq len
#define MM 4096       // NB*LL rows
#define DMODEL 512
#define DINNER 1024
#define DTRANK 32
#define DSTATE 16
#define NSEG 64
#define SEGLEN 32     // NSEG*SEGLEN == LL
#define NST (NB * DINNER * DSTATE)         // 32768 (b,d,s) chains
#define NSCAN (NSEG * NB * DINNER)         // 131072 scan threads
#define KCH 8         // xproj K-chunks (split-K)

typedef short bf16x8 __attribute__((ext_vector_type(8)));
typedef float f32x4  __attribute__((ext_vector_type(4)));

__device__ __forceinline__ float silu_f(float x) { return x / (1.f + __expf(-x)); }
__device__ __forceinline__ short f2b(float f) {
    unsigned u = __float_as_uint(f);
    u += 0x7fffu + ((u >> 16) & 1u);   // RNE
    return (short)(u >> 16);
}
__device__ __forceinline__ float b2f(unsigned short u) {
    return __uint_as_float(((unsigned)u) << 16);
}

// ---------------------------------------------------------------------------
// K1: fused interleaved gather + in_proj GEMM (bf16 MFMA).
// n<1024 -> xc_raw (fp32, conv input); n>=1024 -> zb (bf16).
// ---------------------------------------------------------------------------
__global__ __launch_bounds__(256) void k_inproj(
    const float* __restrict__ t0, const float* __restrict__ t1,
    const float* __restrict__ t2, const float* __restrict__ t3,
    const float* __restrict__ W,
    float* __restrict__ xc_raw, unsigned short* __restrict__ zb)
{
    __shared__ short As[128 * 40];   // 32 cols + 8 pad (80B row stride)
    __shared__ short Bs[128 * 40];
    const int t = threadIdx.x;
    const int lane = t & 63;
    const int wid = t >> 6;
    const int wm = wid >> 1, wn = wid & 1;
    const int bm = blockIdx.x, bn = blockIdx.y;

    const int srow  = t >> 1;          // 0..127 staging row
    const int shalf = (t & 1) * 16;    // 0 or 16 (col offset)

    const int arow = bm * 128 + srow;
    const int gb = arow >> 11;
    const int gl = arow & 2047;
    const int gc = gl >> 7, gr = gl & 127;
    const int ti = gc & 3, ci = gc >> 2;
    const float* tp = (ti == 0) ? t0 : (ti == 1) ? t1 : (ti == 2) ? t2 : t3;
    const float* asrc = tp + ((size_t)gb * 512 + (size_t)(ci + 4 * gr)) * 512 + shalf;
    const float* bsrc = W + (size_t)(bn * 128 + srow) * 512 + shalf;

    f32x4 acc[4][4];
#pragma unroll
    for (int i = 0; i < 4; ++i)
#pragma unroll
        for (int j = 0; j < 4; ++j) acc[i][j] = (f32x4){0.f, 0.f, 0.f, 0.f};

    float4 ra[4], rb[4];
#pragma unroll
    for (int q = 0; q < 4; ++q) {
        ra[q] = *(const float4*)(asrc + q * 4);
        rb[q] = *(const float4*)(bsrc + q * 4);
    }

    const int ko = (lane >> 4) * 8;
    const int fr = lane & 15;

    for (int ks = 0; ks < 512 / 32; ++ks) {
        __syncthreads();
        {
            bf16x8 v0, v1, w0, w1;
            v0[0]=f2b(ra[0].x); v0[1]=f2b(ra[0].y); v0[2]=f2b(ra[0].z); v0[3]=f2b(ra[0].w);
            v0[4]=f2b(ra[1].x); v0[5]=f2b(ra[1].y); v0[6]=f2b(ra[1].z); v0[7]=f2b(ra[1].w);
            v1[0]=f2b(ra[2].x); v1[1]=f2b(ra[2].y); v1[2]=f2b(ra[2].z); v1[3]=f2b(ra[2].w);
            v1[4]=f2b(ra[3].x); v1[5]=f2b(ra[3].y); v1[6]=f2b(ra[3].z); v1[7]=f2b(ra[3].w);
            w0[0]=f2b(rb[0].x); w0[1]=f2b(rb[0].y); w0[2]=f2b(rb[0].z); w0[3]=f2b(rb[0].w);
            w0[4]=f2b(rb[1].x); w0[5]=f2b(rb[1].y); w0[6]=f2b(rb[1].z); w0[7]=f2b(rb[1].w);
            w1[0]=f2b(rb[2].x); w1[1]=f2b(rb[2].y); w1[2]=f2b(rb[2].z); w1[3]=f2b(rb[2].w);
            w1[4]=f2b(rb[3].x); w1[5]=f2b(rb[3].y); w1[6]=f2b(rb[3].z); w1[7]=f2b(rb[3].w);
            *(bf16x8*)&As[srow * 40 + shalf]     = v0;
            *(bf16x8*)&As[srow * 40 + shalf + 8] = v1;
            *(bf16x8*)&Bs[srow * 40 + shalf]     = w0;
            *(bf16x8*)&Bs[srow * 40 + shalf + 8] = w1;
        }
        __syncthreads();
        if (ks + 1 < 512 / 32) {
            const int k0 = (ks + 1) * 32;
#pragma unroll
            for (int q = 0; q < 4; ++q) {
                ra[q] = *(const float4*)(asrc + k0 + q * 4);
                rb[q] = *(const float4*)(bsrc + k0 + q * 4);
            }
        }
        bf16x8 af[4], bfr[4];
#pragma unroll
        for (int mf = 0; mf < 4; ++mf)
            af[mf] = *(const bf16x8*)&As[(wm * 64 + mf * 16 + fr) * 40 + ko];
#pragma unroll
        for (int nf = 0; nf < 4; ++nf)
            bfr[nf] = *(const bf16x8*)&Bs[(wn * 64 + nf * 16 + fr) * 40 + ko];
#pragma unroll
        for (int mf = 0; mf < 4; ++mf)
#pragma unroll
            for (int nf = 0; nf < 4; ++nf)
                acc[mf][nf] = __builtin_amdgcn_mfma_f32_16x16x32_bf16(
                    af[mf], bfr[nf], acc[mf][nf], 0, 0, 0);
    }

    if (bn < 8) {
#pragma unroll
        for (int mf = 0; mf < 4; ++mf) {
            const int gmb = bm * 128 + wm * 64 + mf * 16 + (lane >> 4) * 4;
#pragma unroll
            for (int nf = 0; nf < 4; ++nf) {
                const int gn = bn * 128 + wn * 64 + nf * 16 + (lane & 15);
#pragma unroll
                for (int j = 0; j < 4; ++j)
                    xc_raw[(size_t)(gmb + j) * DINNER + gn] = acc[mf][nf][j];
            }
        }
    } else {
#pragma unroll
        for (int mf = 0; mf < 4; ++mf) {
            const int gmb = bm * 128 + wm * 64 + mf * 16 + (lane >> 4) * 4;
#pragma unroll
            for (int nf = 0; nf < 4; ++nf) {
                const int gn = bn * 128 + wn * 64 + nf * 16 + (lane & 15) - 1024;
#pragma unroll
                for (int j = 0; j < 4; ++j)
                    zb[(size_t)(gmb + j) * DINNER + gn] = (unsigned short)f2b(acc[mf][nf][j]);
            }
        }
    }
}

// ---------------------------------------------------------------------------
// K2: causal depthwise conv1d (K=4, left pad 3) + bias + SiLU -> bf16 xc_b.
// ---------------------------------------------------------------------------
__global__ __launch_bounds__(256) void k_conv(
    const float* __restrict__ xc_raw, const float* __restrict__ cw,
    const float* __restrict__ cb, unsigned short* __restrict__ xc_b)
{
    const int d0 = threadIdx.x * 4;           // 0..1020
    const int m0 = blockIdx.x * 4;            // group of 4 rows, within one batch
    const int l0 = m0 & 2047;

    float4 w[4];
#pragma unroll
    for (int c = 0; c < 4; ++c) w[c] = *(const float4*)(cw + (size_t)(d0 + c) * 4);
    const float4 bb = *(const float4*)(cb + d0);

    float4 row[7];
#pragma unroll
    for (int o = 0; o < 7; ++o) {
        const int l = l0 + o - 3;
        if (l >= 0)
            row[o] = *(const float4*)(xc_raw + (size_t)(m0 + o - 3) * DINNER + d0);
        else
            row[o] = (float4){0.f, 0.f, 0.f, 0.f};
    }

#pragma unroll
    for (int mm = 0; mm < 4; ++mm) {
        float4 s = bb;
#pragma unroll
        for (int k = 0; k < 4; ++k) {
            const float4 r = row[mm + k];
            s.x += ((const float*)&w[0])[k] * r.x;
            s.y += ((const float*)&w[1])[k] * r.y;
            s.z += ((const float*)&w[2])[k] * r.z;
            s.w += ((const float*)&w[3])[k] * r.w;
        }
        ushort4 ob;
        ob.x = (unsigned short)f2b(silu_f(s.x));
        ob.y = (unsigned short)f2b(silu_f(s.y));
        ob.z = (unsigned short)f2b(silu_f(s.z));
        ob.w = (unsigned short)f2b(silu_f(s.w));
        *(ushort4*)(xc_b + (size_t)(m0 + mm) * DINNER + d0) = ob;
    }
}

// ---------------------------------------------------------------------------
// K2b: convert x_proj_w (64x1024 f32) -> bf16
// ---------------------------------------------------------------------------
__global__ __launch_bounds__(256) void k_cvt_wx(
    const float* __restrict__ Wx, unsigned short* __restrict__ wxb)
{
    const int i4 = blockIdx.x * 256 + threadIdx.x;    // < 16384
    float4 v = *(const float4*)(Wx + (size_t)i4 * 4);
    ushort4 o;
    o.x = (unsigned short)f2b(v.x);
    o.y = (unsigned short)f2b(v.y);
    o.z = (unsigned short)f2b(v.z);
    o.w = (unsigned short)f2b(v.w);
    *(ushort4*)(wxb + (size_t)i4 * 4) = o;
}

// ---------------------------------------------------------------------------
// K3: xproj split-K MFMA GEMM.
// ---------------------------------------------------------------------------
__global__ __launch_bounds__(256) void k_xproj_mfma(
    const unsigned short* __restrict__ xc_b, const unsigned short* __restrict__ wxb,
    float* __restrict__ part)
{
    __shared__ short As[128 * 136];   // 128 K-cols + 8 pad
    __shared__ short Bs[64 * 136];
    const int t = threadIdx.x;
    const int lane = t & 63;
    const int w = t >> 6;
    const int bm = blockIdx.x;        // 0..31
    const int kc = blockIdx.y;        // 0..7

    {
        const int row = t >> 1;
        const int cb0 = (t & 1) * 64;
        const unsigned short* src = xc_b + (size_t)(bm * 128 + row) * 1024 + kc * 128 + cb0;
#pragma unroll
        for (int q = 0; q < 8; ++q)
            *(bf16x8*)&As[row * 136 + cb0 + q * 8] = *(const bf16x8*)(src + q * 8);
    }
    {
        const int row = t >> 2;
        const int cb0 = (t & 3) * 32;
        const unsigned short* src = wxb + (size_t)row * 1024 + kc * 128 + cb0;
#pragma unroll
        for (int q = 0; q < 4; ++q)
            *(bf16x8*)&Bs[row * 136 + cb0 + q * 8] = *(const bf16x8*)(src + q * 8);
    }
    __syncthreads();

    const int fr = lane & 15;
    const int ko = (lane >> 4) * 8;

    f32x4 acc[2][4];
#pragma unroll
    for (int i = 0; i < 2; ++i)
#pragma unroll
        for (int j = 0; j < 4; ++j) acc[i][j] = (f32x4){0.f, 0.f, 0.f, 0.f};

#pragma unroll
    for (int ks = 0; ks < 4; ++ks) {
        const int kb = ks * 32 + ko;
        bf16x8 af[2], bfr[4];
#pragma unroll
        for (int mf = 0; mf < 2; ++mf)
            af[mf] = *(const bf16x8*)&As[(w * 32 + mf * 16 + fr) * 136 + kb];
#pragma unroll
        for (int nf = 0; nf < 4; ++nf)
            bfr[nf] = *(const bf16x8*)&Bs[(nf * 16 + fr) * 136 + kb];
#pragma unroll
        for (int mf = 0; mf < 2; ++mf)
#pragma unroll
            for (int nf = 0; nf < 4; ++nf)
                acc[mf][nf] = __builtin_amdgcn_mfma_f32_16x16x32_bf16(
                    af[mf], bfr[nf], acc[mf][nf], 0, 0, 0);
    }

    float* pb = part + (size_t)kc * (MM * 64);
#pragma unroll
    for (int mf = 0; mf < 2; ++mf) {
        const int rb = bm * 128 + w * 32 + mf * 16 + (lane >> 4) * 4;
#pragma unroll
        for (int nf = 0; nf < 4; ++nf) {
            const int col = nf * 16 + (lane & 15);
#pragma unroll
            for (int j = 0; j < 4; ++j)
                pb[(size_t)(rb + j) * 64 + col] = acc[mf][nf][j];
        }
    }
}

// ---------------------------------------------------------------------------
// K3b: reduce split-K partials -> dbc
// ---------------------------------------------------------------------------
__global__ __launch_bounds__(256) void k_xreduce(
    const float* __restrict__ part, float* __restrict__ dbc)
{
    const int i = blockIdx.x * 256 + threadIdx.x;    // < MM*64
    float s = 0.f;
#pragma unroll
    for (int kc = 0; kc < KCH; ++kc)
        s += part[(size_t)kc * (MM * 64) + i];
    dbc[i] = s;
}

// ---------------------------------------------------------------------------
// K4: dtproj — scalar-uniform dbc loads (SGPR), fast softplus -> bf16 delta.
// ---------------------------------------------------------------------------
__global__ __launch_bounds__(256) void k_dtproj(
    const float* __restrict__ dbc, const float* __restrict__ dtw,
    const float* __restrict__ dtb, unsigned short* __restrict__ delta_b)
{
    const int tid = threadIdx.x;
    const int m0 = blockIdx.x * 16;
    const int d  = blockIdx.y * 256 + tid;

    float w[DTRANK];
#pragma unroll
    for (int q = 0; q < 8; ++q) {
        float4 v = *(const float4*)(dtw + (size_t)d * DTRANK + q * 4);
        w[q * 4 + 0] = v.x; w[q * 4 + 1] = v.y;
        w[q * 4 + 2] = v.z; w[q * 4 + 3] = v.w;
    }
    const float bias = dtb[d];

#pragma unroll 4
    for (int m = 0; m < 16; ++m) {
        const float* bc = dbc + (size_t)(m0 + m) * 64;   // wave-uniform address
        float s0 = bias, s1 = 0.f, s2 = 0.f, s3 = 0.f;
#pragma unroll
        for (int r = 0; r < DTRANK; r += 4) {
            s0 += bc[r + 0] * w[r + 0];
            s1 += bc[r + 1] * w[r + 1];
            s2 += bc[r + 2] * w[r + 2];
            s3 += bc[r + 3] * w[r + 3];
        }
        const float s = (s0 + s1) + (s2 + s3);
        const float sp = (s > 20.f) ? s : __logf(1.f + __expf(s));
        delta_b[(size_t)(m0 + m) * DINNER + d] = (unsigned short)f2b(sp);
    }
}

// ---------------------------------------------------------------------------
// K5: scan phase A with 1-step prefetch + scalar (readfirstlane) dbc loads.
// delta/x read as bf16.
// ---------------------------------------------------------------------------
__global__ __launch_bounds__(256) void k_scan_partial(
    const unsigned short* __restrict__ delta_b, const unsigned short* __restrict__ xcb,
    const float* __restrict__ dbc, const float* __restrict__ A_log,
    float* __restrict__ hfin, float* __restrict__ aprod)
{
    const int gid = blockIdx.x * 256 + threadIdx.x;   // < NSCAN
    const int d = gid & 1023;
    const int b = (gid >> 10) & (NB - 1);
    const int g = gid >> 11;                           // 0..63

    float Af[DSTATE];
#pragma unroll
    for (int q = 0; q < 4; ++q) {
        float4 a4 = *(const float4*)(A_log + d * DSTATE + q * 4);
        Af[q * 4 + 0] = -__expf(a4.x);
        Af[q * 4 + 1] = -__expf(a4.y);
        Af[q * 4 + 2] = -__expf(a4.z);
        Af[q * 4 + 3] = -__expf(a4.w);
    }

    float h[DSTATE], ap[DSTATE];
#pragma unroll
    for (int s = 0; s < DSTATE; ++s) { h[s] = 0.f; ap[s] = 1.f; }

    const int mbase = b * LL + g * SEGLEN;
    const int mlast = mbase + SEGLEN - 1;

    int m = mbase;
    float de = b2f(delta_b[(size_t)m * DINNER + d]);
    float x  = b2f(xcb    [(size_t)m * DINNER + d]);
    float Bv[DSTATE];
    {
        const int mu = __builtin_amdgcn_readfirstlane(m);
        const float* bc = dbc + (size_t)mu * 64 + 32;   // uniform -> s_load
#pragma unroll
        for (int q = 0; q < 4; ++q) {
            float4 b4 = *(const float4*)(bc + q * 4);
            Bv[q * 4 + 0] = b4.x; Bv[q * 4 + 1] = b4.y;
            Bv[q * 4 + 2] = b4.z; Bv[q * 4 + 3] = b4.w;
        }
    }

#pragma unroll 2
    for (int ll = 0; ll < SEGLEN; ++ll) {
        const int mn = (m < mlast) ? m + 1 : mlast;
        const float de_n = b2f(delta_b[(size_t)mn * DINNER + d]);
        const float x_n  = b2f(xcb    [(size_t)mn * DINNER + d]);
        float Bn[DSTATE];
        {
            const int mun = __builtin_amdgcn_readfirstlane(mn);
            const float* bcn = dbc + (size_t)mun * 64 + 32;
#pragma unroll
            for (int q = 0; q < 4; ++q) {
                float4 b4 = *(const float4*)(bcn + q * 4);
                Bn[q * 4 + 0] = b4.x; Bn[q * 4 + 1] = b4.y;
                Bn[q * 4 + 2] = b4.z; Bn[q * 4 + 3] = b4.w;
            }
        }
        const float dx = de * x;
#pragma unroll
        for (int s = 0; s < DSTATE; ++s) {
            const float dA = __expf(de * Af[s]);
            ap[s] *= dA;
            h[s] = dA * h[s] + dx * Bv[s];
        }
        de = de_n; x = x_n;
#pragma unroll
        for (int s = 0; s < DSTATE; ++s) Bv[s] = Bn[s];
        ++m;
    }

    const size_t base = (size_t)(b * DINNER + d) * DSTATE;
#pragma unroll
    for (int s = 0; s < DSTATE; ++s) {
        hfin [(base + s) * NSEG + g] = h[s];
        aprod[(base + s) * NSEG + g] = ap[s];
    }
}

// ---------------------------------------------------------------------------
// K6: combine: wave-parallel Hillis-Steele scan over 64 segments.
// ---------------------------------------------------------------------------
__global__ __launch_bounds__(256) void k_scan_combine(
    float* __restrict__ hfin, const float* __restrict__ aprod)
{
    const int tid = blockIdx.x * 256 + threadIdx.x;   // < NST*NSEG
    const int g = tid & 63;
    const size_t bds = (size_t)(tid >> 6);
    float A = aprod[bds * NSEG + g];
    float B = hfin [bds * NSEG + g];
#pragma unroll
    for (int off = 1; off < 64; off <<= 1) {
        const float Ap = __shfl_up(A, off, 64);
        const float Bp = __shfl_up(B, off, 64);
        if (g >= off) { B = A * Bp + B; A = A * Ap; }
    }
    const float hprev = __shfl_up(B, 1, 64);
    hfin[bds * NSEG + g] = (g == 0) ? 0.f : hprev;
}

// ---------------------------------------------------------------------------
// K7: scan phase C with 1-step prefetch + scalar dbc loads.
// delta/x/z read bf16, yz written bf16.
// ---------------------------------------------------------------------------
__global__ __launch_bounds__(256) void k_scan_final(
    const unsigned short* __restrict__ delta_b, const unsigned short* __restrict__ xcb,
    const float* __restrict__ dbc, const float* __restrict__ A_log,
    const float* __restrict__ Dp, const unsigned short* __restrict__ zb,
    const float* __restrict__ hin, unsigned short* __restrict__ yzb)
{
    const int gid = blockIdx.x * 256 + threadIdx.x;   // < NSCAN
    const int d = gid & 1023;
    const int b = (gid >> 10) & (NB - 1);
    const int g = gid >> 11;

    float Af[DSTATE];
#pragma unroll
    for (int q = 0; q < 4; ++q) {
        float4 a4 = *(const float4*)(A_log + d * DSTATE + q * 4);
        Af[q * 4 + 0] = -__expf(a4.x);
        Af[q * 4 + 1] = -__expf(a4.y);
        Af[q * 4 + 2] = -__expf(a4.z);
        Af[q * 4 + 3] = -__expf(a4.w);
    }
    const float Dd = Dp[d];

    const size_t base = (size_t)(b * DINNER + d) * DSTATE;
    float h[DSTATE];
#pragma unroll
    for (int s = 0; s < DSTATE; ++s) h[s] = hin[(base + s) * NSEG + g];

    const int mbase = b * LL + g * SEGLEN;
    const int mlast = mbase + SEGLEN - 1;

    int m = mbase;
    float de = b2f(delta_b[(size_t)m * DINNER + d]);
    float x  = b2f(xcb    [(size_t)m * DINNER + d]);
    float zz = b2f(zb     [(size_t)m * DINNER + d]);
    float Bv[DSTATE], Cv[DSTATE];
    {
        const int mu = __builtin_amdgcn_readfirstlane(m);
        const float* bc = dbc + (size_t)mu * 64;
#pragma unroll
        for (int q = 0; q < 4; ++q) {
            float4 b4 = *(const float4*)(bc + 32 + q * 4);
            float4 c4 = *(const float4*)(bc + 48 + q * 4);
            Bv[q * 4 + 0] = b4.x; Bv[q * 4 + 1] = b4.y;
            Bv[q * 4 + 2] = b4.z; Bv[q * 4 + 3] = b4.w;
            Cv[q * 4 + 0] = c4.x; Cv[q * 4 + 1] = c4.y;
            Cv[q * 4 + 2] = c4.z; Cv[q * 4 + 3] = c4.w;
        }
    }

#pragma unroll 2
    for (int ll = 0; ll < SEGLEN; ++ll) {
        const int mn = (m < mlast) ? m + 1 : mlast;
        const float de_n = b2f(delta_b[(size_t)mn * DINNER + d]);
        const float x_n  = b2f(xcb    [(size_t)mn * DINNER + d]);
        const float z_n  = b2f(zb     [(size_t)mn * DINNER + d]);
        float Bn[DSTATE], Cn[DSTATE];
        {
            const int mun = __builtin_amdgcn_readfirstlane(mn);
            const float* bcn = dbc + (size_t)mun * 64;
#pragma unroll
            for (int q = 0; q < 4; ++q) {
                float4 b4 = *(const float4*)(bcn + 32 + q * 4);
                float4 c4 = *(const float4*)(bcn + 48 + q * 4);
                Bn[q * 4 + 0] = b4.x; Bn[q * 4 + 1] = b4.y;
                Bn[q * 4 + 2] = b4.z; Bn[q * 4 + 3] = b4.w;
                Cn[q * 4 + 0] = c4.x; Cn[q * 4 + 1] = c4.y;
                Cn[q * 4 + 2] = c4.z; Cn[q * 4 + 3] = c4.w;
            }
        }
        const float dx = de * x;
        float y0 = 0.f, y1 = 0.f, y2 = 0.f, y3 = 0.f;
#pragma unroll
        for (int s = 0; s < DSTATE; s += 4) {
            float dA;
            dA = __expf(de * Af[s + 0]); h[s + 0] = dA * h[s + 0] + dx * Bv[s + 0]; y0 += h[s + 0] * Cv[s + 0];
            dA = __expf(de * Af[s + 1]); h[s + 1] = dA * h[s + 1] + dx * Bv[s + 1]; y1 += h[s + 1] * Cv[s + 1];
            dA = __expf(de * Af[s + 2]); h[s + 2] = dA * h[s + 2] + dx * Bv[s + 2]; y2 += h[s + 2] * Cv[s + 2];
            dA = __expf(de * Af[s + 3]); h[s + 3] = dA * h[s + 3] + dx * Bv[s + 3]; y3 += h[s + 3] * Cv[s + 3];
        }
        const float y = (y0 + y1) + (y2 + y3);
        yzb[(size_t)m * DINNER + d] = (unsigned short)f2b((y + Dd * x) * silu_f(zz));
        de = de_n; x = x_n; zz = z_n;
#pragma unroll
        for (int s = 0; s < DSTATE; ++s) { Bv[s] = Bn[s]; Cv[s] = Cn[s]; }
        ++m;
    }
}

// ---------------------------------------------------------------------------
// K8: out_proj GEMM (bf16 MFMA), 64x64 tiles, grid (64,8)=512 blocks.
// A operand (yz) already bf16 in global.
// ---------------------------------------------------------------------------
__global__ __launch_bounds__(256) void k_outproj(
    const unsigned short* __restrict__ yzb, const float* __restrict__ Wo,
    const float* __restrict__ t0, const float* __restrict__ t1,
    const float* __restrict__ t2, const float* __restrict__ t3,
    float* __restrict__ outp)
{
    __shared__ short As[64 * 40];   // 64 rows x (32 + 8 pad) shorts
    __shared__ short Bs[64 * 40];
    const int t = threadIdx.x;
    const int lane = t & 63;
    const int wid = t >> 6;
    const int wm = wid >> 1, wn = wid & 1;
    const int bm = blockIdx.x;      // 0..63
    const int bn = blockIdx.y;      // 0..7

    const int srow = t >> 2;          // 0..63
    const int scol = (t & 3) * 8;     // 0,8,16,24

    const unsigned short* asrc = yzb + (size_t)(bm * 64 + srow) * DINNER + scol;
    const float* bsrc = Wo + (size_t)(bn * 64 + srow) * DINNER + scol;

    f32x4 acc[2][2];
#pragma unroll
    for (int i = 0; i < 2; ++i)
#pragma unroll
        for (int j = 0; j < 2; ++j) acc[i][j] = (f32x4){0.f, 0.f, 0.f, 0.f};

    bf16x8 raA = *(const bf16x8*)asrc;
    float4 rb[2];
#pragma unroll
    for (int q = 0; q < 2; ++q) rb[q] = *(const float4*)(bsrc + q * 4);

    const int ko = (lane >> 4) * 8;
    const int fr = lane & 15;

    for (int ks = 0; ks < DINNER / 32; ++ks) {
        __syncthreads();
        {
            bf16x8 w0;
            w0[0]=f2b(rb[0].x); w0[1]=f2b(rb[0].y); w0[2]=f2b(rb[0].z); w0[3]=f2b(rb[0].w);
            w0[4]=f2b(rb[1].x); w0[5]=f2b(rb[1].y); w0[6]=f2b(rb[1].z); w0[7]=f2b(rb[1].w);
            *(bf16x8*)&As[srow * 40 + scol] = raA;
            *(bf16x8*)&Bs[srow * 40 + scol] = w0;
        }
        __syncthreads();
        if (ks + 1 < DINNER / 32) {
            const int k0 = (ks + 1) * 32;
            raA = *(const bf16x8*)(asrc + k0);
#pragma unroll
            for (int q = 0; q < 2; ++q) rb[q] = *(const float4*)(bsrc + k0 + q * 4);
        }
        bf16x8 af[2], bfr[2];
#pragma unroll
        for (int mf = 0; mf < 2; ++mf)
            af[mf] = *(const bf16x8*)&As[(wm * 32 + mf * 16 + fr) * 40 + ko];
#pragma unroll
        for (int nf = 0; nf < 2; ++nf)
            bfr[nf] = *(const bf16x8*)&Bs[(wn * 32 + nf * 16 + fr) * 40 + ko];
#pragma unroll
        for (int mf = 0; mf < 2; ++mf)
#pragma unroll
            for (int nf = 0; nf < 2; ++nf)
                acc[mf][nf] = __builtin_amdgcn_mfma_f32_16x16x32_bf16(
                    af[mf], bfr[nf], acc[mf][nf], 0, 0, 0);
    }

#pragma unroll
    for (int mf = 0; mf < 2; ++mf) {
#pragma unroll
        for (int j = 0; j < 4; ++j) {
            const int gm = bm * 64 + wm * 32 + mf * 16 + (lane >> 4) * 4 + j;
            const int b = gm >> 11;
            const int l = gm & 2047;
            const int ii = l & 3;
            const int jj = l >> 2;
            const float* tsel = (ii == 0) ? t0 : (ii == 1) ? t1 : (ii == 2) ? t2 : t3;
#pragma unroll
            for (int nf = 0; nf < 2; ++nf) {
                const int gn = bn * 64 + wn * 32 + nf * 16 + (lane & 15);
                const float tv = tsel[((size_t)b * 512 + jj) * 512 + gn];
                outp[(((size_t)ii * NB + b) * 512 + jj) * 512 + gn] = acc[mf][nf][j] + tv;
            }
        }
    }
}

// ---------------------------------------------------------------------------
extern "C" void kernel_launch(void* const* d_in, const int* in_sizes, int n_in,
                              void* d_out, int out_size, void* d_ws, size_t ws_size,
                              hipStream_t stream)
{
    const float* t0 = (const float*)d_in[0];
    const float* t1 = (const float*)d_in[1];
    const float* t2 = (const float*)d_in[2];
    const float* t3 = (const float*)d_in[3];
    const float* in_proj_w  = (const float*)d_in[4];
    const float* conv_w     = (const float*)d_in[5];
    const float* conv_b     = (const float*)d_in[6];
    const float* x_proj_w   = (const float*)d_in[7];
    const float* dt_w       = (const float*)d_in[8];
    const float* dt_b       = (const float*)d_in[9];
    const float* A_log      = (const float*)d_in[10];
    const float* D_param    = (const float*)d_in[11];
    const float* out_proj_w = (const float*)d_in[12];
    float* outp = (float*)d_out;

    // workspace carve.  bf16 streams: zb, xc_b, delta_b, yzb.
    // Aliasing timeline (stream-ordered, audited):
    // 1 inproj:   W xc_raw(f32), zb(bf16)
    // 2 conv:     R xc_raw          -> W xc_b
    // 3 cvt_wx:   W wxb (xc_raw+2M floats) [xc_raw dead]
    // 4 xproj:    R xc_b, wxb       -> W part (xc_raw 0..2M floats)
    // 5 xreduce:  R part            -> W dbc
    // 6 dtproj:   R dbc, dt_w       -> W delta_b
    // 7 scanA:    R delta_b,xc_b,dbc-> W hfin, aprod (xc_raw 0..2M; part dead)
    // 8 combine:  R hfin, aprod     -> W hfin (in place)
    // 9 scanC:    R delta_b,xc_b,dbc,hfin,zb -> W yzb (xc_raw region; aprod dead)
    // 10 outproj: R yzb, Wo, t*     -> W outp
    float* xc_raw = (float*)d_ws;                                   // 4M floats (16MB)
    unsigned short* zb      = (unsigned short*)(xc_raw + (size_t)MM * DINNER);  // 4M shorts
    unsigned short* xc_b    = zb + (size_t)MM * DINNER;             // 4M shorts
    unsigned short* delta_b = xc_b + (size_t)MM * DINNER;           // 4M shorts
    float* dbc  = (float*)(delta_b + (size_t)MM * DINNER);          // 256K floats
    float* hfin = dbc + (size_t)MM * 64;                            // 2M floats
    float* part  = xc_raw;                                          // alias (2M floats)
    float* aprod = xc_raw;                                          // alias (2M floats)
    unsigned short* wxb = (unsigned short*)(xc_raw + (size_t)KCH * MM * 64);
    unsigned short* yzb = (unsigned short*)xc_raw;                  // alias (4M shorts)

    k_inproj<<<dim3(32, 16), 256, 0, stream>>>(t0, t1, t2, t3, in_proj_w, xc_raw, zb);
    k_conv<<<MM / 4, 256, 0, stream>>>(xc_raw, conv_w, conv_b, xc_b);
    k_cvt_wx<<<64, 256, 0, stream>>>(x_proj_w, wxb);
    k_xproj_mfma<<<dim3(32, KCH), 256, 0, stream>>>(xc_b, wxb, part);
    k_xreduce<<<(MM * 64) / 256, 256, 0, stream>>>(part, dbc);
    k_dtproj<<<dim3(MM / 16, 4), 256, 0, stream>>>(dbc, dt_w, dt_b, delta_b);
    k_scan_partial<<<NSCAN / 256, 256, 0, stream>>>(delta_b, xc_b, dbc, A_log, hfin, aprod);
    k_scan_combine<<<(NST * NSEG) / 256, 256, 0, stream>>>(hfin, aprod);
    k_scan_final<<<NSCAN / 256, 256, 0, stream>>>(delta_b, xc_b, dbc, A_log, D_param, zb, hfin, yzb);
    k_outproj<<<dim3(64, 8), 256, 0, stream>>>(yzb, out_proj_w, t0, t1, t2, t3, outp);
}